// Round 2
// baseline (1644.743 us; speedup 1.0000x reference)
//
#include <hip/hip_runtime.h>
#include <hip/hip_bf16.h>

// Problem constants
#define BS   4
#define C    256
#define H_   64
#define W_   64
#define HW   4096          // 64*64
#define NPIX 16384         // 4*4096
#define NCH  289           // cost-volume channels (17*17)
#define MO   17
#define PH   80            // padded 64+2*8
#define PW   80
#define C1   144
#define C2   49

// ---------------------------------------------------------------------------
// K1: per-pixel inverse L2 norm over 256 channels of f1 (NCHW input)
__global__ void norm_kernel(const float* __restrict__ f1, float* __restrict__ inv_norm) {
    int p = blockIdx.x * 256 + threadIdx.x;     // 0..16383
    if (p >= NPIX) return;
    int b = p >> 12;
    int hw = p & 4095;
    const float* base = f1 + (size_t)b * C * HW + hw;
    float s = 0.f;
    for (int c = 0; c < C; ++c) {
        float v = base[(size_t)c * HW];
        s += v * v;
    }
    float n = sqrtf(s);
    inv_norm[p] = 1.0f / fmaxf(n, 1e-12f);
}

// ---------------------------------------------------------------------------
// K2: NCHW -> NHWC transpose. padded=0: dst [BS,64,64,C] scaled by inv_norm.
//     padded=1: dst [BS,80,80,C] at +8 offset (pad pre-zeroed by memset).
__global__ void transpose_kernel(const float* __restrict__ src, float* __restrict__ dst,
                                 const float* __restrict__ inv_norm, int padded) {
    __shared__ float tile[32][33];
    int blk = blockIdx.x;                 // 4 * 8 * 128 = 4096 blocks
    int pblk = blk & 127;                 // HW/32
    int cblk = (blk >> 7) & 7;            // C/32
    int b    = blk >> 10;
    int tx = threadIdx.x & 31, ty = threadIdx.x >> 5;
    int c0 = cblk * 32, p0 = pblk * 32;
    const float* s = src + (size_t)b * C * HW;
#pragma unroll
    for (int i = 0; i < 4; ++i) {
        int c = c0 + ty + 8 * i;
        tile[ty + 8 * i][tx] = s[(size_t)c * HW + p0 + tx];
    }
    __syncthreads();
#pragma unroll
    for (int i = 0; i < 4; ++i) {
        int p = p0 + ty + 8 * i;
        float v = tile[tx][ty + 8 * i];
        int c = c0 + tx;
        if (!padded) {
            v *= inv_norm[b * HW + p];
            dst[((size_t)b * HW + p) * C + c] = v;
        } else {
            int h = p >> 6, w = p & 63;
            dst[(((size_t)b * PH + h + 8) * PW + (w + 8)) * C + c] = v;
        }
    }
}

// ---------------------------------------------------------------------------
// Weight rearrange kernels
__global__ void rearrange_w1(const float* __restrict__ w, float* __restrict__ wr) {
    // [144][289][3][3] OIHW -> [9][289][144]
    int idx = blockIdx.x * 256 + threadIdx.x;
    if (idx >= C1 * NCH * 9) return;
    int o = idx / (NCH * 9);
    int r = idx - o * (NCH * 9);
    int ci = r / 9;
    int kk = r - ci * 9;
    wr[((size_t)kk * NCH + ci) * C1 + o] = w[idx];
}
__global__ void rearrange_w2(const float* __restrict__ w, float* __restrict__ wr) {
    // [49][144][3][3] -> [9][144][49]
    int idx = blockIdx.x * 256 + threadIdx.x;
    if (idx >= C2 * C1 * 9) return;
    int o = idx / (C1 * 9);
    int r = idx - o * (C1 * 9);
    int ci = r / 9;
    int kk = r - ci * 9;
    wr[((size_t)kk * C1 + ci) * C2 + o] = w[idx];
}
__global__ void rearrange_dw(const float* __restrict__ w, float* __restrict__ wr) {
    // [289][1][7][7] -> [49][289]
    int idx = blockIdx.x * 256 + threadIdx.x;
    if (idx >= NCH * 49) return;
    int ch = idx / 49;
    int kk = idx - ch * 49;
    wr[kk * NCH + ch] = w[idx];
}

// ---------------------------------------------------------------------------
// K3: cost volume. Block = 16 pixels of one row (b,h,w0..w0+15).
// LDS: x1 tile 16x256 (16KB) + x2 row buffer 32x256 (32KB).
// Each wave handles 4 pixels; per (dj,di) a 256-ch dot via float4 + shuffle.
__global__ void cv_kernel(const float* __restrict__ x1t, const float* __restrict__ x2t,
                          float* __restrict__ cv) {
    __shared__ float x1s[16 * 256];
    __shared__ float x2s[32 * 256];
    int blk = blockIdx.x;                  // 1024
    int wseg = blk & 3;
    int h = (blk >> 2) & 63;
    int b = blk >> 8;
    int w0 = wseg * 16;
    int t = threadIdx.x;

    const float* x1p = x1t + ((size_t)b * HW + h * 64 + w0) * C;
    for (int idx = t; idx < 16 * 256; idx += 256) x1s[idx] = x1p[idx];
    __syncthreads();

    int wave = t >> 6, lane = t & 63;
    const float4* x1s4 = (const float4*)x1s;
    float4 a[4];
#pragma unroll
    for (int pp = 0; pp < 4; ++pp) a[pp] = x1s4[(wave * 4 + pp) * 64 + lane];

    const float* x2b = x2t + (size_t)b * PH * PW * C;
    const float4* x2s4 = (const float4*)x2s;

    for (int dj = 0; dj < MO; ++dj) {
        __syncthreads();
        const float* rowp = x2b + ((size_t)(h + dj) * PW + w0) * C;
        for (int idx = t; idx < 32 * 256; idx += 256) x2s[idx] = rowp[idx];
        __syncthreads();
#pragma unroll
        for (int pp = 0; pp < 4; ++pp) {
            int px = wave * 4 + pp;
            size_t outbase = ((size_t)b * HW + h * 64 + w0 + px) * NCH + dj * MO;
            for (int di = 0; di < MO; ++di) {
                float4 x = x2s4[(px + di) * 64 + lane];
                float p = a[pp].x * x.x + a[pp].y * x.y + a[pp].z * x.z + a[pp].w * x.w;
                p += __shfl_xor(p, 32);
                p += __shfl_xor(p, 16);
                p += __shfl_xor(p, 8);
                p += __shfl_xor(p, 4);
                p += __shfl_xor(p, 2);
                p += __shfl_xor(p, 1);
                if (lane == 0) {
                    float v = p * (1.0f / 256.0f);
                    cv[outbase + di] = (v > 0.f) ? v : 0.1f * v;   // leaky 0.1
                }
            }
        }
    }
}

// ---------------------------------------------------------------------------
// K4: depthwise 7x7 attention conv + elementwise multiply. cv/av are NHWC.
__global__ void dw_att_kernel(const float* __restrict__ cv, const float* __restrict__ wdw,
                              const float* __restrict__ att_b, float* __restrict__ av) {
    size_t tid = (size_t)blockIdx.x * 256 + threadIdx.x;
    if (tid >= (size_t)NPIX * NCH) return;
    int ch = (int)(tid % NCH);
    size_t pix = tid / NCH;
    int b = (int)(pix >> 12);
    int hw = (int)(pix & 4095);
    int h = hw >> 6, w = hw & 63;
    float acc = att_b[ch];
#pragma unroll
    for (int dy = 0; dy < 7; ++dy) {
        int y = h + dy - 3;
        if ((unsigned)y >= 64u) continue;
        const float* crow = cv + ((size_t)b * HW + y * 64) * NCH;
#pragma unroll
        for (int dx = 0; dx < 7; ++dx) {
            int x = w + dx - 3;
            if ((unsigned)x >= 64u) continue;
            acc += crow[(size_t)x * NCH + ch] * wdw[(dy * 7 + dx) * NCH + ch];
        }
    }
    float c0 = cv[pix * NCH + ch];
    av[pix * NCH + ch] = c0 * acc;
}

// ---------------------------------------------------------------------------
// K5: conv3x3 289->144 + ReLU. Block = 16 px * 144 out, 256 thr (9 acc each).
// K loop: 9 taps x 17 chunks of 17 channels, weights+acts staged in LDS.
// NOTE: activation stage is 17*16=272 entries -> strided loop (256 threads).
__global__ void agg1_kernel(const float* __restrict__ av, const float* __restrict__ wr,
                            const float* __restrict__ bias, float* __restrict__ h1) {
    __shared__ float wS[17 * 144];
    __shared__ float aS[17][16];
    int blk = blockIdx.x;
    int wseg = blk & 3;
    int h = (blk >> 2) & 63;
    int b = blk >> 8;
    int w0 = wseg * 16;
    int t = threadIdx.x;
    int px = t >> 4, og = t & 15;
    float acc[9];
#pragma unroll
    for (int j = 0; j < 9; ++j) acc[j] = bias[og + 16 * j];
    for (int k = 0; k < 9; ++k) {
        int dy = k / 3 - 1, dx = k % 3 - 1;
        int y = h + dy;
        const float* wkp = wr + (size_t)k * NCH * C1;
        for (int cc = 0; cc < NCH; cc += 17) {
            __syncthreads();
            for (int idx = t; idx < 17 * C1; idx += 256)
                wS[idx] = wkp[(size_t)cc * C1 + idx];
            // stage 272 activation entries with 256 threads (2 iters for t<16)
            for (int idx = t; idx < 17 * 16; idx += 256) {
                int aci = idx % 17, apx = idx / 17;
                int col = w0 + apx + dx;
                float v = 0.f;
                if ((unsigned)y < 64u && (unsigned)col < 64u)
                    v = av[(((size_t)b * HW) + y * 64 + col) * NCH + cc + aci];
                aS[aci][apx] = v;
            }
            __syncthreads();
#pragma unroll
            for (int ci = 0; ci < 17; ++ci) {
                float aval = aS[ci][px];
#pragma unroll
                for (int j = 0; j < 9; ++j)
                    acc[j] += aval * wS[ci * C1 + og + 16 * j];
            }
        }
    }
    size_t pix = (size_t)b * HW + h * 64 + w0 + px;
#pragma unroll
    for (int j = 0; j < 9; ++j)
        h1[pix * C1 + og + 16 * j] = fmaxf(acc[j], 0.f);
}

// ---------------------------------------------------------------------------
// K6: conv3x3 144->49 + ReLU, writes NCHW output.
__global__ void agg2_kernel(const float* __restrict__ h1, const float* __restrict__ wr,
                            const float* __restrict__ bias, float* __restrict__ out) {
    __shared__ float wS[16 * 49];
    __shared__ float aS[16][17];
    int blk = blockIdx.x;
    int wseg = blk & 3;
    int h = (blk >> 2) & 63;
    int b = blk >> 8;
    int w0 = wseg * 16;
    int t = threadIdx.x;
    int px = t >> 4, og = t & 15;
    float acc[4];
#pragma unroll
    for (int j = 0; j < 4; ++j) {
        int o = og + 16 * j;
        acc[j] = (o < C2) ? bias[o] : 0.f;
    }
    for (int k = 0; k < 9; ++k) {
        int dy = k / 3 - 1, dx = k % 3 - 1;
        int y = h + dy;
        int col = w0 + px + dx;
        for (int cc = 0; cc < C1; cc += 16) {
            __syncthreads();
            for (int idx = t; idx < 16 * C2; idx += 256)
                wS[idx] = wr[((size_t)k * C1 + cc) * C2 + idx];
            {
                float v = 0.f;
                if ((unsigned)y < 64u && (unsigned)col < 64u)
                    v = h1[(((size_t)b * HW) + y * 64 + col) * C1 + cc + og];
                aS[px][og] = v;
            }
            __syncthreads();
#pragma unroll
            for (int ci = 0; ci < 16; ++ci) {
                float aval = aS[px][ci];
#pragma unroll
                for (int j = 0; j < 4; ++j) {
                    int o = og + 16 * j;
                    if (o < C2) acc[j] += aval * wS[ci * C2 + o];
                }
            }
        }
    }
#pragma unroll
    for (int j = 0; j < 4; ++j) {
        int o = og + 16 * j;
        if (o < C2)
            out[(((size_t)b * C2 + o) * 64 + h) * 64 + w0 + px] = fmaxf(acc[j], 0.f);
    }
}

// ---------------------------------------------------------------------------
extern "C" void kernel_launch(void* const* d_in, const int* in_sizes, int n_in,
                              void* d_out, int out_size, void* d_ws, size_t ws_size,
                              hipStream_t stream) {
    const float* f1    = (const float*)d_in[0];
    const float* f2    = (const float*)d_in[1];
    const float* att_w = (const float*)d_in[2];
    const float* att_b = (const float*)d_in[3];
    const float* w1    = (const float*)d_in[4];
    const float* b1    = (const float*)d_in[5];
    const float* w2    = (const float*)d_in[6];
    const float* b2    = (const float*)d_in[7];
    float* out = (float*)d_out;
    float* ws = (float*)d_ws;

    // Workspace layout (floats)
    size_t o_norm = 0;                       // 16384
    size_t o_x1t  = o_norm + 16384;          // 4,194,304
    size_t o_x2t  = o_x1t + (size_t)BS * HW * C;          // 6,553,600 (padded)
    size_t o_cv   = o_x2t + (size_t)BS * PH * PW * C;     // 4,734,976
    size_t o_av   = o_cv + (size_t)NPIX * NCH;            // 4,734,976
    size_t o_h1   = o_av + (size_t)NPIX * NCH;            // 2,359,296
    size_t o_w1r  = o_h1 + (size_t)NPIX * C1;             // 374,544
    size_t o_w2r  = o_w1r + (size_t)9 * NCH * C1;         // 63,504
    size_t o_wdw  = o_w2r + (size_t)9 * C1 * C2;          // 14,161
    size_t total  = o_wdw + (size_t)49 * NCH;
    if (ws_size < total * sizeof(float)) return;          // workspace too small

    float* inv_norm = ws + o_norm;
    float* x1t = ws + o_x1t;
    float* x2t = ws + o_x2t;
    float* cv  = ws + o_cv;
    float* av  = ws + o_av;
    float* h1  = ws + o_h1;
    float* w1r = ws + o_w1r;
    float* w2r = ws + o_w2r;
    float* wdw = ws + o_wdw;

    // zero the padded x2 buffer (pad region must be 0)
    hipMemsetAsync(x2t, 0, (size_t)BS * PH * PW * C * sizeof(float), stream);

    norm_kernel<<<NPIX / 256, 256, 0, stream>>>(f1, inv_norm);
    transpose_kernel<<<4096, 256, 0, stream>>>(f1, x1t, inv_norm, 0);
    transpose_kernel<<<4096, 256, 0, stream>>>(f2, x2t, nullptr, 1);

    rearrange_w1<<<(C1 * NCH * 9 + 255) / 256, 256, 0, stream>>>(w1, w1r);
    rearrange_w2<<<(C2 * C1 * 9 + 255) / 256, 256, 0, stream>>>(w2, w2r);
    rearrange_dw<<<(NCH * 49 + 255) / 256, 256, 0, stream>>>(att_w, wdw);

    cv_kernel<<<1024, 256, 0, stream>>>(x1t, x2t, cv);
    dw_att_kernel<<<(NPIX * NCH + 255) / 256, 256, 0, stream>>>(cv, wdw, att_b, av);
    agg1_kernel<<<1024, 256, 0, stream>>>(av, w1r, b1, h1);
    agg2_kernel<<<1024, 256, 0, stream>>>(h1, w2r, b2, out);
}

// Round 3
// 1032.441 us; speedup vs baseline: 1.5931x; 1.5931x over previous
//
#include <hip/hip_runtime.h>
#include <hip/hip_bf16.h>

// Problem constants
#define BS   4
#define C    256
#define H_   64
#define W_   64
#define HW   4096          // 64*64
#define NPIX 16384         // 4*4096
#define NCH  289           // cost-volume channels (17*17)
#define MO   17
#define PH   80            // padded 64+2*8
#define PW   80
#define C1   144
#define C2   49
#define ASTR 264           // LDS row stride in bf16 elems (=8*33, breaks 512B banks)

typedef __bf16  bf16x8 __attribute__((ext_vector_type(8)));
typedef float   f32x4  __attribute__((ext_vector_type(4)));
typedef unsigned short us8 __attribute__((ext_vector_type(8)));

// ---------------------------------------------------------------------------
// K1: per-pixel inverse L2 norm over 256 channels of f1 (NCHW input)
__global__ void norm_kernel(const float* __restrict__ f1, float* __restrict__ inv_norm) {
    int p = blockIdx.x * 256 + threadIdx.x;     // 0..16383
    if (p >= NPIX) return;
    int b = p >> 12;
    int hw = p & 4095;
    const float* base = f1 + (size_t)b * C * HW + hw;
    float s = 0.f;
    for (int c = 0; c < C; ++c) {
        float v = base[(size_t)c * HW];
        s += v * v;
    }
    float n = sqrtf(s);
    inv_norm[p] = 1.0f / fmaxf(n, 1e-12f);
}

// ---------------------------------------------------------------------------
// K2: NCHW fp32 -> NHWC bf16 transpose.
//  padded=0: dst [BS,64,64,C] scaled by inv_norm.
//  padded=1: dst [BS,80,80,C] at +8 offset (pad pre-zeroed by memset).
__global__ void transpose_kernel(const float* __restrict__ src, unsigned short* __restrict__ dst,
                                 const float* __restrict__ inv_norm, int padded) {
    __shared__ float tile[32][33];
    int blk = blockIdx.x;                 // 4 * 8 * 128 = 4096 blocks
    int pblk = blk & 127;                 // HW/32
    int cblk = (blk >> 7) & 7;            // C/32
    int b    = blk >> 10;
    int tx = threadIdx.x & 31, ty = threadIdx.x >> 5;
    int c0 = cblk * 32, p0 = pblk * 32;
    const float* s = src + (size_t)b * C * HW;
#pragma unroll
    for (int i = 0; i < 4; ++i) {
        int c = c0 + ty + 8 * i;
        tile[ty + 8 * i][tx] = s[(size_t)c * HW + p0 + tx];
    }
    __syncthreads();
#pragma unroll
    for (int i = 0; i < 4; ++i) {
        int p = p0 + ty + 8 * i;
        float v = tile[tx][ty + 8 * i];
        int c = c0 + tx;
        if (!padded) {
            v *= inv_norm[b * HW + p];
            __hip_bfloat16 hb = __float2bfloat16(v);
            dst[((size_t)b * HW + p) * C + c] = *(unsigned short*)&hb;
        } else {
            int h = p >> 6, w = p & 63;
            __hip_bfloat16 hb = __float2bfloat16(v);
            dst[(((size_t)b * PH + h + 8) * PW + (w + 8)) * C + c] = *(unsigned short*)&hb;
        }
    }
}

// ---------------------------------------------------------------------------
// Weight rearrange kernels
__global__ void rearrange_w1(const float* __restrict__ w, float* __restrict__ wr) {
    // [144][289][3][3] OIHW -> [9][289][144]
    int idx = blockIdx.x * 256 + threadIdx.x;
    if (idx >= C1 * NCH * 9) return;
    int o = idx / (NCH * 9);
    int r = idx - o * (NCH * 9);
    int ci = r / 9;
    int kk = r - ci * 9;
    wr[((size_t)kk * NCH + ci) * C1 + o] = w[idx];
}
__global__ void rearrange_w2(const float* __restrict__ w, float* __restrict__ wr) {
    // [49][144][3][3] -> [9][144][49]
    int idx = blockIdx.x * 256 + threadIdx.x;
    if (idx >= C2 * C1 * 9) return;
    int o = idx / (C1 * 9);
    int r = idx - o * (C1 * 9);
    int ci = r / 9;
    int kk = r - ci * 9;
    wr[((size_t)kk * C1 + ci) * C2 + o] = w[idx];
}
__global__ void rearrange_dw(const float* __restrict__ w, float* __restrict__ wr) {
    // [289][1][7][7] -> [49][289]
    int idx = blockIdx.x * 256 + threadIdx.x;
    if (idx >= NCH * 49) return;
    int ch = idx / 49;
    int kk = idx - ch * 49;
    wr[kk * NCH + ch] = w[idx];
}

// ---------------------------------------------------------------------------
// K3: cost volume via bf16 MFMA.
// Block = (b, h, wseg): 32 px of one row. 512 blocks, 256 thr (4 waves).
// A = x1[32 px][256 ch] bf16 in LDS -> hoisted to regs (8 frags/wave).
// Per dj: B = x2pad row (h+dj), cols [w0..w0+47] in LDS; each wave does one
// 16x16 px-tile x col-tile GEMM (K=256 -> 8 mfma_f32_16x16x32_bf16).
// D layout: row(px) = quad*4+r, col = lane&15 -> di = col_l - px_l, keep 0..16.
__global__ void cv_mfma_kernel(const unsigned short* __restrict__ x1b,
                               const unsigned short* __restrict__ x2b,
                               float* __restrict__ cv) {
    __shared__ __align__(16) unsigned short x1s[32 * ASTR];
    __shared__ __align__(16) unsigned short x2s[48 * ASTR];
    int blk = blockIdx.x;                  // 512
    int wseg = blk & 1;
    int h = (blk >> 1) & 63;
    int b = blk >> 7;
    int w0 = wseg * 32;
    int t = threadIdx.x;

    // stage x1 tile: 32 px x 256 ch (us8 = 16B per store)
    const unsigned short* x1p = x1b + ((size_t)b * HW + h * 64 + w0) * C;
#pragma unroll
    for (int i = 0; i < 4; ++i) {
        int v = t + i * 256;               // 0..1023 vec8 index
        int px = v >> 5, ch8 = v & 31;
        *(us8*)&x1s[px * ASTR + ch8 * 8] = *(const us8*)&x1p[px * 256 + ch8 * 8];
    }
    __syncthreads();

    int wave = t >> 6, lane = t & 63;
    int pt = wave >> 1, ct = wave & 1;     // px-tile, col-tile
    int lrow = lane & 15, quad = lane >> 4;

    bf16x8 a[8];
#pragma unroll
    for (int kk = 0; kk < 8; ++kk)
        a[kk] = *(const bf16x8*)&x1s[(pt * 16 + lrow) * ASTR + kk * 32 + quad * 8];

    const unsigned short* x2base = x2b + (size_t)b * PH * PW * C;
    int col_l = ct * 16 + lrow;

    for (int dj = 0; dj < MO; ++dj) {
        __syncthreads();                   // protect x2s reuse
        const unsigned short* rowp = x2base + ((size_t)(h + dj) * PW + w0) * C;
#pragma unroll
        for (int i = 0; i < 6; ++i) {
            int v = t + i * 256;           // 0..1535 vec8 index
            int col = v >> 5, ch8 = v & 31;
            *(us8*)&x2s[col * ASTR + ch8 * 8] = *(const us8*)&rowp[col * 256 + ch8 * 8];
        }
        __syncthreads();

        f32x4 acc = {0.f, 0.f, 0.f, 0.f};
#pragma unroll
        for (int kk = 0; kk < 8; ++kk) {
            bf16x8 bb = *(const bf16x8*)&x2s[col_l * ASTR + kk * 32 + quad * 8];
            acc = __builtin_amdgcn_mfma_f32_16x16x32_bf16(a[kk], bb, acc, 0, 0, 0);
        }
#pragma unroll
        for (int r = 0; r < 4; ++r) {
            int px_l = pt * 16 + quad * 4 + r;
            int di = col_l - px_l;
            if ((unsigned)di <= 16u) {
                float v = acc[r] * (1.0f / 256.0f);
                cv[((size_t)b * HW + h * 64 + w0 + px_l) * NCH + dj * MO + di] =
                    (v > 0.f) ? v : 0.1f * v;
            }
        }
    }
}

// ---------------------------------------------------------------------------
// K4: depthwise 7x7 attention conv + elementwise multiply. cv/av are NHWC.
__global__ void dw_att_kernel(const float* __restrict__ cv, const float* __restrict__ wdw,
                              const float* __restrict__ att_b, float* __restrict__ av) {
    size_t tid = (size_t)blockIdx.x * 256 + threadIdx.x;
    if (tid >= (size_t)NPIX * NCH) return;
    int ch = (int)(tid % NCH);
    size_t pix = tid / NCH;
    int b = (int)(pix >> 12);
    int hw = (int)(pix & 4095);
    int h = hw >> 6, w = hw & 63;
    float acc = att_b[ch];
#pragma unroll
    for (int dy = 0; dy < 7; ++dy) {
        int y = h + dy - 3;
        if ((unsigned)y >= 64u) continue;
        const float* crow = cv + ((size_t)b * HW + y * 64) * NCH;
#pragma unroll
        for (int dx = 0; dx < 7; ++dx) {
            int x = w + dx - 3;
            if ((unsigned)x >= 64u) continue;
            acc += crow[(size_t)x * NCH + ch] * wdw[(dy * 7 + dx) * NCH + ch];
        }
    }
    float c0 = cv[pix * NCH + ch];
    av[pix * NCH + ch] = c0 * acc;
}

// ---------------------------------------------------------------------------
// K5: conv3x3 289->144 + ReLU. Block = 16 px * 144 out, 256 thr (9 acc each).
__global__ void agg1_kernel(const float* __restrict__ av, const float* __restrict__ wr,
                            const float* __restrict__ bias, float* __restrict__ h1) {
    __shared__ float wS[17 * 144];
    __shared__ float aS[17][16];
    int blk = blockIdx.x;
    int wseg = blk & 3;
    int h = (blk >> 2) & 63;
    int b = blk >> 8;
    int w0 = wseg * 16;
    int t = threadIdx.x;
    int px = t >> 4, og = t & 15;
    float acc[9];
#pragma unroll
    for (int j = 0; j < 9; ++j) acc[j] = bias[og + 16 * j];
    for (int k = 0; k < 9; ++k) {
        int dy = k / 3 - 1, dx = k % 3 - 1;
        int y = h + dy;
        const float* wkp = wr + (size_t)k * NCH * C1;
        for (int cc = 0; cc < NCH; cc += 17) {
            __syncthreads();
            for (int idx = t; idx < 17 * C1; idx += 256)
                wS[idx] = wkp[(size_t)cc * C1 + idx];
            for (int idx = t; idx < 17 * 16; idx += 256) {
                int aci = idx % 17, apx = idx / 17;
                int col = w0 + apx + dx;
                float v = 0.f;
                if ((unsigned)y < 64u && (unsigned)col < 64u)
                    v = av[(((size_t)b * HW) + y * 64 + col) * NCH + cc + aci];
                aS[aci][apx] = v;
            }
            __syncthreads();
#pragma unroll
            for (int ci = 0; ci < 17; ++ci) {
                float aval = aS[ci][px];
#pragma unroll
                for (int j = 0; j < 9; ++j)
                    acc[j] += aval * wS[ci * C1 + og + 16 * j];
            }
        }
    }
    size_t pix = (size_t)b * HW + h * 64 + w0 + px;
#pragma unroll
    for (int j = 0; j < 9; ++j)
        h1[pix * C1 + og + 16 * j] = fmaxf(acc[j], 0.f);
}

// ---------------------------------------------------------------------------
// K6: conv3x3 144->49 + ReLU, writes NCHW output.
__global__ void agg2_kernel(const float* __restrict__ h1, const float* __restrict__ wr,
                            const float* __restrict__ bias, float* __restrict__ out) {
    __shared__ float wS[16 * 49];
    __shared__ float aS[16][17];
    int blk = blockIdx.x;
    int wseg = blk & 3;
    int h = (blk >> 2) & 63;
    int b = blk >> 8;
    int w0 = wseg * 16;
    int t = threadIdx.x;
    int px = t >> 4, og = t & 15;
    float acc[4];
#pragma unroll
    for (int j = 0; j < 4; ++j) {
        int o = og + 16 * j;
        acc[j] = (o < C2) ? bias[o] : 0.f;
    }
    for (int k = 0; k < 9; ++k) {
        int dy = k / 3 - 1, dx = k % 3 - 1;
        int y = h + dy;
        int col = w0 + px + dx;
        for (int cc = 0; cc < C1; cc += 16) {
            __syncthreads();
            for (int idx = t; idx < 16 * C2; idx += 256)
                wS[idx] = wr[((size_t)k * C1 + cc) * C2 + idx];
            {
                float v = 0.f;
                if ((unsigned)y < 64u && (unsigned)col < 64u)
                    v = h1[(((size_t)b * HW) + y * 64 + col) * C1 + cc + og];
                aS[px][og] = v;
            }
            __syncthreads();
#pragma unroll
            for (int ci = 0; ci < 16; ++ci) {
                float aval = aS[px][ci];
#pragma unroll
                for (int j = 0; j < 4; ++j) {
                    int o = og + 16 * j;
                    if (o < C2) acc[j] += aval * wS[ci * C2 + o];
                }
            }
        }
    }
#pragma unroll
    for (int j = 0; j < 4; ++j) {
        int o = og + 16 * j;
        if (o < C2)
            out[(((size_t)b * C2 + o) * 64 + h) * 64 + w0 + px] = fmaxf(acc[j], 0.f);
    }
}

// ---------------------------------------------------------------------------
extern "C" void kernel_launch(void* const* d_in, const int* in_sizes, int n_in,
                              void* d_out, int out_size, void* d_ws, size_t ws_size,
                              hipStream_t stream) {
    const float* f1    = (const float*)d_in[0];
    const float* f2    = (const float*)d_in[1];
    const float* att_w = (const float*)d_in[2];
    const float* att_b = (const float*)d_in[3];
    const float* w1    = (const float*)d_in[4];
    const float* b1    = (const float*)d_in[5];
    const float* w2    = (const float*)d_in[6];
    const float* b2    = (const float*)d_in[7];
    float* out = (float*)d_out;

    // Workspace layout: float region, then bf16 (ushort) region.
    char* wsb = (char*)d_ws;
    size_t off = 0;
    float* inv_norm = (float*)(wsb + off); off += (size_t)NPIX * 4;
    float* cv  = (float*)(wsb + off); off += (size_t)NPIX * NCH * 4;
    float* av  = (float*)(wsb + off); off += (size_t)NPIX * NCH * 4;
    float* h1  = (float*)(wsb + off); off += (size_t)NPIX * C1 * 4;
    float* w1r = (float*)(wsb + off); off += (size_t)9 * NCH * C1 * 4;
    float* w2r = (float*)(wsb + off); off += (size_t)9 * C1 * C2 * 4;
    float* wdw = (float*)(wsb + off); off += (size_t)49 * NCH * 4;
    off = (off + 15) & ~(size_t)15;
    unsigned short* x1bf = (unsigned short*)(wsb + off); off += (size_t)NPIX * C * 2;
    unsigned short* x2bf = (unsigned short*)(wsb + off); off += (size_t)BS * PH * PW * C * 2;
    if (ws_size < off) return;

    // zero the padded x2 buffer (bf16 zero == 0x0000)
    hipMemsetAsync(x2bf, 0, (size_t)BS * PH * PW * C * 2, stream);

    norm_kernel<<<NPIX / 256, 256, 0, stream>>>(f1, inv_norm);
    transpose_kernel<<<4096, 256, 0, stream>>>(f1, x1bf, inv_norm, 0);
    transpose_kernel<<<4096, 256, 0, stream>>>(f2, x2bf, nullptr, 1);

    rearrange_w1<<<(C1 * NCH * 9 + 255) / 256, 256, 0, stream>>>(w1, w1r);
    rearrange_w2<<<(C2 * C1 * 9 + 255) / 256, 256, 0, stream>>>(w2, w2r);
    rearrange_dw<<<(NCH * 49 + 255) / 256, 256, 0, stream>>>(att_w, wdw);

    cv_mfma_kernel<<<512, 256, 0, stream>>>(x1bf, x2bf, cv);
    dw_att_kernel<<<(NPIX * NCH + 255) / 256, 256, 0, stream>>>(cv, wdw, att_b, av);
    agg1_kernel<<<1024, 256, 0, stream>>>(av, w1r, b1, h1);
    agg2_kernel<<<1024, 256, 0, stream>>>(h1, w2r, b2, out);
}

// Round 4
// 517.119 us; speedup vs baseline: 3.1806x; 1.9965x over previous
//
#include <hip/hip_runtime.h>
#include <hip/hip_bf16.h>

// Problem constants
#define BS   4
#define C    256
#define HW   4096          // 64*64
#define NPIX 16384         // 4*4096
#define NCH  289           // cost-volume channels (17*17)
#define MO   17
#define PH   80            // padded 64+2*8
#define PW   80
#define C1   144
#define C2   49
#define ASTR 264           // cv LDS row stride in bf16 elems
#define ICP  320           // agg1 padded input channels (289 -> 320)
#define A1STR 328          // agg1 A-slab LDS stride (320+8): 2-way banks
#define B1STR 40           // agg1 B LDS stride (32+8): 2-way banks

typedef __bf16  bf16x8 __attribute__((ext_vector_type(8)));
typedef float   f32x4  __attribute__((ext_vector_type(4)));
typedef unsigned short us8 __attribute__((ext_vector_type(8)));

// ---------------------------------------------------------------------------
// K1: per-pixel inverse L2 norm over 256 channels of f1 (NCHW input)
__global__ void norm_kernel(const float* __restrict__ f1, float* __restrict__ inv_norm) {
    int p = blockIdx.x * 256 + threadIdx.x;     // 0..16383
    if (p >= NPIX) return;
    int b = p >> 12;
    int hw = p & 4095;
    const float* base = f1 + (size_t)b * C * HW + hw;
    float s = 0.f;
    for (int c = 0; c < C; ++c) {
        float v = base[(size_t)c * HW];
        s += v * v;
    }
    float n = sqrtf(s);
    inv_norm[p] = 1.0f / fmaxf(n, 1e-12f);
}

// ---------------------------------------------------------------------------
// K2: NCHW fp32 -> NHWC bf16 transpose.
__global__ void transpose_kernel(const float* __restrict__ src, unsigned short* __restrict__ dst,
                                 const float* __restrict__ inv_norm, int padded) {
    __shared__ float tile[32][33];
    int blk = blockIdx.x;                 // 4096 blocks
    int pblk = blk & 127;
    int cblk = (blk >> 7) & 7;
    int b    = blk >> 10;
    int tx = threadIdx.x & 31, ty = threadIdx.x >> 5;
    int c0 = cblk * 32, p0 = pblk * 32;
    const float* s = src + (size_t)b * C * HW;
#pragma unroll
    for (int i = 0; i < 4; ++i) {
        int c = c0 + ty + 8 * i;
        tile[ty + 8 * i][tx] = s[(size_t)c * HW + p0 + tx];
    }
    __syncthreads();
#pragma unroll
    for (int i = 0; i < 4; ++i) {
        int p = p0 + ty + 8 * i;
        float v = tile[tx][ty + 8 * i];
        int c = c0 + tx;
        if (!padded) {
            v *= inv_norm[b * HW + p];
            __hip_bfloat16 hb = __float2bfloat16(v);
            dst[((size_t)b * HW + p) * C + c] = *(unsigned short*)&hb;
        } else {
            int h = p >> 6, w = p & 63;
            __hip_bfloat16 hb = __float2bfloat16(v);
            dst[(((size_t)b * PH + h + 8) * PW + (w + 8)) * C + c] = *(unsigned short*)&hb;
        }
    }
}

// ---------------------------------------------------------------------------
// Weight rearrange kernels
__global__ void rearrange_w1_bf(const float* __restrict__ w, unsigned short* __restrict__ wb) {
    // OIHW [144][289][3][3] -> bf16 [9][144][320] (ic zero-padded)
    int idx = blockIdx.x * 256 + threadIdx.x;
    if (idx >= 9 * C1 * ICP) return;
    int tap = idx / (C1 * ICP);
    int r = idx - tap * (C1 * ICP);
    int oc = r / ICP;
    int ic = r - oc * ICP;
    float v = (ic < NCH) ? w[((size_t)(oc * NCH + ic)) * 9 + tap] : 0.f;
    __hip_bfloat16 hb = __float2bfloat16(v);
    wb[idx] = *(unsigned short*)&hb;
}
__global__ void rearrange_w2(const float* __restrict__ w, float* __restrict__ wr) {
    // [49][144][3][3] -> [9][144][49]
    int idx = blockIdx.x * 256 + threadIdx.x;
    if (idx >= C2 * C1 * 9) return;
    int o = idx / (C1 * 9);
    int r = idx - o * (C1 * 9);
    int ci = r / 9;
    int kk = r - ci * 9;
    wr[((size_t)kk * C1 + ci) * C2 + o] = w[idx];
}
__global__ void rearrange_dw(const float* __restrict__ w, float* __restrict__ wr) {
    // [289][1][7][7] -> [49][289]
    int idx = blockIdx.x * 256 + threadIdx.x;
    if (idx >= NCH * 49) return;
    int ch = idx / 49;
    int kk = idx - ch * 49;
    wr[kk * NCH + ch] = w[idx];
}

// ---------------------------------------------------------------------------
// K3: cost volume via bf16 MFMA (unchanged from round 3).
__global__ void cv_mfma_kernel(const unsigned short* __restrict__ x1b,
                               const unsigned short* __restrict__ x2b,
                               float* __restrict__ cv) {
    __shared__ __align__(16) unsigned short x1s[32 * ASTR];
    __shared__ __align__(16) unsigned short x2s[48 * ASTR];
    int blk = blockIdx.x;                  // 512
    int wseg = blk & 1;
    int h = (blk >> 1) & 63;
    int b = blk >> 7;
    int w0 = wseg * 32;
    int t = threadIdx.x;

    const unsigned short* x1p = x1b + ((size_t)b * HW + h * 64 + w0) * C;
#pragma unroll
    for (int i = 0; i < 4; ++i) {
        int v = t + i * 256;
        int px = v >> 5, ch8 = v & 31;
        *(us8*)&x1s[px * ASTR + ch8 * 8] = *(const us8*)&x1p[px * 256 + ch8 * 8];
    }
    __syncthreads();

    int wave = t >> 6, lane = t & 63;
    int pt = wave >> 1, ct = wave & 1;
    int lrow = lane & 15, quad = lane >> 4;

    bf16x8 a[8];
#pragma unroll
    for (int kk = 0; kk < 8; ++kk)
        a[kk] = *(const bf16x8*)&x1s[(pt * 16 + lrow) * ASTR + kk * 32 + quad * 8];

    const unsigned short* x2base = x2b + (size_t)b * PH * PW * C;
    int col_l = ct * 16 + lrow;

    for (int dj = 0; dj < MO; ++dj) {
        __syncthreads();
        const unsigned short* rowp = x2base + ((size_t)(h + dj) * PW + w0) * C;
#pragma unroll
        for (int i = 0; i < 6; ++i) {
            int v = t + i * 256;
            int col = v >> 5, ch8 = v & 31;
            *(us8*)&x2s[col * ASTR + ch8 * 8] = *(const us8*)&rowp[col * 256 + ch8 * 8];
        }
        __syncthreads();

        f32x4 acc = {0.f, 0.f, 0.f, 0.f};
#pragma unroll
        for (int kk = 0; kk < 8; ++kk) {
            bf16x8 bb = *(const bf16x8*)&x2s[col_l * ASTR + kk * 32 + quad * 8];
            acc = __builtin_amdgcn_mfma_f32_16x16x32_bf16(a[kk], bb, acc, 0, 0, 0);
        }
#pragma unroll
        for (int r = 0; r < 4; ++r) {
            int px_l = pt * 16 + quad * 4 + r;
            int di = col_l - px_l;
            if ((unsigned)di <= 16u) {
                float v = acc[r] * (1.0f / 256.0f);
                cv[((size_t)b * HW + h * 64 + w0 + px_l) * NCH + dj * MO + di] =
                    (v > 0.f) ? v : 0.1f * v;
            }
        }
    }
}

// ---------------------------------------------------------------------------
// K4: depthwise 7x7 attention conv + multiply. Reads cv fp32 NHWC;
// writes bf16 into zero-padded av_pad [BS][66][66][320].
__global__ void dw_att_kernel(const float* __restrict__ cv, const float* __restrict__ wdw,
                              const float* __restrict__ att_b, unsigned short* __restrict__ av_pad) {
    size_t tid = (size_t)blockIdx.x * 256 + threadIdx.x;
    if (tid >= (size_t)NPIX * NCH) return;
    int ch = (int)(tid % NCH);
    size_t pix = tid / NCH;
    int b = (int)(pix >> 12);
    int hw = (int)(pix & 4095);
    int h = hw >> 6, w = hw & 63;
    float acc = att_b[ch];
#pragma unroll
    for (int dy = 0; dy < 7; ++dy) {
        int y = h + dy - 3;
        if ((unsigned)y >= 64u) continue;
        const float* crow = cv + ((size_t)b * HW + y * 64) * NCH;
#pragma unroll
        for (int dx = 0; dx < 7; ++dx) {
            int x = w + dx - 3;
            if ((unsigned)x >= 64u) continue;
            acc += crow[(size_t)x * NCH + ch] * wdw[(dy * 7 + dx) * NCH + ch];
        }
    }
    float c0 = cv[pix * NCH + ch];
    __hip_bfloat16 hb = __float2bfloat16(c0 * acc);
    av_pad[(((size_t)b * 66 + h + 1) * 66 + (w + 1)) * ICP + ch] = *(unsigned short*)&hb;
}

// ---------------------------------------------------------------------------
// K5: conv3x3 289->144 + ReLU via bf16 MFMA (implicit GEMM).
// Block = one row (b,h): 64 px x 144 oc. 4 waves = 4 px-tiles of 16.
// Each wave: 9 oc-tiles (full 144) -> 9 f32x4 accs.
// K = 9 taps x 320 ch. A-slab (row h+dy, 66 cols x 320 ch) staged per dy;
// B chunk (144 oc x 32 ch of tap) staged per (dy,dx,cc).
__global__ void agg1_mfma_kernel(const unsigned short* __restrict__ av_pad,
                                 const unsigned short* __restrict__ wb1,
                                 const float* __restrict__ bias, float* __restrict__ h1) {
    __shared__ __align__(16) unsigned short aS[66 * A1STR];   // 43.3 KB
    __shared__ __align__(16) unsigned short bS[C1 * B1STR];   // 11.5 KB
    int blk = blockIdx.x;                  // 256
    int h = blk & 63;
    int b = blk >> 6;
    int t = threadIdx.x;
    int wave = t >> 6, lane = t & 63;
    int lrow = lane & 15, quad = lane >> 4;
    int pt = wave;                         // px-tile (16 px)

    f32x4 acc[9];
#pragma unroll
    for (int ot = 0; ot < 9; ++ot) acc[ot] = (f32x4){0.f, 0.f, 0.f, 0.f};

    const unsigned short* avb = av_pad + (((size_t)b * 66 + h) * 66) * ICP;

    for (int dy = 0; dy < 3; ++dy) {
        __syncthreads();                   // protect aS+bS from previous step readers
        // stage A: row (h+dy) of av_pad: 66 cols x 320 ch = 2640 us8 chunks
        const unsigned short* arow = avb + (size_t)dy * 66 * ICP;
        for (int v = t; v < 66 * (ICP / 8); v += 256) {
            int col = v / (ICP / 8);
            int c8 = v - col * (ICP / 8);
            *(us8*)&aS[col * A1STR + c8 * 8] = *(const us8*)&arow[col * ICP + c8 * 8];
        }
        for (int dx = 0; dx < 3; ++dx) {
            int tap = dy * 3 + dx;
            const unsigned short* wtap = wb1 + (size_t)tap * C1 * ICP;
            for (int cc = 0; cc < ICP; cc += 32) {
                if (!(dx == 0 && cc == 0)) {
                    // stage B for this (tap, cc): 144 oc x 32 ch = 576 us8
                    for (int v = t; v < C1 * 4; v += 256) {
                        int oc = v >> 2, c8 = v & 3;
                        *(us8*)&bS[oc * B1STR + c8 * 8] =
                            *(const us8*)&wtap[(size_t)oc * ICP + cc + c8 * 8];
                    }
                } else {
                    // first step of this dy: stage B concurrently with A
                    for (int v = t; v < C1 * 4; v += 256) {
                        int oc = v >> 2, c8 = v & 3;
                        *(us8*)&bS[oc * B1STR + c8 * 8] =
                            *(const us8*)&wtap[(size_t)oc * ICP + c8 * 8];
                    }
                }
                __syncthreads();
                // A-frag: px m = pt*16+lrow, slab col = px + dx, k = quad*8+j
                bf16x8 af = *(const bf16x8*)&aS[(pt * 16 + lrow + dx) * A1STR + cc + quad * 8];
#pragma unroll
                for (int ot = 0; ot < 9; ++ot) {
                    bf16x8 bf = *(const bf16x8*)&bS[(ot * 16 + lrow) * B1STR + quad * 8];
                    acc[ot] = __builtin_amdgcn_mfma_f32_16x16x32_bf16(af, bf, acc[ot], 0, 0, 0);
                }
                __syncthreads();           // before next B stage overwrites
            }
        }
    }

    // epilogue: bias + ReLU, h1[pix][144] fp32
    size_t pixbase = (size_t)b * HW + h * 64 + pt * 16;
#pragma unroll
    for (int ot = 0; ot < 9; ++ot) {
        int oc = ot * 16 + lrow;
        float bv = bias[oc];
#pragma unroll
        for (int r = 0; r < 4; ++r) {
            int px_l = quad * 4 + r;
            h1[(pixbase + px_l) * C1 + oc] = fmaxf(acc[ot][r] + bv, 0.f);
        }
    }
}

// ---------------------------------------------------------------------------
// K6: conv3x3 144->49 + ReLU, writes NCHW output (unchanged).
__global__ void agg2_kernel(const float* __restrict__ h1, const float* __restrict__ wr,
                            const float* __restrict__ bias, float* __restrict__ out) {
    __shared__ float wS[16 * 49];
    __shared__ float aS2[16][17];
    int blk = blockIdx.x;
    int wseg = blk & 3;
    int h = (blk >> 2) & 63;
    int b = blk >> 8;
    int w0 = wseg * 16;
    int t = threadIdx.x;
    int px = t >> 4, og = t & 15;
    float acc[4];
#pragma unroll
    for (int j = 0; j < 4; ++j) {
        int o = og + 16 * j;
        acc[j] = (o < C2) ? bias[o] : 0.f;
    }
    for (int k = 0; k < 9; ++k) {
        int dy = k / 3 - 1, dx = k % 3 - 1;
        int y = h + dy;
        int col = w0 + px + dx;
        for (int cc = 0; cc < C1; cc += 16) {
            __syncthreads();
            for (int idx = t; idx < 16 * C2; idx += 256)
                wS[idx] = wr[((size_t)k * C1 + cc) * C2 + idx];
            {
                float v = 0.f;
                if ((unsigned)y < 64u && (unsigned)col < 64u)
                    v = h1[(((size_t)b * HW) + y * 64 + col) * C1 + cc + og];
                aS2[px][og] = v;
            }
            __syncthreads();
#pragma unroll
            for (int ci = 0; ci < 16; ++ci) {
                float aval = aS2[px][ci];
#pragma unroll
                for (int j = 0; j < 4; ++j) {
                    int o = og + 16 * j;
                    if (o < C2) acc[j] += aval * wS[ci * C2 + o];
                }
            }
        }
    }
#pragma unroll
    for (int j = 0; j < 4; ++j) {
        int o = og + 16 * j;
        if (o < C2)
            out[(((size_t)b * C2 + o) * 64 + h) * 64 + w0 + px] = fmaxf(acc[j], 0.f);
    }
}

// ---------------------------------------------------------------------------
extern "C" void kernel_launch(void* const* d_in, const int* in_sizes, int n_in,
                              void* d_out, int out_size, void* d_ws, size_t ws_size,
                              hipStream_t stream) {
    const float* f1    = (const float*)d_in[0];
    const float* f2    = (const float*)d_in[1];
    const float* att_w = (const float*)d_in[2];
    const float* att_b = (const float*)d_in[3];
    const float* w1    = (const float*)d_in[4];
    const float* b1    = (const float*)d_in[5];
    const float* w2    = (const float*)d_in[6];
    const float* b2    = (const float*)d_in[7];
    float* out = (float*)d_out;

    char* wsb = (char*)d_ws;
    size_t off = 0;
    float* inv_norm = (float*)(wsb + off); off += (size_t)NPIX * 4;
    float* cv  = (float*)(wsb + off); off += (size_t)NPIX * NCH * 4;
    float* h1  = (float*)(wsb + off); off += (size_t)NPIX * C1 * 4;
    float* w2r = (float*)(wsb + off); off += (size_t)9 * C1 * C2 * 4;
    float* wdw = (float*)(wsb + off); off += (size_t)49 * NCH * 4;
    off = (off + 15) & ~(size_t)15;
    unsigned short* x1bf = (unsigned short*)(wsb + off); off += (size_t)NPIX * C * 2;
    unsigned short* x2bf = (unsigned short*)(wsb + off); off += (size_t)BS * PH * PW * C * 2;
    unsigned short* avp  = (unsigned short*)(wsb + off); off += (size_t)BS * 66 * 66 * ICP * 2;
    unsigned short* wb1  = (unsigned short*)(wsb + off); off += (size_t)9 * C1 * ICP * 2;
    if (ws_size < off) return;

    hipMemsetAsync(x2bf, 0, (size_t)BS * PH * PW * C * 2, stream);
    hipMemsetAsync(avp, 0, (size_t)BS * 66 * 66 * ICP * 2, stream);

    norm_kernel<<<NPIX / 256, 256, 0, stream>>>(f1, inv_norm);
    transpose_kernel<<<4096, 256, 0, stream>>>(f1, x1bf, inv_norm, 0);
    transpose_kernel<<<4096, 256, 0, stream>>>(f2, x2bf, nullptr, 1);

    rearrange_w1_bf<<<(9 * C1 * ICP + 255) / 256, 256, 0, stream>>>(w1, wb1);
    rearrange_w2<<<(C2 * C1 * 9 + 255) / 256, 256, 0, stream>>>(w2, w2r);
    rearrange_dw<<<(NCH * 49 + 255) / 256, 256, 0, stream>>>(att_w, wdw);

    cv_mfma_kernel<<<512, 256, 0, stream>>>(x1bf, x2bf, cv);
    dw_att_kernel<<<(NPIX * NCH + 255) / 256, 256, 0, stream>>>(cv, wdw, att_b, avp);
    agg1_mfma_kernel<<<256, 256, 0, stream>>>(avp, wb1, b1, h1);
    agg2_kernel<<<1024, 256, 0, stream>>>(h1, w2r, b2, out);
}

// Round 5
// 390.272 us; speedup vs baseline: 4.2144x; 1.3250x over previous
//
#include <hip/hip_runtime.h>
#include <hip/hip_bf16.h>

// Problem constants
#define BS   4
#define C    256
#define HW   4096          // 64*64
#define NPIX 16384         // 4*4096
#define NCH  289           // cost-volume channels (17*17)
#define MO   17
#define PH   80            // padded 64+2*8
#define PW   80
#define C1   144
#define C2   49
#define ASTR 264           // cv LDS row stride in bf16 elems
#define ICP  320           // agg1 padded input channels (289 -> 320)
#define A1STR 328          // agg1 A-slab LDS stride
#define B1STR 40           // agg1 B LDS stride
#define IC2  160           // agg2 padded input channels (144 -> 160)
#define A2STR 168          // agg2 LDS row stride (160+8), 16B-aligned rows

typedef __bf16  bf16x8 __attribute__((ext_vector_type(8)));
typedef float   f32x4  __attribute__((ext_vector_type(4)));
typedef unsigned short us8 __attribute__((ext_vector_type(8)));

// ---------------------------------------------------------------------------
// K1: per-pixel inverse L2 norm over 256 channels of f1 (NCHW input)
__global__ void norm_kernel(const float* __restrict__ f1, float* __restrict__ inv_norm) {
    int p = blockIdx.x * 256 + threadIdx.x;     // 0..16383
    if (p >= NPIX) return;
    int b = p >> 12;
    int hw = p & 4095;
    const float* base = f1 + (size_t)b * C * HW + hw;
    float s = 0.f;
    for (int c = 0; c < C; ++c) {
        float v = base[(size_t)c * HW];
        s += v * v;
    }
    float n = sqrtf(s);
    inv_norm[p] = 1.0f / fmaxf(n, 1e-12f);
}

// ---------------------------------------------------------------------------
// K2: NCHW fp32 -> NHWC bf16 transpose.
__global__ void transpose_kernel(const float* __restrict__ src, unsigned short* __restrict__ dst,
                                 const float* __restrict__ inv_norm, int padded) {
    __shared__ float tile[32][33];
    int blk = blockIdx.x;                 // 4096 blocks
    int pblk = blk & 127;
    int cblk = (blk >> 7) & 7;
    int b    = blk >> 10;
    int tx = threadIdx.x & 31, ty = threadIdx.x >> 5;
    int c0 = cblk * 32, p0 = pblk * 32;
    const float* s = src + (size_t)b * C * HW;
#pragma unroll
    for (int i = 0; i < 4; ++i) {
        int c = c0 + ty + 8 * i;
        tile[ty + 8 * i][tx] = s[(size_t)c * HW + p0 + tx];
    }
    __syncthreads();
#pragma unroll
    for (int i = 0; i < 4; ++i) {
        int p = p0 + ty + 8 * i;
        float v = tile[tx][ty + 8 * i];
        int c = c0 + tx;
        if (!padded) {
            v *= inv_norm[b * HW + p];
            __hip_bfloat16 hb = __float2bfloat16(v);
            dst[((size_t)b * HW + p) * C + c] = *(unsigned short*)&hb;
        } else {
            int h = p >> 6, w = p & 63;
            __hip_bfloat16 hb = __float2bfloat16(v);
            dst[(((size_t)b * PH + h + 8) * PW + (w + 8)) * C + c] = *(unsigned short*)&hb;
        }
    }
}

// ---------------------------------------------------------------------------
// Weight rearrange kernels
__global__ void rearrange_w1_bf(const float* __restrict__ w, unsigned short* __restrict__ wb) {
    // OIHW [144][289][3][3] -> bf16 [9][144][320] (ic zero-padded)
    int idx = blockIdx.x * 256 + threadIdx.x;
    if (idx >= 9 * C1 * ICP) return;
    int tap = idx / (C1 * ICP);
    int r = idx - tap * (C1 * ICP);
    int oc = r / ICP;
    int ic = r - oc * ICP;
    float v = (ic < NCH) ? w[((size_t)(oc * NCH + ic)) * 9 + tap] : 0.f;
    __hip_bfloat16 hb = __float2bfloat16(v);
    wb[idx] = *(unsigned short*)&hb;
}
__global__ void rearrange_w2_bf(const float* __restrict__ w, unsigned short* __restrict__ wb) {
    // OIHW [49][144][3][3] -> bf16 [9][64][160] (oc + ic zero-padded)
    int idx = blockIdx.x * 256 + threadIdx.x;
    if (idx >= 9 * 64 * IC2) return;
    int tap = idx / (64 * IC2);
    int r = idx - tap * (64 * IC2);
    int oc = r / IC2;
    int ic = r - oc * IC2;
    float v = (oc < C2 && ic < C1) ? w[((size_t)(oc * C1 + ic)) * 9 + tap] : 0.f;
    __hip_bfloat16 hb = __float2bfloat16(v);
    wb[idx] = *(unsigned short*)&hb;
}
__global__ void rearrange_dw(const float* __restrict__ w, float* __restrict__ wr) {
    // [289][1][7][7] -> [49][289]
    int idx = blockIdx.x * 256 + threadIdx.x;
    if (idx >= NCH * 49) return;
    int ch = idx / 49;
    int kk = idx - ch * 49;
    wr[kk * NCH + ch] = w[idx];
}

// ---------------------------------------------------------------------------
// K3: cost volume via bf16 MFMA (unchanged).
__global__ void cv_mfma_kernel(const unsigned short* __restrict__ x1b,
                               const unsigned short* __restrict__ x2b,
                               float* __restrict__ cv) {
    __shared__ __align__(16) unsigned short x1s[32 * ASTR];
    __shared__ __align__(16) unsigned short x2s[48 * ASTR];
    int blk = blockIdx.x;                  // 512
    int wseg = blk & 1;
    int h = (blk >> 1) & 63;
    int b = blk >> 7;
    int w0 = wseg * 32;
    int t = threadIdx.x;

    const unsigned short* x1p = x1b + ((size_t)b * HW + h * 64 + w0) * C;
#pragma unroll
    for (int i = 0; i < 4; ++i) {
        int v = t + i * 256;
        int px = v >> 5, ch8 = v & 31;
        *(us8*)&x1s[px * ASTR + ch8 * 8] = *(const us8*)&x1p[px * 256 + ch8 * 8];
    }
    __syncthreads();

    int wave = t >> 6, lane = t & 63;
    int pt = wave >> 1, ct = wave & 1;
    int lrow = lane & 15, quad = lane >> 4;

    bf16x8 a[8];
#pragma unroll
    for (int kk = 0; kk < 8; ++kk)
        a[kk] = *(const bf16x8*)&x1s[(pt * 16 + lrow) * ASTR + kk * 32 + quad * 8];

    const unsigned short* x2base = x2b + (size_t)b * PH * PW * C;
    int col_l = ct * 16 + lrow;

    for (int dj = 0; dj < MO; ++dj) {
        __syncthreads();
        const unsigned short* rowp = x2base + ((size_t)(h + dj) * PW + w0) * C;
#pragma unroll
        for (int i = 0; i < 6; ++i) {
            int v = t + i * 256;
            int col = v >> 5, ch8 = v & 31;
            *(us8*)&x2s[col * ASTR + ch8 * 8] = *(const us8*)&rowp[col * 256 + ch8 * 8];
        }
        __syncthreads();

        f32x4 acc = {0.f, 0.f, 0.f, 0.f};
#pragma unroll
        for (int kk = 0; kk < 8; ++kk) {
            bf16x8 bb = *(const bf16x8*)&x2s[col_l * ASTR + kk * 32 + quad * 8];
            acc = __builtin_amdgcn_mfma_f32_16x16x32_bf16(a[kk], bb, acc, 0, 0, 0);
        }
#pragma unroll
        for (int r = 0; r < 4; ++r) {
            int px_l = pt * 16 + quad * 4 + r;
            int di = col_l - px_l;
            if ((unsigned)di <= 16u) {
                float v = acc[r] * (1.0f / 256.0f);
                cv[((size_t)b * HW + h * 64 + w0 + px_l) * NCH + dj * MO + di] =
                    (v > 0.f) ? v : 0.1f * v;
            }
        }
    }
}

// ---------------------------------------------------------------------------
// K4: depthwise 7x7 attention conv + multiply -> bf16 av_pad [BS][66][66][320].
__global__ void dw_att_kernel(const float* __restrict__ cv, const float* __restrict__ wdw,
                              const float* __restrict__ att_b, unsigned short* __restrict__ av_pad) {
    size_t tid = (size_t)blockIdx.x * 256 + threadIdx.x;
    if (tid >= (size_t)NPIX * NCH) return;
    int ch = (int)(tid % NCH);
    size_t pix = tid / NCH;
    int b = (int)(pix >> 12);
    int hw = (int)(pix & 4095);
    int h = hw >> 6, w = hw & 63;
    float acc = att_b[ch];
#pragma unroll
    for (int dy = 0; dy < 7; ++dy) {
        int y = h + dy - 3;
        if ((unsigned)y >= 64u) continue;
        const float* crow = cv + ((size_t)b * HW + y * 64) * NCH;
#pragma unroll
        for (int dx = 0; dx < 7; ++dx) {
            int x = w + dx - 3;
            if ((unsigned)x >= 64u) continue;
            acc += crow[(size_t)x * NCH + ch] * wdw[(dy * 7 + dx) * NCH + ch];
        }
    }
    float c0 = cv[pix * NCH + ch];
    __hip_bfloat16 hb = __float2bfloat16(c0 * acc);
    av_pad[(((size_t)b * 66 + h + 1) * 66 + (w + 1)) * ICP + ch] = *(unsigned short*)&hb;
}

// ---------------------------------------------------------------------------
// K5: conv3x3 289->144 + ReLU via bf16 MFMA. Writes bf16 into padded
// h1p [BS][66][66][160] (halo + ch-pad pre-zeroed).
__global__ void agg1_mfma_kernel(const unsigned short* __restrict__ av_pad,
                                 const unsigned short* __restrict__ wb1,
                                 const float* __restrict__ bias, unsigned short* __restrict__ h1p) {
    __shared__ __align__(16) unsigned short aS[66 * A1STR];   // 43.3 KB
    __shared__ __align__(16) unsigned short bS[C1 * B1STR];   // 11.5 KB
    int blk = blockIdx.x;                  // 256
    int h = blk & 63;
    int b = blk >> 6;
    int t = threadIdx.x;
    int wave = t >> 6, lane = t & 63;
    int lrow = lane & 15, quad = lane >> 4;
    int pt = wave;

    f32x4 acc[9];
#pragma unroll
    for (int ot = 0; ot < 9; ++ot) acc[ot] = (f32x4){0.f, 0.f, 0.f, 0.f};

    const unsigned short* avb = av_pad + (((size_t)b * 66 + h) * 66) * ICP;

    for (int dy = 0; dy < 3; ++dy) {
        __syncthreads();
        const unsigned short* arow = avb + (size_t)dy * 66 * ICP;
        for (int v = t; v < 66 * (ICP / 8); v += 256) {
            int col = v / (ICP / 8);
            int c8 = v - col * (ICP / 8);
            *(us8*)&aS[col * A1STR + c8 * 8] = *(const us8*)&arow[col * ICP + c8 * 8];
        }
        for (int dx = 0; dx < 3; ++dx) {
            int tap = dy * 3 + dx;
            const unsigned short* wtap = wb1 + (size_t)tap * C1 * ICP;
            for (int cc = 0; cc < ICP; cc += 32) {
                if (!(dx == 0 && cc == 0)) {
                    for (int v = t; v < C1 * 4; v += 256) {
                        int oc = v >> 2, c8 = v & 3;
                        *(us8*)&bS[oc * B1STR + c8 * 8] =
                            *(const us8*)&wtap[(size_t)oc * ICP + cc + c8 * 8];
                    }
                } else {
                    for (int v = t; v < C1 * 4; v += 256) {
                        int oc = v >> 2, c8 = v & 3;
                        *(us8*)&bS[oc * B1STR + c8 * 8] =
                            *(const us8*)&wtap[(size_t)oc * ICP + c8 * 8];
                    }
                }
                __syncthreads();
                bf16x8 af = *(const bf16x8*)&aS[(pt * 16 + lrow + dx) * A1STR + cc + quad * 8];
#pragma unroll
                for (int ot = 0; ot < 9; ++ot) {
                    bf16x8 bf = *(const bf16x8*)&bS[(ot * 16 + lrow) * B1STR + quad * 8];
                    acc[ot] = __builtin_amdgcn_mfma_f32_16x16x32_bf16(af, bf, acc[ot], 0, 0, 0);
                }
                __syncthreads();
            }
        }
    }

    // epilogue: bias + ReLU -> bf16 h1p at (h+1, w+1)
#pragma unroll
    for (int ot = 0; ot < 9; ++ot) {
        int oc = ot * 16 + lrow;
        float bv = bias[oc];
#pragma unroll
        for (int r = 0; r < 4; ++r) {
            int w = pt * 16 + quad * 4 + r;
            float val = fmaxf(acc[ot][r] + bv, 0.f);
            __hip_bfloat16 hb = __float2bfloat16(val);
            h1p[(((size_t)b * 66 + h + 1) * 66 + (w + 1)) * IC2 + oc] = *(unsigned short*)&hb;
        }
    }
}

// ---------------------------------------------------------------------------
// K6: conv3x3 144->49 + ReLU via bf16 MFMA, writes NCHW fp32 output.
// Block = one row (b,h): 64 px. 4 waves = 4 px-tiles; acc[4] = oc 0..63 (49 real).
// K = 9 taps x 160 ch. A-slab staged per dy; full B tap-slab staged per tap.
__global__ void agg2_mfma_kernel(const unsigned short* __restrict__ h1p,
                                 const unsigned short* __restrict__ wb2,
                                 const float* __restrict__ bias, float* __restrict__ out) {
    __shared__ __align__(16) unsigned short aS[66 * A2STR];   // 22.2 KB
    __shared__ __align__(16) unsigned short bS[64 * A2STR];   // 21.5 KB
    int blk = blockIdx.x;                  // 256
    int h = blk & 63;
    int b = blk >> 6;
    int t = threadIdx.x;
    int wave = t >> 6, lane = t & 63;
    int lrow = lane & 15, quad = lane >> 4;
    int pt = wave;

    f32x4 acc[4];
#pragma unroll
    for (int ot = 0; ot < 4; ++ot) acc[ot] = (f32x4){0.f, 0.f, 0.f, 0.f};

    const unsigned short* h1b = h1p + (((size_t)b * 66 + h) * 66) * IC2;

    for (int dy = 0; dy < 3; ++dy) {
        __syncthreads();                   // all waves done with aS+bS
        const unsigned short* arow = h1b + (size_t)dy * 66 * IC2;
        for (int v = t; v < 66 * (IC2 / 8); v += 256) {
            int col = v / (IC2 / 8);
            int c8 = v - col * (IC2 / 8);
            *(us8*)&aS[col * A2STR + c8 * 8] = *(const us8*)&arow[col * IC2 + c8 * 8];
        }
        for (int dx = 0; dx < 3; ++dx) {
            int tap = dy * 3 + dx;
            if (dx != 0) __syncthreads();  // prior MFMA reads of bS done
            const unsigned short* wtap = wb2 + (size_t)tap * 64 * IC2;
            for (int v = t; v < 64 * (IC2 / 8); v += 256) {
                int oc = v / (IC2 / 8);
                int c8 = v - oc * (IC2 / 8);
                *(us8*)&bS[oc * A2STR + c8 * 8] = *(const us8*)&wtap[(size_t)oc * IC2 + c8 * 8];
            }
            __syncthreads();               // staging visible
#pragma unroll
            for (int cc = 0; cc < 5; ++cc) {
                bf16x8 af = *(const bf16x8*)&aS[(pt * 16 + lrow + dx) * A2STR + cc * 32 + quad * 8];
#pragma unroll
                for (int ot = 0; ot < 4; ++ot) {
                    bf16x8 bf = *(const bf16x8*)&bS[(ot * 16 + lrow) * A2STR + cc * 32 + quad * 8];
                    acc[ot] = __builtin_amdgcn_mfma_f32_16x16x32_bf16(af, bf, acc[ot], 0, 0, 0);
                }
            }
        }
    }

    // epilogue: bias + ReLU -> NCHW fp32 out, oc < 49 only
#pragma unroll
    for (int ot = 0; ot < 4; ++ot) {
        int o = ot * 16 + lrow;
        if (o < C2) {
            float bv = bias[o];
#pragma unroll
            for (int r = 0; r < 4; ++r) {
                int w = pt * 16 + quad * 4 + r;
                out[((size_t)b * C2 + o) * HW + h * 64 + w] = fmaxf(acc[ot][r] + bv, 0.f);
            }
        }
    }
}

// ---------------------------------------------------------------------------
extern "C" void kernel_launch(void* const* d_in, const int* in_sizes, int n_in,
                              void* d_out, int out_size, void* d_ws, size_t ws_size,
                              hipStream_t stream) {
    const float* f1    = (const float*)d_in[0];
    const float* f2    = (const float*)d_in[1];
    const float* att_w = (const float*)d_in[2];
    const float* att_b = (const float*)d_in[3];
    const float* w1    = (const float*)d_in[4];
    const float* b1    = (const float*)d_in[5];
    const float* w2    = (const float*)d_in[6];
    const float* b2    = (const float*)d_in[7];
    float* out = (float*)d_out;

    char* wsb = (char*)d_ws;
    size_t off = 0;
    float* inv_norm = (float*)(wsb + off); off += (size_t)NPIX * 4;
    float* cv  = (float*)(wsb + off); off += (size_t)NPIX * NCH * 4;
    float* wdw = (float*)(wsb + off); off += (size_t)49 * NCH * 4;
    off = (off + 15) & ~(size_t)15;
    unsigned short* x1bf = (unsigned short*)(wsb + off); off += (size_t)NPIX * C * 2;
    unsigned short* x2bf = (unsigned short*)(wsb + off); off += (size_t)BS * PH * PW * C * 2;
    unsigned short* avp  = (unsigned short*)(wsb + off); off += (size_t)BS * 66 * 66 * ICP * 2;
    unsigned short* wb1  = (unsigned short*)(wsb + off); off += (size_t)9 * C1 * ICP * 2;
    unsigned short* h1p  = (unsigned short*)(wsb + off); off += (size_t)BS * 66 * 66 * IC2 * 2;
    unsigned short* wb2  = (unsigned short*)(wsb + off); off += (size_t)9 * 64 * IC2 * 2;
    if (ws_size < off) return;

    hipMemsetAsync(x2bf, 0, (size_t)BS * PH * PW * C * 2, stream);
    hipMemsetAsync(avp, 0, (size_t)BS * 66 * 66 * ICP * 2, stream);
    hipMemsetAsync(h1p, 0, (size_t)BS * 66 * 66 * IC2 * 2, stream);

    norm_kernel<<<NPIX / 256, 256, 0, stream>>>(f1, inv_norm);
    transpose_kernel<<<4096, 256, 0, stream>>>(f1, x1bf, inv_norm, 0);
    transpose_kernel<<<4096, 256, 0, stream>>>(f2, x2bf, nullptr, 1);

    rearrange_w1_bf<<<(9 * C1 * ICP + 255) / 256, 256, 0, stream>>>(w1, wb1);
    rearrange_w2_bf<<<(9 * 64 * IC2 + 255) / 256, 256, 0, stream>>>(w2, wb2);
    rearrange_dw<<<(NCH * 49 + 255) / 256, 256, 0, stream>>>(att_w, wdw);

    cv_mfma_kernel<<<512, 256, 0, stream>>>(x1bf, x2bf, cv);
    dw_att_kernel<<<(NPIX * NCH + 255) / 256, 256, 0, stream>>>(cv, wdw, att_b, avp);
    agg1_mfma_kernel<<<256, 256, 0, stream>>>(avp, wb1, b1, h1p);
    agg2_mfma_kernel<<<256, 256, 0, stream>>>(h1p, wb2, b2, out);
}

// Round 6
// 310.880 us; speedup vs baseline: 5.2906x; 1.2554x over previous
//
#include <hip/hip_runtime.h>
#include <hip/hip_bf16.h>

// Problem constants
#define BS   4
#define C    256
#define HW   4096          // 64*64
#define NPIX 16384         // 4*4096
#define NCH  289           // cost-volume channels (17*17)
#define MO   17
#define PH   80            // padded 64+2*8
#define PW   80
#define C1   144
#define C2   49
#define ASTR 264           // cv LDS row stride in bf16 elems
#define ICP  320           // agg1 padded input channels (289 -> 320)
#define A1STR 328          // agg1 A-slab LDS stride
#define B1STR 40           // agg1 B LDS stride
#define IC2  160           // agg2 padded input channels (144 -> 160)
#define A2STR 168          // agg2 LDS row stride
#define CVP  70            // cv padded spatial (64 + 2*3)
#define CVC  320           // cv padded channels

typedef __bf16  bf16x8 __attribute__((ext_vector_type(8)));
typedef float   f32x4  __attribute__((ext_vector_type(4)));
typedef unsigned short us8 __attribute__((ext_vector_type(8)));

// ---------------------------------------------------------------------------
// K1: per-pixel inverse L2 norm over 256 channels of f1 (NCHW input)
__global__ void norm_kernel(const float* __restrict__ f1, float* __restrict__ inv_norm) {
    int p = blockIdx.x * 256 + threadIdx.x;     // 0..16383
    if (p >= NPIX) return;
    int b = p >> 12;
    int hw = p & 4095;
    const float* base = f1 + (size_t)b * C * HW + hw;
    float s = 0.f;
    for (int c = 0; c < C; ++c) {
        float v = base[(size_t)c * HW];
        s += v * v;
    }
    float n = sqrtf(s);
    inv_norm[p] = 1.0f / fmaxf(n, 1e-12f);
}

// ---------------------------------------------------------------------------
// K2: NCHW fp32 -> NHWC bf16 transpose.
__global__ void transpose_kernel(const float* __restrict__ src, unsigned short* __restrict__ dst,
                                 const float* __restrict__ inv_norm, int padded) {
    __shared__ float tile[32][33];
    int blk = blockIdx.x;                 // 4096 blocks
    int pblk = blk & 127;
    int cblk = (blk >> 7) & 7;
    int b    = blk >> 10;
    int tx = threadIdx.x & 31, ty = threadIdx.x >> 5;
    int c0 = cblk * 32, p0 = pblk * 32;
    const float* s = src + (size_t)b * C * HW;
#pragma unroll
    for (int i = 0; i < 4; ++i) {
        int c = c0 + ty + 8 * i;
        tile[ty + 8 * i][tx] = s[(size_t)c * HW + p0 + tx];
    }
    __syncthreads();
#pragma unroll
    for (int i = 0; i < 4; ++i) {
        int p = p0 + ty + 8 * i;
        float v = tile[tx][ty + 8 * i];
        int c = c0 + tx;
        if (!padded) {
            v *= inv_norm[b * HW + p];
            __hip_bfloat16 hb = __float2bfloat16(v);
            dst[((size_t)b * HW + p) * C + c] = *(unsigned short*)&hb;
        } else {
            int h = p >> 6, w = p & 63;
            __hip_bfloat16 hb = __float2bfloat16(v);
            dst[(((size_t)b * PH + h + 8) * PW + (w + 8)) * C + c] = *(unsigned short*)&hb;
        }
    }
}

// ---------------------------------------------------------------------------
// Weight rearrange kernels
__global__ void rearrange_w1_bf(const float* __restrict__ w, unsigned short* __restrict__ wb) {
    // OIHW [144][289][3][3] -> bf16 [9][144][320] (ic zero-padded)
    int idx = blockIdx.x * 256 + threadIdx.x;
    if (idx >= 9 * C1 * ICP) return;
    int tap = idx / (C1 * ICP);
    int r = idx - tap * (C1 * ICP);
    int oc = r / ICP;
    int ic = r - oc * ICP;
    float v = (ic < NCH) ? w[((size_t)(oc * NCH + ic)) * 9 + tap] : 0.f;
    __hip_bfloat16 hb = __float2bfloat16(v);
    wb[idx] = *(unsigned short*)&hb;
}
__global__ void rearrange_w2_bf(const float* __restrict__ w, unsigned short* __restrict__ wb) {
    // OIHW [49][144][3][3] -> bf16 [9][64][160] (oc + ic zero-padded)
    int idx = blockIdx.x * 256 + threadIdx.x;
    if (idx >= 9 * 64 * IC2) return;
    int tap = idx / (64 * IC2);
    int r = idx - tap * (64 * IC2);
    int oc = r / IC2;
    int ic = r - oc * IC2;
    float v = (oc < C2 && ic < C1) ? w[((size_t)(oc * C1 + ic)) * 9 + tap] : 0.f;
    __hip_bfloat16 hb = __float2bfloat16(v);
    wb[idx] = *(unsigned short*)&hb;
}
__global__ void rearrange_dw_pad(const float* __restrict__ w, float* __restrict__ wr) {
    // [289][1][7][7] -> [49 taps][320 ch] zero-padded
    int idx = blockIdx.x * 256 + threadIdx.x;
    if (idx >= 49 * CVC) return;
    int tap = idx / CVC;
    int ch = idx - tap * CVC;
    wr[idx] = (ch < NCH) ? w[ch * 49 + tap] : 0.f;
}

// ---------------------------------------------------------------------------
// K3: cost volume via bf16 MFMA -> padded cvp [4][70][70][320] at (+3,+3).
__global__ void cv_mfma_kernel(const unsigned short* __restrict__ x1b,
                               const unsigned short* __restrict__ x2b,
                               float* __restrict__ cvp) {
    __shared__ __align__(16) unsigned short x1s[32 * ASTR];
    __shared__ __align__(16) unsigned short x2s[48 * ASTR];
    int blk = blockIdx.x;                  // 512
    int wseg = blk & 1;
    int h = (blk >> 1) & 63;
    int b = blk >> 7;
    int w0 = wseg * 32;
    int t = threadIdx.x;

    const unsigned short* x1p = x1b + ((size_t)b * HW + h * 64 + w0) * C;
#pragma unroll
    for (int i = 0; i < 4; ++i) {
        int v = t + i * 256;
        int px = v >> 5, ch8 = v & 31;
        *(us8*)&x1s[px * ASTR + ch8 * 8] = *(const us8*)&x1p[px * 256 + ch8 * 8];
    }
    __syncthreads();

    int wave = t >> 6, lane = t & 63;
    int pt = wave >> 1, ct = wave & 1;
    int lrow = lane & 15, quad = lane >> 4;

    bf16x8 a[8];
#pragma unroll
    for (int kk = 0; kk < 8; ++kk)
        a[kk] = *(const bf16x8*)&x1s[(pt * 16 + lrow) * ASTR + kk * 32 + quad * 8];

    const unsigned short* x2base = x2b + (size_t)b * PH * PW * C;
    int col_l = ct * 16 + lrow;

    for (int dj = 0; dj < MO; ++dj) {
        __syncthreads();
        const unsigned short* rowp = x2base + ((size_t)(h + dj) * PW + w0) * C;
#pragma unroll
        for (int i = 0; i < 6; ++i) {
            int v = t + i * 256;
            int col = v >> 5, ch8 = v & 31;
            *(us8*)&x2s[col * ASTR + ch8 * 8] = *(const us8*)&rowp[col * 256 + ch8 * 8];
        }
        __syncthreads();

        f32x4 acc = {0.f, 0.f, 0.f, 0.f};
#pragma unroll
        for (int kk = 0; kk < 8; ++kk) {
            bf16x8 bb = *(const bf16x8*)&x2s[col_l * ASTR + kk * 32 + quad * 8];
            acc = __builtin_amdgcn_mfma_f32_16x16x32_bf16(a[kk], bb, acc, 0, 0, 0);
        }
#pragma unroll
        for (int r = 0; r < 4; ++r) {
            int px_l = pt * 16 + quad * 4 + r;
            int di = col_l - px_l;
            if ((unsigned)di <= 16u) {
                float v = acc[r] * (1.0f / 256.0f);
                cvp[(((size_t)b * CVP + h + 3) * CVP + (w0 + px_l + 3)) * CVC + dj * MO + di] =
                    (v > 0.f) ? v : 0.1f * v;
            }
        }
    }
}

// ---------------------------------------------------------------------------
// K4: depthwise 7x7 attention conv + multiply, LDS-tiled.
// Block = (b, 8x8 px tile, 64-ch chunk): 1280 blocks.
// actS: 14x14x64 fp32 tile (50 KB), wdwS: 49x64 (12.5 KB).
// Thread = 1 ch x 16 px (2 rows x 8 cols). Zero bounds checks (padded cvp).
__global__ void dw_att_tiled(const float* __restrict__ cvp, const float* __restrict__ wdwp,
                             const float* __restrict__ att_b, unsigned short* __restrict__ av_pad) {
    __shared__ float actS[14 * 14 * 64];
    __shared__ float wdwS[49 * 64];
    int blk = blockIdx.x;                  // 1280
    int cc = blk % 5;
    int rest = blk / 5;
    int tx = rest & 7, ty = (rest >> 3) & 7, b = rest >> 6;
    int x0 = tx * 8, y0 = ty * 8;
    int c0 = cc * 64;
    int t = threadIdx.x;

    // stage act tile: 14x14 px x 64 ch (float4)
    const float* cvb = cvp + (((size_t)b * CVP + y0) * CVP + x0) * CVC + c0;
    for (int v = t; v < 14 * 14 * 16; v += 256) {
        int rc = v >> 4, c4 = v & 15;
        int yy = rc / 14, xx = rc - yy * 14;
        *(f32x4*)&actS[rc * 64 + c4 * 4] =
            *(const f32x4*)&cvb[((size_t)yy * CVP + xx) * CVC + c4 * 4];
    }
    // stage weights: 49 taps x 64 ch
    for (int v = t; v < 49 * 64; v += 256) {
        int tap = v >> 6, ch = v & 63;
        wdwS[v] = wdwp[tap * CVC + c0 + ch];
    }
    __syncthreads();

    int ch_l = t & 63, pgrp = t >> 6;
    int ch = c0 + ch_l;
    float bv = (ch < NCH) ? att_b[ch] : 0.f;
    float acc[16];
#pragma unroll
    for (int i = 0; i < 16; ++i) acc[i] = bv;

    for (int dy = 0; dy < 7; ++dy) {
#pragma unroll
        for (int dx = 0; dx < 7; ++dx) {
            float wv = wdwS[(dy * 7 + dx) * 64 + ch_l];
#pragma unroll
            for (int i = 0; i < 16; ++i) {
                int py = pgrp * 2 + (i >> 3), px = i & 7;
                float a = actS[((py + dy) * 14 + (px + dx)) * 64 + ch_l];
                acc[i] += a * wv;
            }
        }
    }

    if (ch < NCH) {
#pragma unroll
        for (int i = 0; i < 16; ++i) {
            int py = pgrp * 2 + (i >> 3), px = i & 7;
            float c0v = actS[((py + 3) * 14 + (px + 3)) * 64 + ch_l];
            __hip_bfloat16 hb = __float2bfloat16(c0v * acc[i]);
            av_pad[(((size_t)b * 66 + y0 + py + 1) * 66 + (x0 + px + 1)) * ICP + ch] =
                *(unsigned short*)&hb;
        }
    }
}

// ---------------------------------------------------------------------------
// K5: conv3x3 289->144 + ReLU via bf16 MFMA -> bf16 h1p [BS][66][66][160].
__global__ void agg1_mfma_kernel(const unsigned short* __restrict__ av_pad,
                                 const unsigned short* __restrict__ wb1,
                                 const float* __restrict__ bias, unsigned short* __restrict__ h1p) {
    __shared__ __align__(16) unsigned short aS[66 * A1STR];   // 43.3 KB
    __shared__ __align__(16) unsigned short bS[C1 * B1STR];   // 11.5 KB
    int blk = blockIdx.x;                  // 256
    int h = blk & 63;
    int b = blk >> 6;
    int t = threadIdx.x;
    int wave = t >> 6, lane = t & 63;
    int lrow = lane & 15, quad = lane >> 4;
    int pt = wave;

    f32x4 acc[9];
#pragma unroll
    for (int ot = 0; ot < 9; ++ot) acc[ot] = (f32x4){0.f, 0.f, 0.f, 0.f};

    const unsigned short* avb = av_pad + (((size_t)b * 66 + h) * 66) * ICP;

    for (int dy = 0; dy < 3; ++dy) {
        __syncthreads();
        const unsigned short* arow = avb + (size_t)dy * 66 * ICP;
        for (int v = t; v < 66 * (ICP / 8); v += 256) {
            int col = v / (ICP / 8);
            int c8 = v - col * (ICP / 8);
            *(us8*)&aS[col * A1STR + c8 * 8] = *(const us8*)&arow[col * ICP + c8 * 8];
        }
        for (int dx = 0; dx < 3; ++dx) {
            int tap = dy * 3 + dx;
            const unsigned short* wtap = wb1 + (size_t)tap * C1 * ICP;
            for (int cc = 0; cc < ICP; cc += 32) {
                for (int v = t; v < C1 * 4; v += 256) {
                    int oc = v >> 2, c8 = v & 3;
                    *(us8*)&bS[oc * B1STR + c8 * 8] =
                        *(const us8*)&wtap[(size_t)oc * ICP + cc + c8 * 8];
                }
                __syncthreads();
                bf16x8 af = *(const bf16x8*)&aS[(pt * 16 + lrow + dx) * A1STR + cc + quad * 8];
#pragma unroll
                for (int ot = 0; ot < 9; ++ot) {
                    bf16x8 bf = *(const bf16x8*)&bS[(ot * 16 + lrow) * B1STR + quad * 8];
                    acc[ot] = __builtin_amdgcn_mfma_f32_16x16x32_bf16(af, bf, acc[ot], 0, 0, 0);
                }
                __syncthreads();
            }
        }
    }

#pragma unroll
    for (int ot = 0; ot < 9; ++ot) {
        int oc = ot * 16 + lrow;
        float bv = bias[oc];
#pragma unroll
        for (int r = 0; r < 4; ++r) {
            int w = pt * 16 + quad * 4 + r;
            float val = fmaxf(acc[ot][r] + bv, 0.f);
            __hip_bfloat16 hb = __float2bfloat16(val);
            h1p[(((size_t)b * 66 + h + 1) * 66 + (w + 1)) * IC2 + oc] = *(unsigned short*)&hb;
        }
    }
}

// ---------------------------------------------------------------------------
// K6: conv3x3 144->49 + ReLU via bf16 MFMA, writes NCHW fp32 output.
__global__ void agg2_mfma_kernel(const unsigned short* __restrict__ h1p,
                                 const unsigned short* __restrict__ wb2,
                                 const float* __restrict__ bias, float* __restrict__ out) {
    __shared__ __align__(16) unsigned short aS[66 * A2STR];   // 22.2 KB
    __shared__ __align__(16) unsigned short bS[64 * A2STR];   // 21.5 KB
    int blk = blockIdx.x;                  // 256
    int h = blk & 63;
    int b = blk >> 6;
    int t = threadIdx.x;
    int wave = t >> 6, lane = t & 63;
    int lrow = lane & 15, quad = lane >> 4;
    int pt = wave;

    f32x4 acc[4];
#pragma unroll
    for (int ot = 0; ot < 4; ++ot) acc[ot] = (f32x4){0.f, 0.f, 0.f, 0.f};

    const unsigned short* h1b = h1p + (((size_t)b * 66 + h) * 66) * IC2;

    for (int dy = 0; dy < 3; ++dy) {
        __syncthreads();
        const unsigned short* arow = h1b + (size_t)dy * 66 * IC2;
        for (int v = t; v < 66 * (IC2 / 8); v += 256) {
            int col = v / (IC2 / 8);
            int c8 = v - col * (IC2 / 8);
            *(us8*)&aS[col * A2STR + c8 * 8] = *(const us8*)&arow[col * IC2 + c8 * 8];
        }
        for (int dx = 0; dx < 3; ++dx) {
            int tap = dy * 3 + dx;
            if (dx != 0) __syncthreads();
            const unsigned short* wtap = wb2 + (size_t)tap * 64 * IC2;
            for (int v = t; v < 64 * (IC2 / 8); v += 256) {
                int oc = v / (IC2 / 8);
                int c8 = v - oc * (IC2 / 8);
                *(us8*)&bS[oc * A2STR + c8 * 8] = *(const us8*)&wtap[(size_t)oc * IC2 + c8 * 8];
            }
            __syncthreads();
#pragma unroll
            for (int cc = 0; cc < 5; ++cc) {
                bf16x8 af = *(const bf16x8*)&aS[(pt * 16 + lrow + dx) * A2STR + cc * 32 + quad * 8];
#pragma unroll
                for (int ot = 0; ot < 4; ++ot) {
                    bf16x8 bf = *(const bf16x8*)&bS[(ot * 16 + lrow) * A2STR + cc * 32 + quad * 8];
                    acc[ot] = __builtin_amdgcn_mfma_f32_16x16x32_bf16(af, bf, acc[ot], 0, 0, 0);
                }
            }
        }
    }

#pragma unroll
    for (int ot = 0; ot < 4; ++ot) {
        int o = ot * 16 + lrow;
        if (o < C2) {
            float bv = bias[o];
#pragma unroll
            for (int r = 0; r < 4; ++r) {
                int w = pt * 16 + quad * 4 + r;
                out[((size_t)b * C2 + o) * HW + h * 64 + w] = fmaxf(acc[ot][r] + bv, 0.f);
            }
        }
    }
}

// ---------------------------------------------------------------------------
extern "C" void kernel_launch(void* const* d_in, const int* in_sizes, int n_in,
                              void* d_out, int out_size, void* d_ws, size_t ws_size,
                              hipStream_t stream) {
    const float* f1    = (const float*)d_in[0];
    const float* f2    = (const float*)d_in[1];
    const float* att_w = (const float*)d_in[2];
    const float* att_b = (const float*)d_in[3];
    const float* w1    = (const float*)d_in[4];
    const float* b1    = (const float*)d_in[5];
    const float* w2    = (const float*)d_in[6];
    const float* b2    = (const float*)d_in[7];
    float* out = (float*)d_out;

    char* wsb = (char*)d_ws;
    size_t off = 0;
    float* inv_norm = (float*)(wsb + off); off += (size_t)NPIX * 4;
    float* cvp  = (float*)(wsb + off); off += (size_t)BS * CVP * CVP * CVC * 4;
    float* wdwp = (float*)(wsb + off); off += (size_t)49 * CVC * 4;
    off = (off + 15) & ~(size_t)15;
    unsigned short* x1bf = (unsigned short*)(wsb + off); off += (size_t)NPIX * C * 2;
    unsigned short* x2bf = (unsigned short*)(wsb + off); off += (size_t)BS * PH * PW * C * 2;
    unsigned short* avp  = (unsigned short*)(wsb + off); off += (size_t)BS * 66 * 66 * ICP * 2;
    unsigned short* wb1  = (unsigned short*)(wsb + off); off += (size_t)9 * C1 * ICP * 2;
    unsigned short* h1p  = (unsigned short*)(wsb + off); off += (size_t)BS * 66 * 66 * IC2 * 2;
    unsigned short* wb2  = (unsigned short*)(wsb + off); off += (size_t)9 * 64 * IC2 * 2;
    if (ws_size < off) return;

    hipMemsetAsync(x2bf, 0, (size_t)BS * PH * PW * C * 2, stream);
    hipMemsetAsync(cvp, 0, (size_t)BS * CVP * CVP * CVC * 4, stream);
    hipMemsetAsync(avp, 0, (size_t)BS * 66 * 66 * ICP * 2, stream);
    hipMemsetAsync(h1p, 0, (size_t)BS * 66 * 66 * IC2 * 2, stream);

    norm_kernel<<<NPIX / 256, 256, 0, stream>>>(f1, inv_norm);
    transpose_kernel<<<4096, 256, 0, stream>>>(f1, x1bf, inv_norm, 0);
    transpose_kernel<<<4096, 256, 0, stream>>>(f2, x2bf, nullptr, 1);

    rearrange_w1_bf<<<(9 * C1 * ICP + 255) / 256, 256, 0, stream>>>(w1, wb1);
    rearrange_w2_bf<<<(9 * 64 * IC2 + 255) / 256, 256, 0, stream>>>(w2, wb2);
    rearrange_dw_pad<<<(49 * CVC + 255) / 256, 256, 0, stream>>>(att_w, wdwp);

    cv_mfma_kernel<<<512, 256, 0, stream>>>(x1bf, x2bf, cvp);
    dw_att_tiled<<<1280, 256, 0, stream>>>(cvp, wdwp, att_b, avp);
    agg1_mfma_kernel<<<256, 256, 0, stream>>>(avp, wb1, b1, h1p);
    agg2_mfma_kernel<<<256, 256, 0, stream>>>(h1p, wb2, b2, out);
}

// Round 7
// 258.601 us; speedup vs baseline: 6.3601x; 1.2022x over previous
//
#include <hip/hip_runtime.h>
#include <hip/hip_bf16.h>

// Problem constants
#define BS   4
#define C    256
#define HW   4096          // 64*64
#define NPIX 16384         // 4*4096
#define NCH  289           // cost-volume channels (17*17)
#define MO   17
#define PH   80            // padded 64+2*8
#define PW   80
#define C1   144
#define C2   49
#define ASTR 264           // cv LDS row stride in bf16 elems
#define ICP  320           // agg1 padded input channels (289 -> 320)
#define IC2  160           // agg2 padded input channels (144 -> 160)
#define A2STR 168          // agg2 LDS row stride
#define CVP  70            // cv padded spatial (64 + 2*3)
#define CVC  320           // cv padded channels
#define CH64 72            // 64-ch chunk LDS stride (64+8): bank-balanced

typedef __bf16  bf16x8 __attribute__((ext_vector_type(8)));
typedef float   f32x4  __attribute__((ext_vector_type(4)));
typedef unsigned short us8 __attribute__((ext_vector_type(8)));

// ---------------------------------------------------------------------------
// K1: per-pixel inverse L2 norm over 256 channels of f1 (NCHW input)
__global__ void norm_kernel(const float* __restrict__ f1, float* __restrict__ inv_norm) {
    int p = blockIdx.x * 256 + threadIdx.x;     // 0..16383
    if (p >= NPIX) return;
    int b = p >> 12;
    int hw = p & 4095;
    const float* base = f1 + (size_t)b * C * HW + hw;
    float s = 0.f;
    for (int c = 0; c < C; ++c) {
        float v = base[(size_t)c * HW];
        s += v * v;
    }
    float n = sqrtf(s);
    inv_norm[p] = 1.0f / fmaxf(n, 1e-12f);
}

// ---------------------------------------------------------------------------
// K2: NCHW fp32 -> NHWC bf16 transpose.
__global__ void transpose_kernel(const float* __restrict__ src, unsigned short* __restrict__ dst,
                                 const float* __restrict__ inv_norm, int padded) {
    __shared__ float tile[32][33];
    int blk = blockIdx.x;                 // 4096 blocks
    int pblk = blk & 127;
    int cblk = (blk >> 7) & 7;
    int b    = blk >> 10;
    int tx = threadIdx.x & 31, ty = threadIdx.x >> 5;
    int c0 = cblk * 32, p0 = pblk * 32;
    const float* s = src + (size_t)b * C * HW;
#pragma unroll
    for (int i = 0; i < 4; ++i) {
        int c = c0 + ty + 8 * i;
        tile[ty + 8 * i][tx] = s[(size_t)c * HW + p0 + tx];
    }
    __syncthreads();
#pragma unroll
    for (int i = 0; i < 4; ++i) {
        int p = p0 + ty + 8 * i;
        float v = tile[tx][ty + 8 * i];
        int c = c0 + tx;
        if (!padded) {
            v *= inv_norm[b * HW + p];
            __hip_bfloat16 hb = __float2bfloat16(v);
            dst[((size_t)b * HW + p) * C + c] = *(unsigned short*)&hb;
        } else {
            int h = p >> 6, w = p & 63;
            __hip_bfloat16 hb = __float2bfloat16(v);
            dst[(((size_t)b * PH + h + 8) * PW + (w + 8)) * C + c] = *(unsigned short*)&hb;
        }
    }
}

// ---------------------------------------------------------------------------
// Weight rearrange kernels
__global__ void rearrange_w1_bf(const float* __restrict__ w, unsigned short* __restrict__ wb) {
    // OIHW [144][289][3][3] -> bf16 [9][144][320] (ic zero-padded)
    int idx = blockIdx.x * 256 + threadIdx.x;
    if (idx >= 9 * C1 * ICP) return;
    int tap = idx / (C1 * ICP);
    int r = idx - tap * (C1 * ICP);
    int oc = r / ICP;
    int ic = r - oc * ICP;
    float v = (ic < NCH) ? w[((size_t)(oc * NCH + ic)) * 9 + tap] : 0.f;
    __hip_bfloat16 hb = __float2bfloat16(v);
    wb[idx] = *(unsigned short*)&hb;
}
__global__ void rearrange_w2_bf(const float* __restrict__ w, unsigned short* __restrict__ wb) {
    // OIHW [49][144][3][3] -> bf16 [9][64][160] (oc + ic zero-padded)
    int idx = blockIdx.x * 256 + threadIdx.x;
    if (idx >= 9 * 64 * IC2) return;
    int tap = idx / (64 * IC2);
    int r = idx - tap * (64 * IC2);
    int oc = r / IC2;
    int ic = r - oc * IC2;
    float v = (oc < C2 && ic < C1) ? w[((size_t)(oc * C1 + ic)) * 9 + tap] : 0.f;
    __hip_bfloat16 hb = __float2bfloat16(v);
    wb[idx] = *(unsigned short*)&hb;
}
__global__ void rearrange_dw_pad(const float* __restrict__ w, float* __restrict__ wr) {
    // [289][1][7][7] -> [49 taps][320 ch] zero-padded
    int idx = blockIdx.x * 256 + threadIdx.x;
    if (idx >= 49 * CVC) return;
    int tap = idx / CVC;
    int ch = idx - tap * CVC;
    wr[idx] = (ch < NCH) ? w[ch * 49 + tap] : 0.f;
}

// ---------------------------------------------------------------------------
// K3: cost volume via bf16 MFMA -> padded cvp [4][70][70][320] at (+3,+3).
__global__ void cv_mfma_kernel(const unsigned short* __restrict__ x1b,
                               const unsigned short* __restrict__ x2b,
                               float* __restrict__ cvp) {
    __shared__ __align__(16) unsigned short x1s[32 * ASTR];
    __shared__ __align__(16) unsigned short x2s[48 * ASTR];
    int blk = blockIdx.x;                  // 512
    int wseg = blk & 1;
    int h = (blk >> 1) & 63;
    int b = blk >> 7;
    int w0 = wseg * 32;
    int t = threadIdx.x;

    const unsigned short* x1p = x1b + ((size_t)b * HW + h * 64 + w0) * C;
#pragma unroll
    for (int i = 0; i < 4; ++i) {
        int v = t + i * 256;
        int px = v >> 5, ch8 = v & 31;
        *(us8*)&x1s[px * ASTR + ch8 * 8] = *(const us8*)&x1p[px * 256 + ch8 * 8];
    }
    __syncthreads();

    int wave = t >> 6, lane = t & 63;
    int pt = wave >> 1, ct = wave & 1;
    int lrow = lane & 15, quad = lane >> 4;

    bf16x8 a[8];
#pragma unroll
    for (int kk = 0; kk < 8; ++kk)
        a[kk] = *(const bf16x8*)&x1s[(pt * 16 + lrow) * ASTR + kk * 32 + quad * 8];

    const unsigned short* x2base = x2b + (size_t)b * PH * PW * C;
    int col_l = ct * 16 + lrow;

    for (int dj = 0; dj < MO; ++dj) {
        __syncthreads();
        const unsigned short* rowp = x2base + ((size_t)(h + dj) * PW + w0) * C;
#pragma unroll
        for (int i = 0; i < 6; ++i) {
            int v = t + i * 256;
            int col = v >> 5, ch8 = v & 31;
            *(us8*)&x2s[col * ASTR + ch8 * 8] = *(const us8*)&rowp[col * 256 + ch8 * 8];
        }
        __syncthreads();

        f32x4 acc = {0.f, 0.f, 0.f, 0.f};
#pragma unroll
        for (int kk = 0; kk < 8; ++kk) {
            bf16x8 bb = *(const bf16x8*)&x2s[col_l * ASTR + kk * 32 + quad * 8];
            acc = __builtin_amdgcn_mfma_f32_16x16x32_bf16(a[kk], bb, acc, 0, 0, 0);
        }
#pragma unroll
        for (int r = 0; r < 4; ++r) {
            int px_l = pt * 16 + quad * 4 + r;
            int di = col_l - px_l;
            if ((unsigned)di <= 16u) {
                float v = acc[r] * (1.0f / 256.0f);
                cvp[(((size_t)b * CVP + h + 3) * CVP + (w0 + px_l + 3)) * CVC + dj * MO + di] =
                    (v > 0.f) ? v : 0.1f * v;
            }
        }
    }
}

// ---------------------------------------------------------------------------
// K4: depthwise 7x7 attention conv + multiply, LDS-tiled (unchanged).
__global__ void dw_att_tiled(const float* __restrict__ cvp, const float* __restrict__ wdwp,
                             const float* __restrict__ att_b, unsigned short* __restrict__ av_pad) {
    __shared__ float actS[14 * 14 * 64];
    __shared__ float wdwS[49 * 64];
    int blk = blockIdx.x;                  // 1280
    int cc = blk % 5;
    int rest = blk / 5;
    int tx = rest & 7, ty = (rest >> 3) & 7, b = rest >> 6;
    int x0 = tx * 8, y0 = ty * 8;
    int c0 = cc * 64;
    int t = threadIdx.x;

    const float* cvb = cvp + (((size_t)b * CVP + y0) * CVP + x0) * CVC + c0;
    for (int v = t; v < 14 * 14 * 16; v += 256) {
        int rc = v >> 4, c4 = v & 15;
        int yy = rc / 14, xx = rc - yy * 14;
        *(f32x4*)&actS[rc * 64 + c4 * 4] =
            *(const f32x4*)&cvb[((size_t)yy * CVP + xx) * CVC + c4 * 4];
    }
    for (int v = t; v < 49 * 64; v += 256) {
        int tap = v >> 6, ch = v & 63;
        wdwS[v] = wdwp[tap * CVC + c0 + ch];
    }
    __syncthreads();

    int ch_l = t & 63, pgrp = t >> 6;
    int ch = c0 + ch_l;
    float bv = (ch < NCH) ? att_b[ch] : 0.f;
    float acc[16];
#pragma unroll
    for (int i = 0; i < 16; ++i) acc[i] = bv;

    for (int dy = 0; dy < 7; ++dy) {
#pragma unroll
        for (int dx = 0; dx < 7; ++dx) {
            float wv = wdwS[(dy * 7 + dx) * 64 + ch_l];
#pragma unroll
            for (int i = 0; i < 16; ++i) {
                int py = pgrp * 2 + (i >> 3), px = i & 7;
                float a = actS[((py + dy) * 14 + (px + dx)) * 64 + ch_l];
                acc[i] += a * wv;
            }
        }
    }

    if (ch < NCH) {
#pragma unroll
        for (int i = 0; i < 16; ++i) {
            int py = pgrp * 2 + (i >> 3), px = i & 7;
            float c0v = actS[((py + 3) * 14 + (px + 3)) * 64 + ch_l];
            __hip_bfloat16 hb = __float2bfloat16(c0v * acc[i]);
            av_pad[(((size_t)b * 66 + y0 + py + 1) * 66 + (x0 + px + 1)) * ICP + ch] =
                *(unsigned short*)&hb;
        }
    }
}

// ---------------------------------------------------------------------------
// K5: conv3x3 289->144 + ReLU via bf16 MFMA, software-pipelined.
// Block = one row (b,h): 64 px x 144 oc, 4 waves (oc-split: {3,2,2,2} oc-tiles,
// each wave covers all 4 px-tiles). 45 K-steps of K=64 over (dy, cc64, dx);
// A-chunk (66 cols x 64ch) and B-chunk (144 oc x 64ch) double-buffered in LDS;
// global prefetch (k+1) -> MFMA burst (k) -> ds_write -> ONE barrier per step.
__global__ void agg1_mfma_kernel(const unsigned short* __restrict__ av_pad,
                                 const unsigned short* __restrict__ wb1,
                                 const float* __restrict__ bias,
                                 unsigned short* __restrict__ h1p) {
    __shared__ __align__(16) unsigned short aS2[2][66 * CH64];   // 2 x 9.3 KB
    __shared__ __align__(16) unsigned short bS[2][C1 * CH64];    // 2 x 20.3 KB
    int blk = blockIdx.x;                  // 256
    int h = blk & 63;
    int b = blk >> 6;
    int t = threadIdx.x;
    int wave = t >> 6, lane = t & 63;
    int lrow = lane & 15, quad = lane >> 4;
    int ot0 = (wave == 0) ? 0 : (wave * 2 + 1);   // 0 / 3 / 5 / 7
    int nt  = (wave == 0) ? 3 : 2;

    f32x4 acc[4][3];
#pragma unroll
    for (int m = 0; m < 4; ++m)
#pragma unroll
        for (int i = 0; i < 3; ++i) acc[m][i] = (f32x4){0.f, 0.f, 0.f, 0.f};

    const unsigned short* avb = av_pad + (((size_t)b * 66 + h) * 66) * ICP;

    // ---- initial stage: A(dy=0,cc=0) -> aS2[0], B(tap0,cc=0) -> bS[0]
    {
        const unsigned short* arow = avb;
#pragma unroll
        for (int s = 0; s < 2; ++s) {
            int v = t + s * 256;
            *(us8*)&aS2[0][(v >> 3) * CH64 + (v & 7) * 8] =
                *(const us8*)&arow[(size_t)(v >> 3) * ICP + (v & 7) * 8];
        }
        if (t < 16) {
            int v = t + 512;
            *(us8*)&aS2[0][(v >> 3) * CH64 + (v & 7) * 8] =
                *(const us8*)&arow[(size_t)(v >> 3) * ICP + (v & 7) * 8];
        }
#pragma unroll
        for (int s = 0; s < 4; ++s) {
            int v = t + s * 256;
            *(us8*)&bS[0][(v >> 3) * CH64 + (v & 7) * 8] =
                *(const us8*)&wb1[(size_t)(v >> 3) * ICP + (v & 7) * 8];
        }
        if (t < 128) {
            int v = t + 1024;
            *(us8*)&bS[0][(v >> 3) * CH64 + (v & 7) * 8] =
                *(const us8*)&wb1[(size_t)(v >> 3) * ICP + (v & 7) * 8];
        }
    }
    __syncthreads();

    for (int k = 0; k < 45; ++k) {
        int rr = k % 15;
        int dx = rr % 3;
        int abuf = (k / 3) & 1, bbuf = k & 1;

        // ---- prefetch k+1 into regs
        us8 br[5], ar[3];
        int kn = k + 1;
        bool do_b = (kn < 45);
        bool do_a = do_b && (kn % 3 == 0);
        int dyn = kn / 15, rn = kn % 15;
        int ccin = rn / 3, dxn = rn % 3;
        if (do_b) {
            const unsigned short* wt = wb1 + ((size_t)(dyn * 3 + dxn) * C1) * ICP + ccin * 64;
#pragma unroll
            for (int s = 0; s < 4; ++s) {
                int v = t + s * 256;
                br[s] = *(const us8*)&wt[(size_t)(v >> 3) * ICP + (v & 7) * 8];
            }
            if (t < 128) {
                int v = t + 1024;
                br[4] = *(const us8*)&wt[(size_t)(v >> 3) * ICP + (v & 7) * 8];
            }
        }
        if (do_a) {
            const unsigned short* arow = avb + (size_t)dyn * 66 * ICP + ccin * 64;
#pragma unroll
            for (int s = 0; s < 2; ++s) {
                int v = t + s * 256;
                ar[s] = *(const us8*)&arow[(size_t)(v >> 3) * ICP + (v & 7) * 8];
            }
            if (t < 16) {
                int v = t + 512;
                ar[2] = *(const us8*)&arow[(size_t)(v >> 3) * ICP + (v & 7) * 8];
            }
        }

        // ---- MFMA burst on buffers(k)
        const unsigned short* aP = aS2[abuf];
        const unsigned short* bP = bS[bbuf];
#pragma unroll
        for (int cc2 = 0; cc2 < 2; ++cc2) {
            bf16x8 bf[3];
#pragma unroll
            for (int i = 0; i < 3; ++i)
                if (i < nt)
                    bf[i] = *(const bf16x8*)&bP[((ot0 + i) * 16 + lrow) * CH64 + cc2 * 32 + quad * 8];
#pragma unroll
            for (int m = 0; m < 4; ++m) {
                bf16x8 af = *(const bf16x8*)&aP[(m * 16 + lrow + dx) * CH64 + cc2 * 32 + quad * 8];
#pragma unroll
                for (int i = 0; i < 3; ++i)
                    if (i < nt)
                        acc[m][i] = __builtin_amdgcn_mfma_f32_16x16x32_bf16(af, bf[i], acc[m][i], 0, 0, 0);
            }
        }

        // ---- commit prefetched to the other buffers, one barrier
        if (do_b) {
            unsigned short* dst = bS[bbuf ^ 1];
#pragma unroll
            for (int s = 0; s < 4; ++s) {
                int v = t + s * 256;
                *(us8*)&dst[(v >> 3) * CH64 + (v & 7) * 8] = br[s];
            }
            if (t < 128) {
                int v = t + 1024;
                *(us8*)&dst[(v >> 3) * CH64 + (v & 7) * 8] = br[4];
            }
        }
        if (do_a) {
            unsigned short* dst = aS2[abuf ^ 1];
#pragma unroll
            for (int s = 0; s < 2; ++s) {
                int v = t + s * 256;
                *(us8*)&dst[(v >> 3) * CH64 + (v & 7) * 8] = ar[s];
            }
            if (t < 16) {
                int v = t + 512;
                *(us8*)&dst[(v >> 3) * CH64 + (v & 7) * 8] = ar[2];
            }
        }
        if (do_b) __syncthreads();
    }

    // ---- epilogue: bias + ReLU -> bf16 h1p at (h+1, w+1)
    size_t rowbase = ((size_t)b * 66 + h + 1) * 66;
#pragma unroll
    for (int m = 0; m < 4; ++m)
#pragma unroll
        for (int i = 0; i < 3; ++i)
            if (i < nt) {
                int oc = (ot0 + i) * 16 + lrow;
                float bv = bias[oc];
#pragma unroll
                for (int r = 0; r < 4; ++r) {
                    int w = m * 16 + quad * 4 + r;
                    float val = fmaxf(acc[m][i][r] + bv, 0.f);
                    __hip_bfloat16 hb = __float2bfloat16(val);
                    h1p[(rowbase + (w + 1)) * IC2 + oc] = *(unsigned short*)&hb;
                }
            }
}

// ---------------------------------------------------------------------------
// K6: conv3x3 144->49 + ReLU via bf16 MFMA, writes NCHW fp32 output.
__global__ void agg2_mfma_kernel(const unsigned short* __restrict__ h1p,
                                 const unsigned short* __restrict__ wb2,
                                 const float* __restrict__ bias, float* __restrict__ out) {
    __shared__ __align__(16) unsigned short aS[66 * A2STR];   // 22.2 KB
    __shared__ __align__(16) unsigned short bS[64 * A2STR];   // 21.5 KB
    int blk = blockIdx.x;                  // 256
    int h = blk & 63;
    int b = blk >> 6;
    int t = threadIdx.x;
    int wave = t >> 6, lane = t & 63;
    int lrow = lane & 15, quad = lane >> 4;
    int pt = wave;

    f32x4 acc[4];
#pragma unroll
    for (int ot = 0; ot < 4; ++ot) acc[ot] = (f32x4){0.f, 0.f, 0.f, 0.f};

    const unsigned short* h1b = h1p + (((size_t)b * 66 + h) * 66) * IC2;

    for (int dy = 0; dy < 3; ++dy) {
        __syncthreads();
        const unsigned short* arow = h1b + (size_t)dy * 66 * IC2;
        for (int v = t; v < 66 * (IC2 / 8); v += 256) {
            int col = v / (IC2 / 8);
            int c8 = v - col * (IC2 / 8);
            *(us8*)&aS[col * A2STR + c8 * 8] = *(const us8*)&arow[col * IC2 + c8 * 8];
        }
        for (int dx = 0; dx < 3; ++dx) {
            int tap = dy * 3 + dx;
            if (dx != 0) __syncthreads();
            const unsigned short* wtap = wb2 + (size_t)tap * 64 * IC2;
            for (int v = t; v < 64 * (IC2 / 8); v += 256) {
                int oc = v / (IC2 / 8);
                int c8 = v - oc * (IC2 / 8);
                *(us8*)&bS[oc * A2STR + c8 * 8] = *(const us8*)&wtap[(size_t)oc * IC2 + c8 * 8];
            }
            __syncthreads();
#pragma unroll
            for (int cc = 0; cc < 5; ++cc) {
                bf16x8 af = *(const bf16x8*)&aS[(pt * 16 + lrow + dx) * A2STR + cc * 32 + quad * 8];
#pragma unroll
                for (int ot = 0; ot < 4; ++ot) {
                    bf16x8 bf = *(const bf16x8*)&bS[(ot * 16 + lrow) * A2STR + cc * 32 + quad * 8];
                    acc[ot] = __builtin_amdgcn_mfma_f32_16x16x32_bf16(af, bf, acc[ot], 0, 0, 0);
                }
            }
        }
    }

#pragma unroll
    for (int ot = 0; ot < 4; ++ot) {
        int o = ot * 16 + lrow;
        if (o < C2) {
            float bv = bias[o];
#pragma unroll
            for (int r = 0; r < 4; ++r) {
                int w = pt * 16 + quad * 4 + r;
                out[((size_t)b * C2 + o) * HW + h * 64 + w] = fmaxf(acc[ot][r] + bv, 0.f);
            }
        }
    }
}

// ---------------------------------------------------------------------------
extern "C" void kernel_launch(void* const* d_in, const int* in_sizes, int n_in,
                              void* d_out, int out_size, void* d_ws, size_t ws_size,
                              hipStream_t stream) {
    const float* f1    = (const float*)d_in[0];
    const float* f2    = (const float*)d_in[1];
    const float* att_w = (const float*)d_in[2];
    const float* att_b = (const float*)d_in[3];
    const float* w1    = (const float*)d_in[4];
    const float* b1    = (const float*)d_in[5];
    const float* w2    = (const float*)d_in[6];
    const float* b2    = (const float*)d_in[7];
    float* out = (float*)d_out;

    char* wsb = (char*)d_ws;
    size_t off = 0;
    float* inv_norm = (float*)(wsb + off); off += (size_t)NPIX * 4;
    float* cvp  = (float*)(wsb + off); off += (size_t)BS * CVP * CVP * CVC * 4;
    float* wdwp = (float*)(wsb + off); off += (size_t)49 * CVC * 4;
    off = (off + 15) & ~(size_t)15;
    unsigned short* x1bf = (unsigned short*)(wsb + off); off += (size_t)NPIX * C * 2;
    unsigned short* x2bf = (unsigned short*)(wsb + off); off += (size_t)BS * PH * PW * C * 2;
    unsigned short* avp  = (unsigned short*)(wsb + off); off += (size_t)BS * 66 * 66 * ICP * 2;
    unsigned short* wb1  = (unsigned short*)(wsb + off); off += (size_t)9 * C1 * ICP * 2;
    unsigned short* h1p  = (unsigned short*)(wsb + off); off += (size_t)BS * 66 * 66 * IC2 * 2;
    unsigned short* wb2  = (unsigned short*)(wsb + off); off += (size_t)9 * 64 * IC2 * 2;
    if (ws_size < off) return;

    hipMemsetAsync(x2bf, 0, (size_t)BS * PH * PW * C * 2, stream);
    hipMemsetAsync(cvp, 0, (size_t)BS * CVP * CVP * CVC * 4, stream);
    hipMemsetAsync(avp, 0, (size_t)BS * 66 * 66 * ICP * 2, stream);
    hipMemsetAsync(h1p, 0, (size_t)BS * 66 * 66 * IC2 * 2, stream);

    norm_kernel<<<NPIX / 256, 256, 0, stream>>>(f1, inv_norm);
    transpose_kernel<<<4096, 256, 0, stream>>>(f1, x1bf, inv_norm, 0);
    transpose_kernel<<<4096, 256, 0, stream>>>(f2, x2bf, nullptr, 1);

    rearrange_w1_bf<<<(9 * C1 * ICP + 255) / 256, 256, 0, stream>>>(w1, wb1);
    rearrange_w2_bf<<<(9 * 64 * IC2 + 255) / 256, 256, 0, stream>>>(w2, wb2);
    rearrange_dw_pad<<<(49 * CVC + 255) / 256, 256, 0, stream>>>(att_w, wdwp);

    cv_mfma_kernel<<<512, 256, 0, stream>>>(x1bf, x2bf, cvp);
    dw_att_tiled<<<1280, 256, 0, stream>>>(cvp, wdwp, att_b, avp);
    agg1_mfma_kernel<<<256, 256, 0, stream>>>(avp, wb1, b1, h1p);
    agg2_mfma_kernel<<<256, 256, 0, stream>>>(h1p, wb2, b2, out);
}

// Round 8
// 253.795 us; speedup vs baseline: 6.4806x; 1.0189x over previous
//
#include <hip/hip_runtime.h>
#include <hip/hip_bf16.h>

// Problem constants
#define BS   4
#define C    256
#define HW   4096          // 64*64
#define NPIX 16384         // 4*4096
#define NCH  289           // cost-volume channels (17*17)
#define MO   17
#define PH   80            // padded 64+2*8
#define PW   80
#define C1   144
#define C2   49
#define ASTR 264           // cv LDS row stride in bf16 elems
#define ICP  320           // agg1 padded input channels (289 -> 320)
#define IC2  160           // agg2 padded input channels (144 -> 160)
#define A2STR 168          // agg2 LDS row stride
#define CVP  70            // cv padded spatial (64 + 2*3)
#define CVC  320           // cv padded channels
#define CH64 72            // 64-ch chunk LDS stride (64+8): bank-balanced

typedef __bf16  bf16x8 __attribute__((ext_vector_type(8)));
typedef float   f32x4  __attribute__((ext_vector_type(4)));
typedef unsigned short us8 __attribute__((ext_vector_type(8)));

// ---------------------------------------------------------------------------
// K1: per-pixel inverse L2 norm over 256 channels of f1 (NCHW input)
__global__ void norm_kernel(const float* __restrict__ f1, float* __restrict__ inv_norm) {
    int p = blockIdx.x * 256 + threadIdx.x;     // 0..16383
    if (p >= NPIX) return;
    int b = p >> 12;
    int hw = p & 4095;
    const float* base = f1 + (size_t)b * C * HW + hw;
    float s = 0.f;
    for (int c = 0; c < C; ++c) {
        float v = base[(size_t)c * HW];
        s += v * v;
    }
    float n = sqrtf(s);
    inv_norm[p] = 1.0f / fmaxf(n, 1e-12f);
}

// ---------------------------------------------------------------------------
// K2: NCHW fp32 -> NHWC bf16 transpose.
__global__ void transpose_kernel(const float* __restrict__ src, unsigned short* __restrict__ dst,
                                 const float* __restrict__ inv_norm, int padded) {
    __shared__ float tile[32][33];
    int blk = blockIdx.x;                 // 4096 blocks
    int pblk = blk & 127;
    int cblk = (blk >> 7) & 7;
    int b    = blk >> 10;
    int tx = threadIdx.x & 31, ty = threadIdx.x >> 5;
    int c0 = cblk * 32, p0 = pblk * 32;
    const float* s = src + (size_t)b * C * HW;
#pragma unroll
    for (int i = 0; i < 4; ++i) {
        int c = c0 + ty + 8 * i;
        tile[ty + 8 * i][tx] = s[(size_t)c * HW + p0 + tx];
    }
    __syncthreads();
#pragma unroll
    for (int i = 0; i < 4; ++i) {
        int p = p0 + ty + 8 * i;
        float v = tile[tx][ty + 8 * i];
        int c = c0 + tx;
        if (!padded) {
            v *= inv_norm[b * HW + p];
            __hip_bfloat16 hb = __float2bfloat16(v);
            dst[((size_t)b * HW + p) * C + c] = *(unsigned short*)&hb;
        } else {
            int h = p >> 6, w = p & 63;
            __hip_bfloat16 hb = __float2bfloat16(v);
            dst[(((size_t)b * PH + h + 8) * PW + (w + 8)) * C + c] = *(unsigned short*)&hb;
        }
    }
}

// ---------------------------------------------------------------------------
// Weight rearrange kernels
__global__ void rearrange_w1_bf(const float* __restrict__ w, unsigned short* __restrict__ wb) {
    // OIHW [144][289][3][3] -> bf16 [9][144][320] (ic zero-padded)
    int idx = blockIdx.x * 256 + threadIdx.x;
    if (idx >= 9 * C1 * ICP) return;
    int tap = idx / (C1 * ICP);
    int r = idx - tap * (C1 * ICP);
    int oc = r / ICP;
    int ic = r - oc * ICP;
    float v = (ic < NCH) ? w[((size_t)(oc * NCH + ic)) * 9 + tap] : 0.f;
    __hip_bfloat16 hb = __float2bfloat16(v);
    wb[idx] = *(unsigned short*)&hb;
}
__global__ void rearrange_w2_bf(const float* __restrict__ w, unsigned short* __restrict__ wb) {
    // OIHW [49][144][3][3] -> bf16 [9][64][160] (oc + ic zero-padded)
    int idx = blockIdx.x * 256 + threadIdx.x;
    if (idx >= 9 * 64 * IC2) return;
    int tap = idx / (64 * IC2);
    int r = idx - tap * (64 * IC2);
    int oc = r / IC2;
    int ic = r - oc * IC2;
    float v = (oc < C2 && ic < C1) ? w[((size_t)(oc * C1 + ic)) * 9 + tap] : 0.f;
    __hip_bfloat16 hb = __float2bfloat16(v);
    wb[idx] = *(unsigned short*)&hb;
}
__global__ void rearrange_dw_pad(const float* __restrict__ w, float* __restrict__ wr) {
    // [289][1][7][7] -> [49 taps][320 ch] zero-padded
    int idx = blockIdx.x * 256 + threadIdx.x;
    if (idx >= 49 * CVC) return;
    int tap = idx / CVC;
    int ch = idx - tap * CVC;
    wr[idx] = (ch < NCH) ? w[ch * 49 + tap] : 0.f;
}

// ---------------------------------------------------------------------------
// K3: cost volume via bf16 MFMA -> padded cvp [4][70][70][320] at (+3,+3).
// XCD-banded: XCD (blk&7) owns h in [xcd*8, xcd*8+8) for all (b,wseg) so the
// 17-row x2 reuse window lives in one XCD's L2.
__global__ void cv_mfma_kernel(const unsigned short* __restrict__ x1b,
                               const unsigned short* __restrict__ x2b,
                               float* __restrict__ cvp) {
    __shared__ __align__(16) unsigned short x1s[32 * ASTR];
    __shared__ __align__(16) unsigned short x2s[48 * ASTR];
    int i = blockIdx.x;                    // 512
    int xcd = i & 7;
    int j = i >> 3;                        // 0..63
    int wseg = j & 1;
    int h = xcd * 8 + ((j >> 1) & 7);
    int b = j >> 4;
    int w0 = wseg * 32;
    int t = threadIdx.x;

    const unsigned short* x1p = x1b + ((size_t)b * HW + h * 64 + w0) * C;
#pragma unroll
    for (int ii = 0; ii < 4; ++ii) {
        int v = t + ii * 256;
        int px = v >> 5, ch8 = v & 31;
        *(us8*)&x1s[px * ASTR + ch8 * 8] = *(const us8*)&x1p[px * 256 + ch8 * 8];
    }
    __syncthreads();

    int wave = t >> 6, lane = t & 63;
    int pt = wave >> 1, ct = wave & 1;
    int lrow = lane & 15, quad = lane >> 4;

    bf16x8 a[8];
#pragma unroll
    for (int kk = 0; kk < 8; ++kk)
        a[kk] = *(const bf16x8*)&x1s[(pt * 16 + lrow) * ASTR + kk * 32 + quad * 8];

    const unsigned short* x2base = x2b + (size_t)b * PH * PW * C;
    int col_l = ct * 16 + lrow;

    for (int dj = 0; dj < MO; ++dj) {
        __syncthreads();
        const unsigned short* rowp = x2base + ((size_t)(h + dj) * PW + w0) * C;
#pragma unroll
        for (int ii = 0; ii < 6; ++ii) {
            int v = t + ii * 256;
            int col = v >> 5, ch8 = v & 31;
            *(us8*)&x2s[col * ASTR + ch8 * 8] = *(const us8*)&rowp[col * 256 + ch8 * 8];
        }
        __syncthreads();

        f32x4 acc = {0.f, 0.f, 0.f, 0.f};
#pragma unroll
        for (int kk = 0; kk < 8; ++kk) {
            bf16x8 bb = *(const bf16x8*)&x2s[col_l * ASTR + kk * 32 + quad * 8];
            acc = __builtin_amdgcn_mfma_f32_16x16x32_bf16(a[kk], bb, acc, 0, 0, 0);
        }
#pragma unroll
        for (int r = 0; r < 4; ++r) {
            int px_l = pt * 16 + quad * 4 + r;
            int di = col_l - px_l;
            if ((unsigned)di <= 16u) {
                float v = acc[r] * (1.0f / 256.0f);
                cvp[(((size_t)b * CVP + h + 3) * CVP + (w0 + px_l + 3)) * CVC + dj * MO + di] =
                    (v > 0.f) ? v : 0.1f * v;
            }
        }
    }
}

// ---------------------------------------------------------------------------
// K4: depthwise 7x7 attention conv + multiply, LDS-tiled, XCD-banded by ty.
__global__ void dw_att_tiled(const float* __restrict__ cvp, const float* __restrict__ wdwp,
                             const float* __restrict__ att_b, unsigned short* __restrict__ av_pad) {
    __shared__ float actS[14 * 14 * 64];
    __shared__ float wdwS[49 * 64];
    int i = blockIdx.x;                    // 1280
    int ty = i & 7;                        // XCD band = tile row
    int j = i >> 3;                        // 0..159
    int cc = j % 5;
    int rest = j / 5;                      // 0..31
    int tx = rest & 7, b = rest >> 3;
    int x0 = tx * 8, y0 = ty * 8;
    int c0 = cc * 64;
    int t = threadIdx.x;

    const float* cvb = cvp + (((size_t)b * CVP + y0) * CVP + x0) * CVC + c0;
    for (int v = t; v < 14 * 14 * 16; v += 256) {
        int rc = v >> 4, c4 = v & 15;
        int yy = rc / 14, xx = rc - yy * 14;
        *(f32x4*)&actS[rc * 64 + c4 * 4] =
            *(const f32x4*)&cvb[((size_t)yy * CVP + xx) * CVC + c4 * 4];
    }
    for (int v = t; v < 49 * 64; v += 256) {
        int tap = v >> 6, ch = v & 63;
        wdwS[v] = wdwp[tap * CVC + c0 + ch];
    }
    __syncthreads();

    int ch_l = t & 63, pgrp = t >> 6;
    int ch = c0 + ch_l;
    float bv = (ch < NCH) ? att_b[ch] : 0.f;
    float acc[16];
#pragma unroll
    for (int ii = 0; ii < 16; ++ii) acc[ii] = bv;

    for (int dy = 0; dy < 7; ++dy) {
#pragma unroll
        for (int dx = 0; dx < 7; ++dx) {
            float wv = wdwS[(dy * 7 + dx) * 64 + ch_l];
#pragma unroll
            for (int ii = 0; ii < 16; ++ii) {
                int py = pgrp * 2 + (ii >> 3), px = ii & 7;
                float a = actS[((py + dy) * 14 + (px + dx)) * 64 + ch_l];
                acc[ii] += a * wv;
            }
        }
    }

    if (ch < NCH) {
#pragma unroll
        for (int ii = 0; ii < 16; ++ii) {
            int py = pgrp * 2 + (ii >> 3), px = ii & 7;
            float c0v = actS[((py + 3) * 14 + (px + 3)) * 64 + ch_l];
            __hip_bfloat16 hb = __float2bfloat16(c0v * acc[ii]);
            av_pad[(((size_t)b * 66 + y0 + py + 1) * 66 + (x0 + px + 1)) * ICP + ch] =
                *(unsigned short*)&hb;
        }
    }
}

// ---------------------------------------------------------------------------
// K5: conv3x3 289->144 + ReLU via bf16 MFMA, software-pipelined, XCD-banded.
__global__ void agg1_mfma_kernel(const unsigned short* __restrict__ av_pad,
                                 const unsigned short* __restrict__ wb1,
                                 const float* __restrict__ bias,
                                 unsigned short* __restrict__ h1p) {
    __shared__ __align__(16) unsigned short aS2[2][66 * CH64];   // 2 x 9.3 KB
    __shared__ __align__(16) unsigned short bS[2][C1 * CH64];    // 2 x 20.3 KB
    int i = blockIdx.x;                    // 256
    int xcd = i & 7;
    int j = i >> 3;                        // 0..31
    int h = xcd * 8 + (j & 7);
    int b = j >> 3;
    int t = threadIdx.x;
    int wave = t >> 6, lane = t & 63;
    int lrow = lane & 15, quad = lane >> 4;
    int ot0 = (wave == 0) ? 0 : (wave * 2 + 1);   // 0 / 3 / 5 / 7
    int nt  = (wave == 0) ? 3 : 2;

    f32x4 acc[4][3];
#pragma unroll
    for (int m = 0; m < 4; ++m)
#pragma unroll
        for (int ii = 0; ii < 3; ++ii) acc[m][ii] = (f32x4){0.f, 0.f, 0.f, 0.f};

    const unsigned short* avb = av_pad + (((size_t)b * 66 + h) * 66) * ICP;

    // ---- initial stage: A(dy=0,cc=0) -> aS2[0], B(tap0,cc=0) -> bS[0]
    {
        const unsigned short* arow = avb;
#pragma unroll
        for (int s = 0; s < 2; ++s) {
            int v = t + s * 256;
            *(us8*)&aS2[0][(v >> 3) * CH64 + (v & 7) * 8] =
                *(const us8*)&arow[(size_t)(v >> 3) * ICP + (v & 7) * 8];
        }
        if (t < 16) {
            int v = t + 512;
            *(us8*)&aS2[0][(v >> 3) * CH64 + (v & 7) * 8] =
                *(const us8*)&arow[(size_t)(v >> 3) * ICP + (v & 7) * 8];
        }
#pragma unroll
        for (int s = 0; s < 4; ++s) {
            int v = t + s * 256;
            *(us8*)&bS[0][(v >> 3) * CH64 + (v & 7) * 8] =
                *(const us8*)&wb1[(size_t)(v >> 3) * ICP + (v & 7) * 8];
        }
        if (t < 128) {
            int v = t + 1024;
            *(us8*)&bS[0][(v >> 3) * CH64 + (v & 7) * 8] =
                *(const us8*)&wb1[(size_t)(v >> 3) * ICP + (v & 7) * 8];
        }
    }
    __syncthreads();

    for (int k = 0; k < 45; ++k) {
        int rr = k % 15;
        int dx = rr % 3;
        int abuf = (k / 3) & 1, bbuf = k & 1;

        // ---- prefetch k+1 into regs
        us8 br[5], ar[3];
        int kn = k + 1;
        bool do_b = (kn < 45);
        bool do_a = do_b && (kn % 3 == 0);
        int dyn = kn / 15, rn = kn % 15;
        int ccin = rn / 3, dxn = rn % 3;
        if (do_b) {
            const unsigned short* wt = wb1 + ((size_t)(dyn * 3 + dxn) * C1) * ICP + ccin * 64;
#pragma unroll
            for (int s = 0; s < 4; ++s) {
                int v = t + s * 256;
                br[s] = *(const us8*)&wt[(size_t)(v >> 3) * ICP + (v & 7) * 8];
            }
            if (t < 128) {
                int v = t + 1024;
                br[4] = *(const us8*)&wt[(size_t)(v >> 3) * ICP + (v & 7) * 8];
            }
        }
        if (do_a) {
            const unsigned short* arow = avb + (size_t)dyn * 66 * ICP + ccin * 64;
#pragma unroll
            for (int s = 0; s < 2; ++s) {
                int v = t + s * 256;
                ar[s] = *(const us8*)&arow[(size_t)(v >> 3) * ICP + (v & 7) * 8];
            }
            if (t < 16) {
                int v = t + 512;
                ar[2] = *(const us8*)&arow[(size_t)(v >> 3) * ICP + (v & 7) * 8];
            }
        }

        // ---- MFMA burst on buffers(k)
        const unsigned short* aP = aS2[abuf];
        const unsigned short* bP = bS[bbuf];
#pragma unroll
        for (int cc2 = 0; cc2 < 2; ++cc2) {
            bf16x8 bfr[3];
#pragma unroll
            for (int ii = 0; ii < 3; ++ii)
                if (ii < nt)
                    bfr[ii] = *(const bf16x8*)&bP[((ot0 + ii) * 16 + lrow) * CH64 + cc2 * 32 + quad * 8];
#pragma unroll
            for (int m = 0; m < 4; ++m) {
                bf16x8 af = *(const bf16x8*)&aP[(m * 16 + lrow + dx) * CH64 + cc2 * 32 + quad * 8];
#pragma unroll
                for (int ii = 0; ii < 3; ++ii)
                    if (ii < nt)
                        acc[m][ii] = __builtin_amdgcn_mfma_f32_16x16x32_bf16(af, bfr[ii], acc[m][ii], 0, 0, 0);
            }
        }

        // ---- commit prefetched to the other buffers, one barrier
        if (do_b) {
            unsigned short* dst = bS[bbuf ^ 1];
#pragma unroll
            for (int s = 0; s < 4; ++s) {
                int v = t + s * 256;
                *(us8*)&dst[(v >> 3) * CH64 + (v & 7) * 8] = br[s];
            }
            if (t < 128) {
                int v = t + 1024;
                *(us8*)&dst[(v >> 3) * CH64 + (v & 7) * 8] = br[4];
            }
        }
        if (do_a) {
            unsigned short* dst = aS2[abuf ^ 1];
#pragma unroll
            for (int s = 0; s < 2; ++s) {
                int v = t + s * 256;
                *(us8*)&dst[(v >> 3) * CH64 + (v & 7) * 8] = ar[s];
            }
            if (t < 16) {
                int v = t + 512;
                *(us8*)&dst[(v >> 3) * CH64 + (v & 7) * 8] = ar[2];
            }
        }
        if (do_b) __syncthreads();
    }

    // ---- epilogue: bias + ReLU -> bf16 h1p at (h+1, w+1)
    size_t rowbase = ((size_t)b * 66 + h + 1) * 66;
#pragma unroll
    for (int m = 0; m < 4; ++m)
#pragma unroll
        for (int ii = 0; ii < 3; ++ii)
            if (ii < nt) {
                int oc = (ot0 + ii) * 16 + lrow;
                float bv = bias[oc];
#pragma unroll
                for (int r = 0; r < 4; ++r) {
                    int w = m * 16 + quad * 4 + r;
                    float val = fmaxf(acc[m][ii][r] + bv, 0.f);
                    __hip_bfloat16 hb = __float2bfloat16(val);
                    h1p[(rowbase + (w + 1)) * IC2 + oc] = *(unsigned short*)&hb;
                }
            }
}

// ---------------------------------------------------------------------------
// K6: conv3x3 144->49 + ReLU via bf16 MFMA, writes NCHW fp32 output. XCD-banded.
__global__ void agg2_mfma_kernel(const unsigned short* __restrict__ h1p,
                                 const unsigned short* __restrict__ wb2,
                                 const float* __restrict__ bias, float* __restrict__ out) {
    __shared__ __align__(16) unsigned short aS[66 * A2STR];   // 22.2 KB
    __shared__ __align__(16) unsigned short bS[64 * A2STR];   // 21.5 KB
    int i = blockIdx.x;                    // 256
    int xcd = i & 7;
    int j = i >> 3;                        // 0..31
    int h = xcd * 8 + (j & 7);
    int b = j >> 3;
    int t = threadIdx.x;
    int wave = t >> 6, lane = t & 63;
    int lrow = lane & 15, quad = lane >> 4;
    int pt = wave;

    f32x4 acc[4];
#pragma unroll
    for (int ot = 0; ot < 4; ++ot) acc[ot] = (f32x4){0.f, 0.f, 0.f, 0.f};

    const unsigned short* h1b = h1p + (((size_t)b * 66 + h) * 66) * IC2;

    for (int dy = 0; dy < 3; ++dy) {
        __syncthreads();
        const unsigned short* arow = h1b + (size_t)dy * 66 * IC2;
        for (int v = t; v < 66 * (IC2 / 8); v += 256) {
            int col = v / (IC2 / 8);
            int c8 = v - col * (IC2 / 8);
            *(us8*)&aS[col * A2STR + c8 * 8] = *(const us8*)&arow[col * IC2 + c8 * 8];
        }
        for (int dx = 0; dx < 3; ++dx) {
            int tap = dy * 3 + dx;
            if (dx != 0) __syncthreads();
            const unsigned short* wtap = wb2 + (size_t)tap * 64 * IC2;
            for (int v = t; v < 64 * (IC2 / 8); v += 256) {
                int oc = v / (IC2 / 8);
                int c8 = v - oc * (IC2 / 8);
                *(us8*)&bS[oc * A2STR + c8 * 8] = *(const us8*)&wtap[(size_t)oc * IC2 + c8 * 8];
            }
            __syncthreads();
#pragma unroll
            for (int cc = 0; cc < 5; ++cc) {
                bf16x8 af = *(const bf16x8*)&aS[(pt * 16 + lrow + dx) * A2STR + cc * 32 + quad * 8];
#pragma unroll
                for (int ot = 0; ot < 4; ++ot) {
                    bf16x8 bfr = *(const bf16x8*)&bS[(ot * 16 + lrow) * A2STR + cc * 32 + quad * 8];
                    acc[ot] = __builtin_amdgcn_mfma_f32_16x16x32_bf16(af, bfr, acc[ot], 0, 0, 0);
                }
            }
        }
    }

#pragma unroll
    for (int ot = 0; ot < 4; ++ot) {
        int o = ot * 16 + lrow;
        if (o < C2) {
            float bv = bias[o];
#pragma unroll
            for (int r = 0; r < 4; ++r) {
                int w = pt * 16 + quad * 4 + r;
                out[((size_t)b * C2 + o) * HW + h * 64 + w] = fmaxf(acc[ot][r] + bv, 0.f);
            }
        }
    }
}

// ---------------------------------------------------------------------------
extern "C" void kernel_launch(void* const* d_in, const int* in_sizes, int n_in,
                              void* d_out, int out_size, void* d_ws, size_t ws_size,
                              hipStream_t stream) {
    const float* f1    = (const float*)d_in[0];
    const float* f2    = (const float*)d_in[1];
    const float* att_w = (const float*)d_in[2];
    const float* att_b = (const float*)d_in[3];
    const float* w1    = (const float*)d_in[4];
    const float* b1    = (const float*)d_in[5];
    const float* w2    = (const float*)d_in[6];
    const float* b2    = (const float*)d_in[7];
    float* out = (float*)d_out;

    char* wsb = (char*)d_ws;
    size_t off = 0;
    float* inv_norm = (float*)(wsb + off); off += (size_t)NPIX * 4;
    float* cvp  = (float*)(wsb + off); off += (size_t)BS * CVP * CVP * CVC * 4;
    float* wdwp = (float*)(wsb + off); off += (size_t)49 * CVC * 4;
    off = (off + 15) & ~(size_t)15;
    unsigned short* x1bf = (unsigned short*)(wsb + off); off += (size_t)NPIX * C * 2;
    unsigned short* x2bf = (unsigned short*)(wsb + off); off += (size_t)BS * PH * PW * C * 2;
    unsigned short* avp  = (unsigned short*)(wsb + off); off += (size_t)BS * 66 * 66 * ICP * 2;
    unsigned short* wb1  = (unsigned short*)(wsb + off); off += (size_t)9 * C1 * ICP * 2;
    unsigned short* h1p  = (unsigned short*)(wsb + off); off += (size_t)BS * 66 * 66 * IC2 * 2;
    unsigned short* wb2  = (unsigned short*)(wsb + off); off += (size_t)9 * 64 * IC2 * 2;
    if (ws_size < off) return;

    hipMemsetAsync(x2bf, 0, (size_t)BS * PH * PW * C * 2, stream);
    hipMemsetAsync(cvp, 0, (size_t)BS * CVP * CVP * CVC * 4, stream);
    hipMemsetAsync(avp, 0, (size_t)BS * 66 * 66 * ICP * 2, stream);
    hipMemsetAsync(h1p, 0, (size_t)BS * 66 * 66 * IC2 * 2, stream);

    norm_kernel<<<NPIX / 256, 256, 0, stream>>>(f1, inv_norm);
    transpose_kernel<<<4096, 256, 0, stream>>>(f1, x1bf, inv_norm, 0);
    transpose_kernel<<<4096, 256, 0, stream>>>(f2, x2bf, nullptr, 1);

    rearrange_w1_bf<<<(9 * C1 * ICP + 255) / 256, 256, 0, stream>>>(w1, wb1);
    rearrange_w2_bf<<<(9 * 64 * IC2 + 255) / 256, 256, 0, stream>>>(w2, wb2);
    rearrange_dw_pad<<<(49 * CVC + 255) / 256, 256, 0, stream>>>(att_w, wdwp);

    cv_mfma_kernel<<<512, 256, 0, stream>>>(x1bf, x2bf, cvp);
    dw_att_tiled<<<1280, 256, 0, stream>>>(cvp, wdwp, att_b, avp);
    agg1_mfma_kernel<<<256, 256, 0, stream>>>(avp, wb1, b1, h1p);
    agg2_mfma_kernel<<<256, 256, 0, stream>>>(h1p, wb2, b2, out);
}

// Round 9
// 236.712 us; speedup vs baseline: 6.9483x; 1.0722x over previous
//
#include <hip/hip_runtime.h>
#include <hip/hip_bf16.h>

// Problem constants
#define BS   4
#define C    256
#define HW   4096          // 64*64
#define NPIX 16384         // 4*4096
#define NCH  289           // cost-volume channels (17*17)
#define MO   17
#define PH   80            // padded 64+2*8
#define PW   80
#define C1   144
#define C2   49
#define ASTR 264           // cv LDS row stride in bf16 elems
#define ICP  320           // agg1 padded input channels (289 -> 320)
#define IC2  160           // agg2 padded input channels (144 -> 160)
#define A2STR 168          // agg2 LDS row stride
#define CVP  70            // cv padded spatial (64 + 2*3)
#define CVC  320           // cv padded channels
#define CH64 72            // 64-ch chunk LDS stride (64+8): bank-balanced

typedef __bf16  bf16x8 __attribute__((ext_vector_type(8)));
typedef float   f32x4  __attribute__((ext_vector_type(4)));
typedef unsigned short us8 __attribute__((ext_vector_type(8)));

// ---------------------------------------------------------------------------
// K1: per-pixel inverse L2 norm over 256 channels of f1 (NCHW input)
__global__ void norm_kernel(const float* __restrict__ f1, float* __restrict__ inv_norm) {
    int p = blockIdx.x * 256 + threadIdx.x;     // 0..16383
    if (p >= NPIX) return;
    int b = p >> 12;
    int hw = p & 4095;
    const float* base = f1 + (size_t)b * C * HW + hw;
    float s = 0.f;
    for (int c = 0; c < C; ++c) {
        float v = base[(size_t)c * HW];
        s += v * v;
    }
    float n = sqrtf(s);
    inv_norm[p] = 1.0f / fmaxf(n, 1e-12f);
}

// ---------------------------------------------------------------------------
// K2: NCHW fp32 -> NHWC bf16 transpose.
__global__ void transpose_kernel(const float* __restrict__ src, unsigned short* __restrict__ dst,
                                 const float* __restrict__ inv_norm, int padded) {
    __shared__ float tile[32][33];
    int blk = blockIdx.x;                 // 4096 blocks
    int pblk = blk & 127;
    int cblk = (blk >> 7) & 7;
    int b    = blk >> 10;
    int tx = threadIdx.x & 31, ty = threadIdx.x >> 5;
    int c0 = cblk * 32, p0 = pblk * 32;
    const float* s = src + (size_t)b * C * HW;
#pragma unroll
    for (int i = 0; i < 4; ++i) {
        int c = c0 + ty + 8 * i;
        tile[ty + 8 * i][tx] = s[(size_t)c * HW + p0 + tx];
    }
    __syncthreads();
#pragma unroll
    for (int i = 0; i < 4; ++i) {
        int p = p0 + ty + 8 * i;
        float v = tile[tx][ty + 8 * i];
        int c = c0 + tx;
        if (!padded) {
            v *= inv_norm[b * HW + p];
            __hip_bfloat16 hb = __float2bfloat16(v);
            dst[((size_t)b * HW + p) * C + c] = *(unsigned short*)&hb;
        } else {
            int h = p >> 6, w = p & 63;
            __hip_bfloat16 hb = __float2bfloat16(v);
            dst[(((size_t)b * PH + h + 8) * PW + (w + 8)) * C + c] = *(unsigned short*)&hb;
        }
    }
}

// ---------------------------------------------------------------------------
// Weight rearrange kernels
__global__ void rearrange_w1_bf(const float* __restrict__ w, unsigned short* __restrict__ wb) {
    // OIHW [144][289][3][3] -> bf16 [9][144][320] (ic zero-padded)
    int idx = blockIdx.x * 256 + threadIdx.x;
    if (idx >= 9 * C1 * ICP) return;
    int tap = idx / (C1 * ICP);
    int r = idx - tap * (C1 * ICP);
    int oc = r / ICP;
    int ic = r - oc * ICP;
    float v = (ic < NCH) ? w[((size_t)(oc * NCH + ic)) * 9 + tap] : 0.f;
    __hip_bfloat16 hb = __float2bfloat16(v);
    wb[idx] = *(unsigned short*)&hb;
}
__global__ void rearrange_w2_bf(const float* __restrict__ w, unsigned short* __restrict__ wb) {
    // OIHW [49][144][3][3] -> bf16 [9][64][160] (oc + ic zero-padded)
    int idx = blockIdx.x * 256 + threadIdx.x;
    if (idx >= 9 * 64 * IC2) return;
    int tap = idx / (64 * IC2);
    int r = idx - tap * (64 * IC2);
    int oc = r / IC2;
    int ic = r - oc * IC2;
    float v = (oc < C2 && ic < C1) ? w[((size_t)(oc * C1 + ic)) * 9 + tap] : 0.f;
    __hip_bfloat16 hb = __float2bfloat16(v);
    wb[idx] = *(unsigned short*)&hb;
}
__global__ void rearrange_dw_pad(const float* __restrict__ w, float* __restrict__ wr) {
    // [289][1][7][7] -> [49 taps][320 ch] zero-padded
    int idx = blockIdx.x * 256 + threadIdx.x;
    if (idx >= 49 * CVC) return;
    int tap = idx / CVC;
    int ch = idx - tap * CVC;
    wr[idx] = (ch < NCH) ? w[ch * 49 + tap] : 0.f;
}

// ---------------------------------------------------------------------------
// K3: cost volume via bf16 MFMA -> padded cvp [4][70][70][320] at (+3,+3).
// Row-sharing restructure: block = (b, 4-row h-quad, 16-col wseg), 256 blocks.
// Wave = one h-row (16 px). Staged x2 row (32 cols x 256 ch) is consumed by
// all 4 rows at dj = rr - r. Register prefetch + double-buffered LDS, one
// barrier per stage (20 stages). A-frags loaded once from global (L2-hot).
// Logical x2 traffic: 256 x 20 x 16.4 KB = 84 MB (was 215 MB).
__global__ void cv_mfma_kernel(const unsigned short* __restrict__ x1b,
                               const unsigned short* __restrict__ x2b,
                               float* __restrict__ cvp) {
    __shared__ __align__(16) unsigned short x2s[2][32 * ASTR];   // 2 x 16.9 KB
    int i = blockIdx.x;                    // 256
    int xcd = i & 7;
    int j = i >> 3;                        // 0..31
    int hq = xcd * 2 + (j & 1);            // h-quad 0..15, XCD-banded
    int jj = j >> 1;                       // 0..15
    int wseg = jj & 3;
    int b = jj >> 2;
    int h0 = hq * 4;
    int w0 = wseg * 16;
    int t = threadIdx.x;
    int wave = t >> 6, lane = t & 63;
    int lrow = lane & 15, quad = lane >> 4;
    int h = h0 + wave;                     // this wave's output row

    // A-frags direct from global: A[m=lrow][k=kk*32+quad*8..+8], px = w0+lrow
    const unsigned short* x1p = x1b + ((size_t)b * HW + h * 64 + w0) * C;
    bf16x8 a[8];
#pragma unroll
    for (int kk = 0; kk < 8; ++kk)
        a[kk] = *(const bf16x8*)&x1p[(size_t)lrow * C + kk * 32 + quad * 8];

    const unsigned short* x2base = x2b + (size_t)b * PH * PW * C;

    // initial stage: rr=0 (padded row h0, cols w0..w0+31)
    {
        const unsigned short* rowp = x2base + ((size_t)h0 * PW + w0) * C;
#pragma unroll
        for (int s = 0; s < 4; ++s) {
            int v = t + s * 256;           // 0..1023 us8 index
            int col = v >> 5, ch8 = v & 31;
            *(us8*)&x2s[0][col * ASTR + ch8 * 8] = *(const us8*)&rowp[(size_t)col * C + ch8 * 8];
        }
    }
    __syncthreads();

    for (int rr = 0; rr < 20; ++rr) {
        // ---- prefetch row rr+1 into regs
        us8 pr[4];
        bool dop = (rr + 1 < 20);
        if (dop) {
            const unsigned short* rowp = x2base + ((size_t)(h0 + rr + 1) * PW + w0) * C;
#pragma unroll
            for (int s = 0; s < 4; ++s) {
                int v = t + s * 256;
                int col = v >> 5, ch8 = v & 31;
                pr[s] = *(const us8*)&rowp[(size_t)col * C + ch8 * 8];
            }
        }

        // ---- compute on staged row rr (this wave's dj = rr - wave)
        int dj = rr - wave;
        if ((unsigned)dj <= 16u) {
            const unsigned short* xs = x2s[rr & 1];
#pragma unroll
            for (int c = 0; c < 2; ++c) {
                f32x4 acc = {0.f, 0.f, 0.f, 0.f};
#pragma unroll
                for (int kk = 0; kk < 8; ++kk) {
                    bf16x8 bb = *(const bf16x8*)&xs[(c * 16 + lrow) * ASTR + kk * 32 + quad * 8];
                    acc = __builtin_amdgcn_mfma_f32_16x16x32_bf16(a[kk], bb, acc, 0, 0, 0);
                }
#pragma unroll
                for (int r = 0; r < 4; ++r) {
                    int px_l = quad * 4 + r;               // D row = px within tile
                    int di = c * 16 + lrow - px_l;         // D col = staged x2 col
                    if ((unsigned)di <= 16u) {
                        float v = acc[r] * (1.0f / 256.0f);
                        cvp[(((size_t)b * CVP + h + 3) * CVP + (w0 + px_l + 3)) * CVC + dj * MO + di] =
                            (v > 0.f) ? v : 0.1f * v;
                    }
                }
            }
        }

        // ---- commit prefetched row to other buffer, one barrier
        if (dop) {
            unsigned short* dst = x2s[(rr + 1) & 1];
#pragma unroll
            for (int s = 0; s < 4; ++s) {
                int v = t + s * 256;
                int col = v >> 5, ch8 = v & 31;
                *(us8*)&dst[col * ASTR + ch8 * 8] = pr[s];
            }
            __syncthreads();
        }
    }
}

// ---------------------------------------------------------------------------
// K4: depthwise 7x7 attention conv + multiply, LDS-tiled, XCD-banded by ty.
__global__ void dw_att_tiled(const float* __restrict__ cvp, const float* __restrict__ wdwp,
                             const float* __restrict__ att_b, unsigned short* __restrict__ av_pad) {
    __shared__ float actS[14 * 14 * 64];
    __shared__ float wdwS[49 * 64];
    int i = blockIdx.x;                    // 1280
    int ty = i & 7;                        // XCD band = tile row
    int j = i >> 3;                        // 0..159
    int cc = j % 5;
    int rest = j / 5;                      // 0..31
    int tx = rest & 7, b = rest >> 3;
    int x0 = tx * 8, y0 = ty * 8;
    int c0 = cc * 64;
    int t = threadIdx.x;

    const float* cvb = cvp + (((size_t)b * CVP + y0) * CVP + x0) * CVC + c0;
    for (int v = t; v < 14 * 14 * 16; v += 256) {
        int rc = v >> 4, c4 = v & 15;
        int yy = rc / 14, xx = rc - yy * 14;
        *(f32x4*)&actS[rc * 64 + c4 * 4] =
            *(const f32x4*)&cvb[((size_t)yy * CVP + xx) * CVC + c4 * 4];
    }
    for (int v = t; v < 49 * 64; v += 256) {
        int tap = v >> 6, ch = v & 63;
        wdwS[v] = wdwp[tap * CVC + c0 + ch];
    }
    __syncthreads();

    int ch_l = t & 63, pgrp = t >> 6;
    int ch = c0 + ch_l;
    float bv = (ch < NCH) ? att_b[ch] : 0.f;
    float acc[16];
#pragma unroll
    for (int ii = 0; ii < 16; ++ii) acc[ii] = bv;

    for (int dy = 0; dy < 7; ++dy) {
#pragma unroll
        for (int dx = 0; dx < 7; ++dx) {
            float wv = wdwS[(dy * 7 + dx) * 64 + ch_l];
#pragma unroll
            for (int ii = 0; ii < 16; ++ii) {
                int py = pgrp * 2 + (ii >> 3), px = ii & 7;
                float a = actS[((py + dy) * 14 + (px + dx)) * 64 + ch_l];
                acc[ii] += a * wv;
            }
        }
    }

    if (ch < NCH) {
#pragma unroll
        for (int ii = 0; ii < 16; ++ii) {
            int py = pgrp * 2 + (ii >> 3), px = ii & 7;
            float c0v = actS[((py + 3) * 14 + (px + 3)) * 64 + ch_l];
            __hip_bfloat16 hb = __float2bfloat16(c0v * acc[ii]);
            av_pad[(((size_t)b * 66 + y0 + py + 1) * 66 + (x0 + px + 1)) * ICP + ch] =
                *(unsigned short*)&hb;
        }
    }
}

// ---------------------------------------------------------------------------
// K5: conv3x3 289->144 + ReLU via bf16 MFMA, software-pipelined, XCD-banded.
__global__ void agg1_mfma_kernel(const unsigned short* __restrict__ av_pad,
                                 const unsigned short* __restrict__ wb1,
                                 const float* __restrict__ bias,
                                 unsigned short* __restrict__ h1p) {
    __shared__ __align__(16) unsigned short aS2[2][66 * CH64];   // 2 x 9.3 KB
    __shared__ __align__(16) unsigned short bS[2][C1 * CH64];    // 2 x 20.3 KB
    int i = blockIdx.x;                    // 256
    int xcd = i & 7;
    int j = i >> 3;                        // 0..31
    int h = xcd * 8 + (j & 7);
    int b = j >> 3;
    int t = threadIdx.x;
    int wave = t >> 6, lane = t & 63;
    int lrow = lane & 15, quad = lane >> 4;
    int ot0 = (wave == 0) ? 0 : (wave * 2 + 1);   // 0 / 3 / 5 / 7
    int nt  = (wave == 0) ? 3 : 2;

    f32x4 acc[4][3];
#pragma unroll
    for (int m = 0; m < 4; ++m)
#pragma unroll
        for (int ii = 0; ii < 3; ++ii) acc[m][ii] = (f32x4){0.f, 0.f, 0.f, 0.f};

    const unsigned short* avb = av_pad + (((size_t)b * 66 + h) * 66) * ICP;

    // ---- initial stage: A(dy=0,cc=0) -> aS2[0], B(tap0,cc=0) -> bS[0]
    {
        const unsigned short* arow = avb;
#pragma unroll
        for (int s = 0; s < 2; ++s) {
            int v = t + s * 256;
            *(us8*)&aS2[0][(v >> 3) * CH64 + (v & 7) * 8] =
                *(const us8*)&arow[(size_t)(v >> 3) * ICP + (v & 7) * 8];
        }
        if (t < 16) {
            int v = t + 512;
            *(us8*)&aS2[0][(v >> 3) * CH64 + (v & 7) * 8] =
                *(const us8*)&arow[(size_t)(v >> 3) * ICP + (v & 7) * 8];
        }
#pragma unroll
        for (int s = 0; s < 4; ++s) {
            int v = t + s * 256;
            *(us8*)&bS[0][(v >> 3) * CH64 + (v & 7) * 8] =
                *(const us8*)&wb1[(size_t)(v >> 3) * ICP + (v & 7) * 8];
        }
        if (t < 128) {
            int v = t + 1024;
            *(us8*)&bS[0][(v >> 3) * CH64 + (v & 7) * 8] =
                *(const us8*)&wb1[(size_t)(v >> 3) * ICP + (v & 7) * 8];
        }
    }
    __syncthreads();

    for (int k = 0; k < 45; ++k) {
        int rr = k % 15;
        int dx = rr % 3;
        int abuf = (k / 3) & 1, bbuf = k & 1;

        // ---- prefetch k+1 into regs
        us8 br[5], ar[3];
        int kn = k + 1;
        bool do_b = (kn < 45);
        bool do_a = do_b && (kn % 3 == 0);
        int dyn = kn / 15, rn = kn % 15;
        int ccin = rn / 3, dxn = rn % 3;
        if (do_b) {
            const unsigned short* wt = wb1 + ((size_t)(dyn * 3 + dxn) * C1) * ICP + ccin * 64;
#pragma unroll
            for (int s = 0; s < 4; ++s) {
                int v = t + s * 256;
                br[s] = *(const us8*)&wt[(size_t)(v >> 3) * ICP + (v & 7) * 8];
            }
            if (t < 128) {
                int v = t + 1024;
                br[4] = *(const us8*)&wt[(size_t)(v >> 3) * ICP + (v & 7) * 8];
            }
        }
        if (do_a) {
            const unsigned short* arow = avb + (size_t)dyn * 66 * ICP + ccin * 64;
#pragma unroll
            for (int s = 0; s < 2; ++s) {
                int v = t + s * 256;
                ar[s] = *(const us8*)&arow[(size_t)(v >> 3) * ICP + (v & 7) * 8];
            }
            if (t < 16) {
                int v = t + 512;
                ar[2] = *(const us8*)&arow[(size_t)(v >> 3) * ICP + (v & 7) * 8];
            }
        }

        // ---- MFMA burst on buffers(k)
        const unsigned short* aP = aS2[abuf];
        const unsigned short* bP = bS[bbuf];
#pragma unroll
        for (int cc2 = 0; cc2 < 2; ++cc2) {
            bf16x8 bfr[3];
#pragma unroll
            for (int ii = 0; ii < 3; ++ii)
                if (ii < nt)
                    bfr[ii] = *(const bf16x8*)&bP[((ot0 + ii) * 16 + lrow) * CH64 + cc2 * 32 + quad * 8];
#pragma unroll
            for (int m = 0; m < 4; ++m) {
                bf16x8 af = *(const bf16x8*)&aP[(m * 16 + lrow + dx) * CH64 + cc2 * 32 + quad * 8];
#pragma unroll
                for (int ii = 0; ii < 3; ++ii)
                    if (ii < nt)
                        acc[m][ii] = __builtin_amdgcn_mfma_f32_16x16x32_bf16(af, bfr[ii], acc[m][ii], 0, 0, 0);
            }
        }

        // ---- commit prefetched to the other buffers, one barrier
        if (do_b) {
            unsigned short* dst = bS[bbuf ^ 1];
#pragma unroll
            for (int s = 0; s < 4; ++s) {
                int v = t + s * 256;
                *(us8*)&dst[(v >> 3) * CH64 + (v & 7) * 8] = br[s];
            }
            if (t < 128) {
                int v = t + 1024;
                *(us8*)&dst[(v >> 3) * CH64 + (v & 7) * 8] = br[4];
            }
        }
        if (do_a) {
            unsigned short* dst = aS2[abuf ^ 1];
#pragma unroll
            for (int s = 0; s < 2; ++s) {
                int v = t + s * 256;
                *(us8*)&dst[(v >> 3) * CH64 + (v & 7) * 8] = ar[s];
            }
            if (t < 16) {
                int v = t + 512;
                *(us8*)&dst[(v >> 3) * CH64 + (v & 7) * 8] = ar[2];
            }
        }
        if (do_b) __syncthreads();
    }

    // ---- epilogue: bias + ReLU -> bf16 h1p at (h+1, w+1)
    size_t rowbase = ((size_t)b * 66 + h + 1) * 66;
#pragma unroll
    for (int m = 0; m < 4; ++m)
#pragma unroll
        for (int ii = 0; ii < 3; ++ii)
            if (ii < nt) {
                int oc = (ot0 + ii) * 16 + lrow;
                float bv = bias[oc];
#pragma unroll
                for (int r = 0; r < 4; ++r) {
                    int w = m * 16 + quad * 4 + r;
                    float val = fmaxf(acc[m][ii][r] + bv, 0.f);
                    __hip_bfloat16 hb = __float2bfloat16(val);
                    h1p[(rowbase + (w + 1)) * IC2 + oc] = *(unsigned short*)&hb;
                }
            }
}

// ---------------------------------------------------------------------------
// K6: conv3x3 144->49 + ReLU via bf16 MFMA, writes NCHW fp32 output. XCD-banded.
__global__ void agg2_mfma_kernel(const unsigned short* __restrict__ h1p,
                                 const unsigned short* __restrict__ wb2,
                                 const float* __restrict__ bias, float* __restrict__ out) {
    __shared__ __align__(16) unsigned short aS[66 * A2STR];   // 22.2 KB
    __shared__ __align__(16) unsigned short bS[64 * A2STR];   // 21.5 KB
    int i = blockIdx.x;                    // 256
    int xcd = i & 7;
    int j = i >> 3;                        // 0..31
    int h = xcd * 8 + (j & 7);
    int b = j >> 3;
    int t = threadIdx.x;
    int wave = t >> 6, lane = t & 63;
    int lrow = lane & 15, quad = lane >> 4;
    int pt = wave;

    f32x4 acc[4];
#pragma unroll
    for (int ot = 0; ot < 4; ++ot) acc[ot] = (f32x4){0.f, 0.f, 0.f, 0.f};

    const unsigned short* h1b = h1p + (((size_t)b * 66 + h) * 66) * IC2;

    for (int dy = 0; dy < 3; ++dy) {
        __syncthreads();
        const unsigned short* arow = h1b + (size_t)dy * 66 * IC2;
        for (int v = t; v < 66 * (IC2 / 8); v += 256) {
            int col = v / (IC2 / 8);
            int c8 = v - col * (IC2 / 8);
            *(us8*)&aS[col * A2STR + c8 * 8] = *(const us8*)&arow[col * IC2 + c8 * 8];
        }
        for (int dx = 0; dx < 3; ++dx) {
            int tap = dy * 3 + dx;
            if (dx != 0) __syncthreads();
            const unsigned short* wtap = wb2 + (size_t)tap * 64 * IC2;
            for (int v = t; v < 64 * (IC2 / 8); v += 256) {
                int oc = v / (IC2 / 8);
                int c8 = v - oc * (IC2 / 8);
                *(us8*)&bS[oc * A2STR + c8 * 8] = *(const us8*)&wtap[(size_t)oc * IC2 + c8 * 8];
            }
            __syncthreads();
#pragma unroll
            for (int cc = 0; cc < 5; ++cc) {
                bf16x8 af = *(const bf16x8*)&aS[(pt * 16 + lrow + dx) * A2STR + cc * 32 + quad * 8];
#pragma unroll
                for (int ot = 0; ot < 4; ++ot) {
                    bf16x8 bfr = *(const bf16x8*)&bS[(ot * 16 + lrow) * A2STR + cc * 32 + quad * 8];
                    acc[ot] = __builtin_amdgcn_mfma_f32_16x16x32_bf16(af, bfr, acc[ot], 0, 0, 0);
                }
            }
        }
    }

#pragma unroll
    for (int ot = 0; ot < 4; ++ot) {
        int o = ot * 16 + lrow;
        if (o < C2) {
            float bv = bias[o];
#pragma unroll
            for (int r = 0; r < 4; ++r) {
                int w = pt * 16 + quad * 4 + r;
                out[((size_t)b * C2 + o) * HW + h * 64 + w] = fmaxf(acc[ot][r] + bv, 0.f);
            }
        }
    }
}

// ---------------------------------------------------------------------------
extern "C" void kernel_launch(void* const* d_in, const int* in_sizes, int n_in,
                              void* d_out, int out_size, void* d_ws, size_t ws_size,
                              hipStream_t stream) {
    const float* f1    = (const float*)d_in[0];
    const float* f2    = (const float*)d_in[1];
    const float* att_w = (const float*)d_in[2];
    const float* att_b = (const float*)d_in[3];
    const float* w1    = (const float*)d_in[4];
    const float* b1    = (const float*)d_in[5];
    const float* w2    = (const float*)d_in[6];
    const float* b2    = (const float*)d_in[7];
    float* out = (float*)d_out;

    char* wsb = (char*)d_ws;
    size_t off = 0;
    float* inv_norm = (float*)(wsb + off); off += (size_t)NPIX * 4;
    float* cvp  = (float*)(wsb + off); off += (size_t)BS * CVP * CVP * CVC * 4;
    float* wdwp = (float*)(wsb + off); off += (size_t)49 * CVC * 4;
    off = (off + 15) & ~(size_t)15;
    unsigned short* x1bf = (unsigned short*)(wsb + off); off += (size_t)NPIX * C * 2;
    unsigned short* x2bf = (unsigned short*)(wsb + off); off += (size_t)BS * PH * PW * C * 2;
    unsigned short* avp  = (unsigned short*)(wsb + off); off += (size_t)BS * 66 * 66 * ICP * 2;
    unsigned short* wb1  = (unsigned short*)(wsb + off); off += (size_t)9 * C1 * ICP * 2;
    unsigned short* h1p  = (unsigned short*)(wsb + off); off += (size_t)BS * 66 * 66 * IC2 * 2;
    unsigned short* wb2  = (unsigned short*)(wsb + off); off += (size_t)9 * 64 * IC2 * 2;
    if (ws_size < off) return;

    hipMemsetAsync(x2bf, 0, (size_t)BS * PH * PW * C * 2, stream);
    hipMemsetAsync(cvp, 0, (size_t)BS * CVP * CVP * CVC * 4, stream);
    hipMemsetAsync(avp, 0, (size_t)BS * 66 * 66 * ICP * 2, stream);
    hipMemsetAsync(h1p, 0, (size_t)BS * 66 * 66 * IC2 * 2, stream);

    norm_kernel<<<NPIX / 256, 256, 0, stream>>>(f1, inv_norm);
    transpose_kernel<<<4096, 256, 0, stream>>>(f1, x1bf, inv_norm, 0);
    transpose_kernel<<<4096, 256, 0, stream>>>(f2, x2bf, nullptr, 1);

    rearrange_w1_bf<<<(9 * C1 * ICP + 255) / 256, 256, 0, stream>>>(w1, wb1);
    rearrange_w2_bf<<<(9 * 64 * IC2 + 255) / 256, 256, 0, stream>>>(w2, wb2);
    rearrange_dw_pad<<<(49 * CVC + 255) / 256, 256, 0, stream>>>(att_w, wdwp);

    cv_mfma_kernel<<<256, 256, 0, stream>>>(x1bf, x2bf, cvp);
    dw_att_tiled<<<1280, 256, 0, stream>>>(cvp, wdwp, att_b, avp);
    agg1_mfma_kernel<<<256, 256, 0, stream>>>(avp, wb1, b1, h1p);
    agg2_mfma_kernel<<<256, 256, 0, stream>>>(h1p, wb2, b2, out);
}

// Round 10
// 213.303 us; speedup vs baseline: 7.7108x; 1.1097x over previous
//
#include <hip/hip_runtime.h>
#include <hip/hip_bf16.h>

// Problem constants
#define BS   4
#define C    256
#define HW   4096          // 64*64
#define NPIX 16384         // 4*4096
#define NCH  289           // cost-volume channels (17*17)
#define MO   17
#define PH   80            // padded 64+2*8
#define PW   80
#define C1   144
#define C2   49
#define ASTR 264           // cv LDS row stride in bf16 elems
#define ICP  320           // agg1 padded input channels (289 -> 320)
#define IC2  160           // agg2 padded input channels (144 -> 160)
#define A2STR 168          // agg2 LDS row stride
#define CVP  70            // cv padded spatial (64 + 2*3)
#define CVC  320           // cv padded channels
#define CH64 72            // 64-ch chunk LDS stride (64+8): bank-balanced

typedef __bf16  bf16x8 __attribute__((ext_vector_type(8)));
typedef float   f32x4  __attribute__((ext_vector_type(4)));
typedef unsigned short us8 __attribute__((ext_vector_type(8)));

// ---------------------------------------------------------------------------
// K1: fused L2-norm + NCHW->NHWC bf16 transpose for f1. Reads f1 ONCE.
// Block = (b, 32 px). LDS tileT[px][ch] stride 257 (conflict-free).
__global__ void fused_norm_transpose(const float* __restrict__ f1,
                                     unsigned short* __restrict__ dst) {
    __shared__ float tileT[32 * 257];
    __shared__ float invS[32];
    int blk = blockIdx.x;                 // 512 = 4b * 128
    int pblk = blk & 127, b = blk >> 7;
    int p0 = pblk * 32;
    int t = threadIdx.x;
    int tx = t & 31, ty = t >> 5;
    const float* s = f1 + (size_t)b * C * HW;
#pragma unroll
    for (int i = 0; i < 32; ++i) {
        int c = ty + 8 * i;
        tileT[tx * 257 + c] = s[(size_t)c * HW + p0 + tx];
    }
    __syncthreads();
    // per-px inv norm: 8 lanes per px
    int lane = t & 63, wave = t >> 6;
    int px = wave * 8 + (lane >> 3);
    int l = lane & 7;
    float ssum = 0.f;
#pragma unroll
    for (int j = 0; j < 32; ++j) {
        float v = tileT[px * 257 + l + 8 * j];
        ssum += v * v;
    }
    ssum += __shfl_xor(ssum, 1);
    ssum += __shfl_xor(ssum, 2);
    ssum += __shfl_xor(ssum, 4);
    if (l == 0) invS[px] = 1.0f / fmaxf(sqrtf(ssum), 1e-12f);
    __syncthreads();
    // write scaled bf16 NHWC
#pragma unroll 4
    for (int p = 0; p < 32; ++p) {
        float v = tileT[p * 257 + t] * invS[p];
        __hip_bfloat16 hb = __float2bfloat16(v);
        dst[((size_t)b * HW + p0 + p) * C + t] = *(unsigned short*)&hb;
    }
}

// ---------------------------------------------------------------------------
// K2: NCHW fp32 -> padded NHWC bf16 transpose (f2 only).
__global__ void transpose_pad_kernel(const float* __restrict__ src,
                                     unsigned short* __restrict__ dst) {
    __shared__ float tile[32][33];
    int blk = blockIdx.x;                 // 4096 blocks
    int pblk = blk & 127;
    int cblk = (blk >> 7) & 7;
    int b    = blk >> 10;
    int tx = threadIdx.x & 31, ty = threadIdx.x >> 5;
    int c0 = cblk * 32, p0 = pblk * 32;
    const float* s = src + (size_t)b * C * HW;
#pragma unroll
    for (int i = 0; i < 4; ++i) {
        int c = c0 + ty + 8 * i;
        tile[ty + 8 * i][tx] = s[(size_t)c * HW + p0 + tx];
    }
    __syncthreads();
#pragma unroll
    for (int i = 0; i < 4; ++i) {
        int p = p0 + ty + 8 * i;
        float v = tile[tx][ty + 8 * i];
        int c = c0 + tx;
        int h = p >> 6, w = p & 63;
        __hip_bfloat16 hb = __float2bfloat16(v);
        dst[(((size_t)b * PH + h + 8) * PW + (w + 8)) * C + c] = *(unsigned short*)&hb;
    }
}

// ---------------------------------------------------------------------------
// Generic halo-zero: zeroes the spatial pad frame of a [nb][H][H][Cc] ushort
// buffer (Cc multiple of 8). Interior + interior ch-pad left untouched.
__global__ void halo_zero(unsigned short* __restrict__ p, int H, int halo, int Cc) {
    int W = H;
    int inter = H - 2 * halo;
    int total_pos = H * W - inter * inter;
    int chunks = Cc >> 3;
    size_t tot = (size_t)total_pos * chunks * BS;
    size_t idx = (size_t)blockIdx.x * 256 + threadIdx.x;
    if (idx >= tot) return;
    int c8 = (int)(idx % chunks);
    size_t r = idx / chunks;
    int pos = (int)(r % total_pos);
    int b = (int)(r / total_pos);
    int h, w;
    int topbot = 2 * halo * W;
    if (pos < halo * W) { h = pos / W; w = pos % W; }
    else if (pos < topbot) { int q = pos - halo * W; h = H - halo + q / W; w = q % W; }
    else {
        int q = pos - topbot;
        int row = q / (2 * halo), off = q % (2 * halo);
        h = halo + row;
        w = (off < halo) ? off : (W - 2 * halo + off);
    }
    us8 z = {0, 0, 0, 0, 0, 0, 0, 0};
    *(us8*)&p[(((size_t)b * H + h) * W + w) * Cc + c8 * 8] = z;
}

// ---------------------------------------------------------------------------
// Weight rearrange kernels
__global__ void rearrange_w1_bf(const float* __restrict__ w, unsigned short* __restrict__ wb) {
    int idx = blockIdx.x * 256 + threadIdx.x;
    if (idx >= 9 * C1 * ICP) return;
    int tap = idx / (C1 * ICP);
    int r = idx - tap * (C1 * ICP);
    int oc = r / ICP;
    int ic = r - oc * ICP;
    float v = (ic < NCH) ? w[((size_t)(oc * NCH + ic)) * 9 + tap] : 0.f;
    __hip_bfloat16 hb = __float2bfloat16(v);
    wb[idx] = *(unsigned short*)&hb;
}
__global__ void rearrange_w2_bf(const float* __restrict__ w, unsigned short* __restrict__ wb) {
    int idx = blockIdx.x * 256 + threadIdx.x;
    if (idx >= 9 * 64 * IC2) return;
    int tap = idx / (64 * IC2);
    int r = idx - tap * (64 * IC2);
    int oc = r / IC2;
    int ic = r - oc * IC2;
    float v = (oc < C2 && ic < C1) ? w[((size_t)(oc * C1 + ic)) * 9 + tap] : 0.f;
    __hip_bfloat16 hb = __float2bfloat16(v);
    wb[idx] = *(unsigned short*)&hb;
}
__global__ void rearrange_dw_pad(const float* __restrict__ w, float* __restrict__ wr) {
    int idx = blockIdx.x * 256 + threadIdx.x;
    if (idx >= 49 * CVC) return;
    int tap = idx / CVC;
    int ch = idx - tap * CVC;
    wr[idx] = (ch < NCH) ? w[ch * 49 + tap] : 0.f;
}

// ---------------------------------------------------------------------------
// K3: cost volume via bf16 MFMA -> padded bf16 cvp [4][70][70][320] at (+3,+3).
// Row-sharing: block = (b, 4-row h-quad, 16-col wseg), 256 blocks; wave = row.
__global__ void cv_mfma_kernel(const unsigned short* __restrict__ x1b,
                               const unsigned short* __restrict__ x2b,
                               unsigned short* __restrict__ cvp) {
    __shared__ __align__(16) unsigned short x2s[2][32 * ASTR];
    int i = blockIdx.x;                    // 256
    int xcd = i & 7;
    int j = i >> 3;
    int hq = xcd * 2 + (j & 1);
    int jj = j >> 1;
    int wseg = jj & 3;
    int b = jj >> 2;
    int h0 = hq * 4;
    int w0 = wseg * 16;
    int t = threadIdx.x;
    int wave = t >> 6, lane = t & 63;
    int lrow = lane & 15, quad = lane >> 4;
    int h = h0 + wave;

    const unsigned short* x1p = x1b + ((size_t)b * HW + h * 64 + w0) * C;
    bf16x8 a[8];
#pragma unroll
    for (int kk = 0; kk < 8; ++kk)
        a[kk] = *(const bf16x8*)&x1p[(size_t)lrow * C + kk * 32 + quad * 8];

    const unsigned short* x2base = x2b + (size_t)b * PH * PW * C;

    {
        const unsigned short* rowp = x2base + ((size_t)h0 * PW + w0) * C;
#pragma unroll
        for (int s = 0; s < 4; ++s) {
            int v = t + s * 256;
            int col = v >> 5, ch8 = v & 31;
            *(us8*)&x2s[0][col * ASTR + ch8 * 8] = *(const us8*)&rowp[(size_t)col * C + ch8 * 8];
        }
    }
    __syncthreads();

    for (int rr = 0; rr < 20; ++rr) {
        us8 pr[4];
        bool dop = (rr + 1 < 20);
        if (dop) {
            const unsigned short* rowp = x2base + ((size_t)(h0 + rr + 1) * PW + w0) * C;
#pragma unroll
            for (int s = 0; s < 4; ++s) {
                int v = t + s * 256;
                int col = v >> 5, ch8 = v & 31;
                pr[s] = *(const us8*)&rowp[(size_t)col * C + ch8 * 8];
            }
        }

        int dj = rr - wave;
        if ((unsigned)dj <= 16u) {
            const unsigned short* xs = x2s[rr & 1];
#pragma unroll
            for (int c = 0; c < 2; ++c) {
                f32x4 acc = {0.f, 0.f, 0.f, 0.f};
#pragma unroll
                for (int kk = 0; kk < 8; ++kk) {
                    bf16x8 bb = *(const bf16x8*)&xs[(c * 16 + lrow) * ASTR + kk * 32 + quad * 8];
                    acc = __builtin_amdgcn_mfma_f32_16x16x32_bf16(a[kk], bb, acc, 0, 0, 0);
                }
#pragma unroll
                for (int r = 0; r < 4; ++r) {
                    int px_l = quad * 4 + r;
                    int di = c * 16 + lrow - px_l;
                    if ((unsigned)di <= 16u) {
                        float v = acc[r] * (1.0f / 256.0f);
                        v = (v > 0.f) ? v : 0.1f * v;
                        __hip_bfloat16 hb = __float2bfloat16(v);
                        cvp[(((size_t)b * CVP + h + 3) * CVP + (w0 + px_l + 3)) * CVC + dj * MO + di] =
                            *(unsigned short*)&hb;
                    }
                }
            }
        }

        if (dop) {
            unsigned short* dst = x2s[(rr + 1) & 1];
#pragma unroll
            for (int s = 0; s < 4; ++s) {
                int v = t + s * 256;
                int col = v >> 5, ch8 = v & 31;
                *(us8*)&dst[col * ASTR + ch8 * 8] = pr[s];
            }
            __syncthreads();
        }
    }
}

// ---------------------------------------------------------------------------
// K4: depthwise 7x7 attention conv + multiply, LDS-tiled. Reads bf16 cvp,
// converts to fp32 during staging (FMA loop unchanged). XCD-banded by ty.
__global__ void dw_att_tiled(const unsigned short* __restrict__ cvp,
                             const float* __restrict__ wdwp,
                             const float* __restrict__ att_b, unsigned short* __restrict__ av_pad) {
    __shared__ float actS[14 * 14 * 64];
    __shared__ float wdwS[49 * 64];
    int i = blockIdx.x;                    // 1280
    int ty = i & 7;
    int j = i >> 3;
    int cc = j % 5;
    int rest = j / 5;
    int tx = rest & 7, b = rest >> 3;
    int x0 = tx * 8, y0 = ty * 8;
    int c0 = cc * 64;
    int t = threadIdx.x;

    const unsigned short* cvb = cvp + (((size_t)b * CVP + y0) * CVP + x0) * CVC + c0;
    for (int v = t; v < 14 * 14 * 8; v += 256) {
        int rc = v >> 3, c8v = v & 7;
        int yy = rc / 14, xx = rc - yy * 14;
        bf16x8 raw = *(const bf16x8*)&cvb[((size_t)yy * CVP + xx) * CVC + c8v * 8];
        f32x4 lo, hi;
#pragma unroll
        for (int e = 0; e < 4; ++e) { lo[e] = (float)raw[e]; hi[e] = (float)raw[e + 4]; }
        *(f32x4*)&actS[rc * 64 + c8v * 8] = lo;
        *(f32x4*)&actS[rc * 64 + c8v * 8 + 4] = hi;
    }
    for (int v = t; v < 49 * 64; v += 256) {
        int tap = v >> 6, ch = v & 63;
        wdwS[v] = wdwp[tap * CVC + c0 + ch];
    }
    __syncthreads();

    int ch_l = t & 63, pgrp = t >> 6;
    int ch = c0 + ch_l;
    float bv = (ch < NCH) ? att_b[ch] : 0.f;
    float acc[16];
#pragma unroll
    for (int ii = 0; ii < 16; ++ii) acc[ii] = bv;

    for (int dy = 0; dy < 7; ++dy) {
#pragma unroll
        for (int dx = 0; dx < 7; ++dx) {
            float wv = wdwS[(dy * 7 + dx) * 64 + ch_l];
#pragma unroll
            for (int ii = 0; ii < 16; ++ii) {
                int py = pgrp * 2 + (ii >> 3), px = ii & 7;
                float a = actS[((py + dy) * 14 + (px + dx)) * 64 + ch_l];
                acc[ii] += a * wv;
            }
        }
    }

    if (ch < NCH) {
#pragma unroll
        for (int ii = 0; ii < 16; ++ii) {
            int py = pgrp * 2 + (ii >> 3), px = ii & 7;
            float c0v = actS[((py + 3) * 14 + (px + 3)) * 64 + ch_l];
            __hip_bfloat16 hb = __float2bfloat16(c0v * acc[ii]);
            av_pad[(((size_t)b * 66 + y0 + py + 1) * 66 + (x0 + px + 1)) * ICP + ch] =
                *(unsigned short*)&hb;
        }
    }
}

// ---------------------------------------------------------------------------
// K5: conv3x3 289->144 + ReLU via bf16 MFMA, software-pipelined, XCD-banded.
__global__ void agg1_mfma_kernel(const unsigned short* __restrict__ av_pad,
                                 const unsigned short* __restrict__ wb1,
                                 const float* __restrict__ bias,
                                 unsigned short* __restrict__ h1p) {
    __shared__ __align__(16) unsigned short aS2[2][66 * CH64];
    __shared__ __align__(16) unsigned short bS[2][C1 * CH64];
    int i = blockIdx.x;                    // 256
    int xcd = i & 7;
    int j = i >> 3;
    int h = xcd * 8 + (j & 7);
    int b = j >> 3;
    int t = threadIdx.x;
    int wave = t >> 6, lane = t & 63;
    int lrow = lane & 15, quad = lane >> 4;
    int ot0 = (wave == 0) ? 0 : (wave * 2 + 1);
    int nt  = (wave == 0) ? 3 : 2;

    f32x4 acc[4][3];
#pragma unroll
    for (int m = 0; m < 4; ++m)
#pragma unroll
        for (int ii = 0; ii < 3; ++ii) acc[m][ii] = (f32x4){0.f, 0.f, 0.f, 0.f};

    const unsigned short* avb = av_pad + (((size_t)b * 66 + h) * 66) * ICP;

    {
        const unsigned short* arow = avb;
#pragma unroll
        for (int s = 0; s < 2; ++s) {
            int v = t + s * 256;
            *(us8*)&aS2[0][(v >> 3) * CH64 + (v & 7) * 8] =
                *(const us8*)&arow[(size_t)(v >> 3) * ICP + (v & 7) * 8];
        }
        if (t < 16) {
            int v = t + 512;
            *(us8*)&aS2[0][(v >> 3) * CH64 + (v & 7) * 8] =
                *(const us8*)&arow[(size_t)(v >> 3) * ICP + (v & 7) * 8];
        }
#pragma unroll
        for (int s = 0; s < 4; ++s) {
            int v = t + s * 256;
            *(us8*)&bS[0][(v >> 3) * CH64 + (v & 7) * 8] =
                *(const us8*)&wb1[(size_t)(v >> 3) * ICP + (v & 7) * 8];
        }
        if (t < 128) {
            int v = t + 1024;
            *(us8*)&bS[0][(v >> 3) * CH64 + (v & 7) * 8] =
                *(const us8*)&wb1[(size_t)(v >> 3) * ICP + (v & 7) * 8];
        }
    }
    __syncthreads();

    for (int k = 0; k < 45; ++k) {
        int rr = k % 15;
        int dx = rr % 3;
        int abuf = (k / 3) & 1, bbuf = k & 1;

        us8 br[5], ar[3];
        int kn = k + 1;
        bool do_b = (kn < 45);
        bool do_a = do_b && (kn % 3 == 0);
        int dyn = kn / 15, rn = kn % 15;
        int ccin = rn / 3, dxn = rn % 3;
        if (do_b) {
            const unsigned short* wt = wb1 + ((size_t)(dyn * 3 + dxn) * C1) * ICP + ccin * 64;
#pragma unroll
            for (int s = 0; s < 4; ++s) {
                int v = t + s * 256;
                br[s] = *(const us8*)&wt[(size_t)(v >> 3) * ICP + (v & 7) * 8];
            }
            if (t < 128) {
                int v = t + 1024;
                br[4] = *(const us8*)&wt[(size_t)(v >> 3) * ICP + (v & 7) * 8];
            }
        }
        if (do_a) {
            const unsigned short* arow = avb + (size_t)dyn * 66 * ICP + ccin * 64;
#pragma unroll
            for (int s = 0; s < 2; ++s) {
                int v = t + s * 256;
                ar[s] = *(const us8*)&arow[(size_t)(v >> 3) * ICP + (v & 7) * 8];
            }
            if (t < 16) {
                int v = t + 512;
                ar[2] = *(const us8*)&arow[(size_t)(v >> 3) * ICP + (v & 7) * 8];
            }
        }

        const unsigned short* aP = aS2[abuf];
        const unsigned short* bP = bS[bbuf];
#pragma unroll
        for (int cc2 = 0; cc2 < 2; ++cc2) {
            bf16x8 bfr[3];
#pragma unroll
            for (int ii = 0; ii < 3; ++ii)
                if (ii < nt)
                    bfr[ii] = *(const bf16x8*)&bP[((ot0 + ii) * 16 + lrow) * CH64 + cc2 * 32 + quad * 8];
#pragma unroll
            for (int m = 0; m < 4; ++m) {
                bf16x8 af = *(const bf16x8*)&aP[(m * 16 + lrow + dx) * CH64 + cc2 * 32 + quad * 8];
#pragma unroll
                for (int ii = 0; ii < 3; ++ii)
                    if (ii < nt)
                        acc[m][ii] = __builtin_amdgcn_mfma_f32_16x16x32_bf16(af, bfr[ii], acc[m][ii], 0, 0, 0);
            }
        }

        if (do_b) {
            unsigned short* dst = bS[bbuf ^ 1];
#pragma unroll
            for (int s = 0; s < 4; ++s) {
                int v = t + s * 256;
                *(us8*)&dst[(v >> 3) * CH64 + (v & 7) * 8] = br[s];
            }
            if (t < 128) {
                int v = t + 1024;
                *(us8*)&dst[(v >> 3) * CH64 + (v & 7) * 8] = br[4];
            }
        }
        if (do_a) {
            unsigned short* dst = aS2[abuf ^ 1];
#pragma unroll
            for (int s = 0; s < 2; ++s) {
                int v = t + s * 256;
                *(us8*)&dst[(v >> 3) * CH64 + (v & 7) * 8] = ar[s];
            }
            if (t < 16) {
                int v = t + 512;
                *(us8*)&dst[(v >> 3) * CH64 + (v & 7) * 8] = ar[2];
            }
        }
        if (do_b) __syncthreads();
    }

    size_t rowbase = ((size_t)b * 66 + h + 1) * 66;
#pragma unroll
    for (int m = 0; m < 4; ++m)
#pragma unroll
        for (int ii = 0; ii < 3; ++ii)
            if (ii < nt) {
                int oc = (ot0 + ii) * 16 + lrow;
                float bv = bias[oc];
#pragma unroll
                for (int r = 0; r < 4; ++r) {
                    int w = m * 16 + quad * 4 + r;
                    float val = fmaxf(acc[m][ii][r] + bv, 0.f);
                    __hip_bfloat16 hb = __float2bfloat16(val);
                    h1p[(rowbase + (w + 1)) * IC2 + oc] = *(unsigned short*)&hb;
                }
            }
}

// ---------------------------------------------------------------------------
// K6: conv3x3 144->49 + ReLU via bf16 MFMA, writes NCHW fp32 output. XCD-banded.
__global__ void agg2_mfma_kernel(const unsigned short* __restrict__ h1p,
                                 const unsigned short* __restrict__ wb2,
                                 const float* __restrict__ bias, float* __restrict__ out) {
    __shared__ __align__(16) unsigned short aS[66 * A2STR];
    __shared__ __align__(16) unsigned short bS[64 * A2STR];
    int i = blockIdx.x;                    // 256
    int xcd = i & 7;
    int j = i >> 3;
    int h = xcd * 8 + (j & 7);
    int b = j >> 3;
    int t = threadIdx.x;
    int wave = t >> 6, lane = t & 63;
    int lrow = lane & 15, quad = lane >> 4;
    int pt = wave;

    f32x4 acc[4];
#pragma unroll
    for (int ot = 0; ot < 4; ++ot) acc[ot] = (f32x4){0.f, 0.f, 0.f, 0.f};

    const unsigned short* h1b = h1p + (((size_t)b * 66 + h) * 66) * IC2;

    for (int dy = 0; dy < 3; ++dy) {
        __syncthreads();
        const unsigned short* arow = h1b + (size_t)dy * 66 * IC2;
        for (int v = t; v < 66 * (IC2 / 8); v += 256) {
            int col = v / (IC2 / 8);
            int c8 = v - col * (IC2 / 8);
            *(us8*)&aS[col * A2STR + c8 * 8] = *(const us8*)&arow[col * IC2 + c8 * 8];
        }
        for (int dx = 0; dx < 3; ++dx) {
            int tap = dy * 3 + dx;
            if (dx != 0) __syncthreads();
            const unsigned short* wtap = wb2 + (size_t)tap * 64 * IC2;
            for (int v = t; v < 64 * (IC2 / 8); v += 256) {
                int oc = v / (IC2 / 8);
                int c8 = v - oc * (IC2 / 8);
                *(us8*)&bS[oc * A2STR + c8 * 8] = *(const us8*)&wtap[(size_t)oc * IC2 + c8 * 8];
            }
            __syncthreads();
#pragma unroll
            for (int cc = 0; cc < 5; ++cc) {
                bf16x8 af = *(const bf16x8*)&aS[(pt * 16 + lrow + dx) * A2STR + cc * 32 + quad * 8];
#pragma unroll
                for (int ot = 0; ot < 4; ++ot) {
                    bf16x8 bfr = *(const bf16x8*)&bS[(ot * 16 + lrow) * A2STR + cc * 32 + quad * 8];
                    acc[ot] = __builtin_amdgcn_mfma_f32_16x16x32_bf16(af, bfr, acc[ot], 0, 0, 0);
                }
            }
        }
    }

#pragma unroll
    for (int ot = 0; ot < 4; ++ot) {
        int o = ot * 16 + lrow;
        if (o < C2) {
            float bv = bias[o];
#pragma unroll
            for (int r = 0; r < 4; ++r) {
                int w = pt * 16 + quad * 4 + r;
                out[((size_t)b * C2 + o) * HW + h * 64 + w] = fmaxf(acc[ot][r] + bv, 0.f);
            }
        }
    }
}

// ---------------------------------------------------------------------------
extern "C" void kernel_launch(void* const* d_in, const int* in_sizes, int n_in,
                              void* d_out, int out_size, void* d_ws, size_t ws_size,
                              hipStream_t stream) {
    const float* f1    = (const float*)d_in[0];
    const float* f2    = (const float*)d_in[1];
    const float* att_w = (const float*)d_in[2];
    const float* att_b = (const float*)d_in[3];
    const float* w1    = (const float*)d_in[4];
    const float* b1    = (const float*)d_in[5];
    const float* w2    = (const float*)d_in[6];
    const float* b2    = (const float*)d_in[7];
    float* out = (float*)d_out;

    char* wsb = (char*)d_ws;
    size_t off = 0;
    float* wdwp = (float*)(wsb + off); off += (size_t)49 * CVC * 4;
    off = (off + 15) & ~(size_t)15;
    unsigned short* x1bf = (unsigned short*)(wsb + off); off += (size_t)NPIX * C * 2;
    unsigned short* x2bf = (unsigned short*)(wsb + off); off += (size_t)BS * PH * PW * C * 2;
    unsigned short* cvp  = (unsigned short*)(wsb + off); off += (size_t)BS * CVP * CVP * CVC * 2;
    unsigned short* avp  = (unsigned short*)(wsb + off); off += (size_t)BS * 66 * 66 * ICP * 2;
    unsigned short* wb1  = (unsigned short*)(wsb + off); off += (size_t)9 * C1 * ICP * 2;
    unsigned short* h1p  = (unsigned short*)(wsb + off); off += (size_t)BS * 66 * 66 * IC2 * 2;
    unsigned short* wb2  = (unsigned short*)(wsb + off); off += (size_t)9 * 64 * IC2 * 2;
    if (ws_size < off) return;

    // halo-only zeroing (replaces 4 full-buffer memsets)
    halo_zero<<<1152, 256, 0, stream>>>(x2bf, PH, 8, C);
    halo_zero<<<503, 256, 0, stream>>>(cvp, CVP, 3, CVC);
    halo_zero<<<163, 256, 0, stream>>>(avp, 66, 1, ICP);
    halo_zero<<<82, 256, 0, stream>>>(h1p, 66, 1, IC2);

    fused_norm_transpose<<<512, 256, 0, stream>>>(f1, x1bf);
    transpose_pad_kernel<<<4096, 256, 0, stream>>>(f2, x2bf);

    rearrange_w1_bf<<<(9 * C1 * ICP + 255) / 256, 256, 0, stream>>>(w1, wb1);
    rearrange_w2_bf<<<(9 * 64 * IC2 + 255) / 256, 256, 0, stream>>>(w2, wb2);
    rearrange_dw_pad<<<(49 * CVC + 255) / 256, 256, 0, stream>>>(att_w, wdwp);

    cv_mfma_kernel<<<256, 256, 0, stream>>>(x1bf, x2bf, cvp);
    dw_att_tiled<<<1280, 256, 0, stream>>>(cvp, wdwp, att_b, avp);
    agg1_mfma_kernel<<<256, 256, 0, stream>>>(avp, wb1, b1, h1p);
    agg2_mfma_kernel<<<256, 256, 0, stream>>>(h1p, wb2, b2, out);
}

// Round 11
// 195.487 us; speedup vs baseline: 8.4136x; 1.0911x over previous
//
#include <hip/hip_runtime.h>
#include <hip/hip_bf16.h>

// Problem constants
#define BS   4
#define C    256
#define HW   4096          // 64*64
#define NPIX 16384         // 4*4096
#define NCH  289           // cost-volume channels (17*17)
#define MO   17
#define PH   80            // padded 64+2*8
#define PW   80
#define C1   144
#define C2   49
#define ASTR 264           // cv LDS row stride in bf16 elems
#define ICP  320           // agg1 padded input channels (289 -> 320)
#define IC3  192           // agg2 padded input channels (144 -> 192 = 3*64)
#define CVP  70            // cv padded spatial (64 + 2*3)
#define CVC  320           // cv padded channels
#define CH64 72            // 64-ch chunk LDS stride (64+8): bank-balanced

typedef __bf16  bf16x8 __attribute__((ext_vector_type(8)));
typedef float   f32x4  __attribute__((ext_vector_type(4)));
typedef unsigned short us8 __attribute__((ext_vector_type(8)));

// ---------------------------------------------------------------------------
// K1: fused L2-norm + NCHW->NHWC bf16 transpose for f1. Reads f1 ONCE.
__global__ void fused_norm_transpose(const float* __restrict__ f1,
                                     unsigned short* __restrict__ dst) {
    __shared__ float tileT[32 * 257];
    __shared__ float invS[32];
    int blk = blockIdx.x;                 // 512 = 4b * 128
    int pblk = blk & 127, b = blk >> 7;
    int p0 = pblk * 32;
    int t = threadIdx.x;
    int tx = t & 31, ty = t >> 5;
    const float* s = f1 + (size_t)b * C * HW;
#pragma unroll
    for (int i = 0; i < 32; ++i) {
        int c = ty + 8 * i;
        tileT[tx * 257 + c] = s[(size_t)c * HW + p0 + tx];
    }
    __syncthreads();
    int lane = t & 63, wave = t >> 6;
    int px = wave * 8 + (lane >> 3);
    int l = lane & 7;
    float ssum = 0.f;
#pragma unroll
    for (int j = 0; j < 32; ++j) {
        float v = tileT[px * 257 + l + 8 * j];
        ssum += v * v;
    }
    ssum += __shfl_xor(ssum, 1);
    ssum += __shfl_xor(ssum, 2);
    ssum += __shfl_xor(ssum, 4);
    if (l == 0) invS[px] = 1.0f / fmaxf(sqrtf(ssum), 1e-12f);
    __syncthreads();
#pragma unroll 4
    for (int p = 0; p < 32; ++p) {
        float v = tileT[p * 257 + t] * invS[p];
        __hip_bfloat16 hb = __float2bfloat16(v);
        dst[((size_t)b * HW + p0 + p) * C + t] = *(unsigned short*)&hb;
    }
}

// ---------------------------------------------------------------------------
// K2: NCHW fp32 -> padded NHWC bf16 transpose (f2 only).
__global__ void transpose_pad_kernel(const float* __restrict__ src,
                                     unsigned short* __restrict__ dst) {
    __shared__ float tile[32][33];
    int blk = blockIdx.x;                 // 4096 blocks
    int pblk = blk & 127;
    int cblk = (blk >> 7) & 7;
    int b    = blk >> 10;
    int tx = threadIdx.x & 31, ty = threadIdx.x >> 5;
    int c0 = cblk * 32, p0 = pblk * 32;
    const float* s = src + (size_t)b * C * HW;
#pragma unroll
    for (int i = 0; i < 4; ++i) {
        int c = c0 + ty + 8 * i;
        tile[ty + 8 * i][tx] = s[(size_t)c * HW + p0 + tx];
    }
    __syncthreads();
#pragma unroll
    for (int i = 0; i < 4; ++i) {
        int p = p0 + ty + 8 * i;
        float v = tile[tx][ty + 8 * i];
        int c = c0 + tx;
        int h = p >> 6, w = p & 63;
        __hip_bfloat16 hb = __float2bfloat16(v);
        dst[(((size_t)b * PH + h + 8) * PW + (w + 8)) * C + c] = *(unsigned short*)&hb;
    }
}

// ---------------------------------------------------------------------------
// Consolidated prep: 4 halo-zeros + 3 weight rearranges, blockIdx-ranged.
__device__ __forceinline__ void halo_zero_dev(unsigned short* p, int H, int halo,
                                              int Cc, int blk, int t) {
    int W = H;
    int inter = H - 2 * halo;
    int total_pos = H * W - inter * inter;
    int chunks = Cc >> 3;
    size_t tot = (size_t)total_pos * chunks * BS;
    size_t idx = (size_t)blk * 256 + t;
    if (idx >= tot) return;
    int c8 = (int)(idx % chunks);
    size_t r = idx / chunks;
    int pos = (int)(r % total_pos);
    int b = (int)(r / total_pos);
    int h, w;
    int topbot = 2 * halo * W;
    if (pos < halo * W) { h = pos / W; w = pos % W; }
    else if (pos < topbot) { int q = pos - halo * W; h = H - halo + q / W; w = q % W; }
    else {
        int q = pos - topbot;
        int row = q / (2 * halo), off = q % (2 * halo);
        h = halo + row;
        w = (off < halo) ? off : (W - 2 * halo + off);
    }
    us8 z = {0, 0, 0, 0, 0, 0, 0, 0};
    *(us8*)&p[(((size_t)b * H + h) * W + w) * Cc + c8 * 8] = z;
}

__global__ void prep_kernel(unsigned short* __restrict__ x2bf, unsigned short* __restrict__ cvp,
                            unsigned short* __restrict__ avp, unsigned short* __restrict__ h1p,
                            const float* __restrict__ w1, unsigned short* __restrict__ wb1,
                            const float* __restrict__ w2, unsigned short* __restrict__ wb2,
                            const float* __restrict__ att_w, float* __restrict__ wdwp) {
    int blk = blockIdx.x;                 // 4030 total
    int t = threadIdx.x;
    if (blk < 1152) { halo_zero_dev(x2bf, PH, 8, C, blk, t); return; }
    if (blk < 1655) { halo_zero_dev(cvp, CVP, 3, CVC, blk - 1152, t); return; }
    if (blk < 1818) { halo_zero_dev(avp, 66, 1, ICP, blk - 1655, t); return; }
    if (blk < 1916) { halo_zero_dev(h1p, 66, 1, IC3, blk - 1818, t); return; }
    if (blk < 3536) {                     // w1: [144][289][3][3] -> [9][144][320]
        int idx = (blk - 1916) * 256 + t; // < 414720 exactly
        int tap = idx / (C1 * ICP);
        int r = idx - tap * (C1 * ICP);
        int oc = r / ICP;
        int ic = r - oc * ICP;
        float v = (ic < NCH) ? w1[((size_t)(oc * NCH + ic)) * 9 + tap] : 0.f;
        __hip_bfloat16 hb = __float2bfloat16(v);
        wb1[idx] = *(unsigned short*)&hb;
        return;
    }
    if (blk < 3968) {                     // w2: [49][144][3][3] -> [9][64][192]
        int idx = (blk - 3536) * 256 + t; // < 110592 exactly
        int tap = idx / (64 * IC3);
        int r = idx - tap * (64 * IC3);
        int oc = r / IC3;
        int ic = r - oc * IC3;
        float v = (oc < C2 && ic < C1) ? w2[((size_t)(oc * C1 + ic)) * 9 + tap] : 0.f;
        __hip_bfloat16 hb = __float2bfloat16(v);
        wb2[idx] = *(unsigned short*)&hb;
        return;
    }
    {                                     // dw: [289][1][7][7] -> [49][320]
        int idx = (blk - 3968) * 256 + t;
        if (idx >= 49 * CVC) return;
        int tap = idx / CVC;
        int ch = idx - tap * CVC;
        wdwp[idx] = (ch < NCH) ? att_w[ch * 49 + tap] : 0.f;
    }
}

// ---------------------------------------------------------------------------
// K3: cost volume via bf16 MFMA -> padded bf16 cvp [4][70][70][320] at (+3,+3).
__global__ void cv_mfma_kernel(const unsigned short* __restrict__ x1b,
                               const unsigned short* __restrict__ x2b,
                               unsigned short* __restrict__ cvp) {
    __shared__ __align__(16) unsigned short x2s[2][32 * ASTR];
    int i = blockIdx.x;                    // 256
    int xcd = i & 7;
    int j = i >> 3;
    int hq = xcd * 2 + (j & 1);
    int jj = j >> 1;
    int wseg = jj & 3;
    int b = jj >> 2;
    int h0 = hq * 4;
    int w0 = wseg * 16;
    int t = threadIdx.x;
    int wave = t >> 6, lane = t & 63;
    int lrow = lane & 15, quad = lane >> 4;
    int h = h0 + wave;

    const unsigned short* x1p = x1b + ((size_t)b * HW + h * 64 + w0) * C;
    bf16x8 a[8];
#pragma unroll
    for (int kk = 0; kk < 8; ++kk)
        a[kk] = *(const bf16x8*)&x1p[(size_t)lrow * C + kk * 32 + quad * 8];

    const unsigned short* x2base = x2b + (size_t)b * PH * PW * C;

    {
        const unsigned short* rowp = x2base + ((size_t)h0 * PW + w0) * C;
#pragma unroll
        for (int s = 0; s < 4; ++s) {
            int v = t + s * 256;
            int col = v >> 5, ch8 = v & 31;
            *(us8*)&x2s[0][col * ASTR + ch8 * 8] = *(const us8*)&rowp[(size_t)col * C + ch8 * 8];
        }
    }
    __syncthreads();

    for (int rr = 0; rr < 20; ++rr) {
        us8 pr[4];
        bool dop = (rr + 1 < 20);
        if (dop) {
            const unsigned short* rowp = x2base + ((size_t)(h0 + rr + 1) * PW + w0) * C;
#pragma unroll
            for (int s = 0; s < 4; ++s) {
                int v = t + s * 256;
                int col = v >> 5, ch8 = v & 31;
                pr[s] = *(const us8*)&rowp[(size_t)col * C + ch8 * 8];
            }
        }

        int dj = rr - wave;
        if ((unsigned)dj <= 16u) {
            const unsigned short* xs = x2s[rr & 1];
#pragma unroll
            for (int c = 0; c < 2; ++c) {
                f32x4 acc = {0.f, 0.f, 0.f, 0.f};
#pragma unroll
                for (int kk = 0; kk < 8; ++kk) {
                    bf16x8 bb = *(const bf16x8*)&xs[(c * 16 + lrow) * ASTR + kk * 32 + quad * 8];
                    acc = __builtin_amdgcn_mfma_f32_16x16x32_bf16(a[kk], bb, acc, 0, 0, 0);
                }
#pragma unroll
                for (int r = 0; r < 4; ++r) {
                    int px_l = quad * 4 + r;
                    int di = c * 16 + lrow - px_l;
                    if ((unsigned)di <= 16u) {
                        float v = acc[r] * (1.0f / 256.0f);
                        v = (v > 0.f) ? v : 0.1f * v;
                        __hip_bfloat16 hb = __float2bfloat16(v);
                        cvp[(((size_t)b * CVP + h + 3) * CVP + (w0 + px_l + 3)) * CVC + dj * MO + di] =
                            *(unsigned short*)&hb;
                    }
                }
            }
        }

        if (dop) {
            unsigned short* dst = x2s[(rr + 1) & 1];
#pragma unroll
            for (int s = 0; s < 4; ++s) {
                int v = t + s * 256;
                int col = v >> 5, ch8 = v & 31;
                *(us8*)&dst[col * ASTR + ch8 * 8] = pr[s];
            }
            __syncthreads();
        }
    }
}

// ---------------------------------------------------------------------------
// K4: depthwise 7x7 attention conv + multiply, LDS-tiled, bf16 cvp in.
__global__ void dw_att_tiled(const unsigned short* __restrict__ cvp,
                             const float* __restrict__ wdwp,
                             const float* __restrict__ att_b, unsigned short* __restrict__ av_pad) {
    __shared__ float actS[14 * 14 * 64];
    __shared__ float wdwS[49 * 64];
    int i = blockIdx.x;                    // 1280
    int ty = i & 7;
    int j = i >> 3;
    int cc = j % 5;
    int rest = j / 5;
    int tx = rest & 7, b = rest >> 3;
    int x0 = tx * 8, y0 = ty * 8;
    int c0 = cc * 64;
    int t = threadIdx.x;

    const unsigned short* cvb = cvp + (((size_t)b * CVP + y0) * CVP + x0) * CVC + c0;
    for (int v = t; v < 14 * 14 * 8; v += 256) {
        int rc = v >> 3, c8v = v & 7;
        int yy = rc / 14, xx = rc - yy * 14;
        bf16x8 raw = *(const bf16x8*)&cvb[((size_t)yy * CVP + xx) * CVC + c8v * 8];
        f32x4 lo, hi;
#pragma unroll
        for (int e = 0; e < 4; ++e) { lo[e] = (float)raw[e]; hi[e] = (float)raw[e + 4]; }
        *(f32x4*)&actS[rc * 64 + c8v * 8] = lo;
        *(f32x4*)&actS[rc * 64 + c8v * 8 + 4] = hi;
    }
    for (int v = t; v < 49 * 64; v += 256) {
        int tap = v >> 6, ch = v & 63;
        wdwS[v] = wdwp[tap * CVC + c0 + ch];
    }
    __syncthreads();

    int ch_l = t & 63, pgrp = t >> 6;
    int ch = c0 + ch_l;
    float bv = (ch < NCH) ? att_b[ch] : 0.f;
    float acc[16];
#pragma unroll
    for (int ii = 0; ii < 16; ++ii) acc[ii] = bv;

    for (int dy = 0; dy < 7; ++dy) {
#pragma unroll
        for (int dx = 0; dx < 7; ++dx) {
            float wv = wdwS[(dy * 7 + dx) * 64 + ch_l];
#pragma unroll
            for (int ii = 0; ii < 16; ++ii) {
                int py = pgrp * 2 + (ii >> 3), px = ii & 7;
                float a = actS[((py + dy) * 14 + (px + dx)) * 64 + ch_l];
                acc[ii] += a * wv;
            }
        }
    }

    if (ch < NCH) {
#pragma unroll
        for (int ii = 0; ii < 16; ++ii) {
            int py = pgrp * 2 + (ii >> 3), px = ii & 7;
            float c0v = actS[((py + 3) * 14 + (px + 3)) * 64 + ch_l];
            __hip_bfloat16 hb = __float2bfloat16(c0v * acc[ii]);
            av_pad[(((size_t)b * 66 + y0 + py + 1) * 66 + (x0 + px + 1)) * ICP + ch] =
                *(unsigned short*)&hb;
        }
    }
}

// ---------------------------------------------------------------------------
// K5: conv3x3 289->144 + ReLU via bf16 MFMA, software-pipelined, XCD-banded.
// Writes bf16 h1p [BS][66][66][192].
__global__ void agg1_mfma_kernel(const unsigned short* __restrict__ av_pad,
                                 const unsigned short* __restrict__ wb1,
                                 const float* __restrict__ bias,
                                 unsigned short* __restrict__ h1p) {
    __shared__ __align__(16) unsigned short aS2[2][66 * CH64];
    __shared__ __align__(16) unsigned short bS[2][C1 * CH64];
    int i = blockIdx.x;                    // 256
    int xcd = i & 7;
    int j = i >> 3;
    int h = xcd * 8 + (j & 7);
    int b = j >> 3;
    int t = threadIdx.x;
    int wave = t >> 6, lane = t & 63;
    int lrow = lane & 15, quad = lane >> 4;
    int ot0 = (wave == 0) ? 0 : (wave * 2 + 1);
    int nt  = (wave == 0) ? 3 : 2;

    f32x4 acc[4][3];
#pragma unroll
    for (int m = 0; m < 4; ++m)
#pragma unroll
        for (int ii = 0; ii < 3; ++ii) acc[m][ii] = (f32x4){0.f, 0.f, 0.f, 0.f};

    const unsigned short* avb = av_pad + (((size_t)b * 66 + h) * 66) * ICP;

    {
        const unsigned short* arow = avb;
#pragma unroll
        for (int s = 0; s < 2; ++s) {
            int v = t + s * 256;
            *(us8*)&aS2[0][(v >> 3) * CH64 + (v & 7) * 8] =
                *(const us8*)&arow[(size_t)(v >> 3) * ICP + (v & 7) * 8];
        }
        if (t < 16) {
            int v = t + 512;
            *(us8*)&aS2[0][(v >> 3) * CH64 + (v & 7) * 8] =
                *(const us8*)&arow[(size_t)(v >> 3) * ICP + (v & 7) * 8];
        }
#pragma unroll
        for (int s = 0; s < 4; ++s) {
            int v = t + s * 256;
            *(us8*)&bS[0][(v >> 3) * CH64 + (v & 7) * 8] =
                *(const us8*)&wb1[(size_t)(v >> 3) * ICP + (v & 7) * 8];
        }
        if (t < 128) {
            int v = t + 1024;
            *(us8*)&bS[0][(v >> 3) * CH64 + (v & 7) * 8] =
                *(const us8*)&wb1[(size_t)(v >> 3) * ICP + (v & 7) * 8];
        }
    }
    __syncthreads();

    for (int k = 0; k < 45; ++k) {
        int rr = k % 15;
        int dx = rr % 3;
        int abuf = (k / 3) & 1, bbuf = k & 1;

        us8 br[5], ar[3];
        int kn = k + 1;
        bool do_b = (kn < 45);
        bool do_a = do_b && (kn % 3 == 0);
        int dyn = kn / 15, rn = kn % 15;
        int ccin = rn / 3, dxn = rn % 3;
        if (do_b) {
            const unsigned short* wt = wb1 + ((size_t)(dyn * 3 + dxn) * C1) * ICP + ccin * 64;
#pragma unroll
            for (int s = 0; s < 4; ++s) {
                int v = t + s * 256;
                br[s] = *(const us8*)&wt[(size_t)(v >> 3) * ICP + (v & 7) * 8];
            }
            if (t < 128) {
                int v = t + 1024;
                br[4] = *(const us8*)&wt[(size_t)(v >> 3) * ICP + (v & 7) * 8];
            }
        }
        if (do_a) {
            const unsigned short* arow = avb + (size_t)dyn * 66 * ICP + ccin * 64;
#pragma unroll
            for (int s = 0; s < 2; ++s) {
                int v = t + s * 256;
                ar[s] = *(const us8*)&arow[(size_t)(v >> 3) * ICP + (v & 7) * 8];
            }
            if (t < 16) {
                int v = t + 512;
                ar[2] = *(const us8*)&arow[(size_t)(v >> 3) * ICP + (v & 7) * 8];
            }
        }

        const unsigned short* aP = aS2[abuf];
        const unsigned short* bP = bS[bbuf];
#pragma unroll
        for (int cc2 = 0; cc2 < 2; ++cc2) {
            bf16x8 bfr[3];
#pragma unroll
            for (int ii = 0; ii < 3; ++ii)
                if (ii < nt)
                    bfr[ii] = *(const bf16x8*)&bP[((ot0 + ii) * 16 + lrow) * CH64 + cc2 * 32 + quad * 8];
#pragma unroll
            for (int m = 0; m < 4; ++m) {
                bf16x8 af = *(const bf16x8*)&aP[(m * 16 + lrow + dx) * CH64 + cc2 * 32 + quad * 8];
#pragma unroll
                for (int ii = 0; ii < 3; ++ii)
                    if (ii < nt)
                        acc[m][ii] = __builtin_amdgcn_mfma_f32_16x16x32_bf16(af, bfr[ii], acc[m][ii], 0, 0, 0);
            }
        }

        if (do_b) {
            unsigned short* dst = bS[bbuf ^ 1];
#pragma unroll
            for (int s = 0; s < 4; ++s) {
                int v = t + s * 256;
                *(us8*)&dst[(v >> 3) * CH64 + (v & 7) * 8] = br[s];
            }
            if (t < 128) {
                int v = t + 1024;
                *(us8*)&dst[(v >> 3) * CH64 + (v & 7) * 8] = br[4];
            }
        }
        if (do_a) {
            unsigned short* dst = aS2[abuf ^ 1];
#pragma unroll
            for (int s = 0; s < 2; ++s) {
                int v = t + s * 256;
                *(us8*)&dst[(v >> 3) * CH64 + (v & 7) * 8] = ar[s];
            }
            if (t < 16) {
                int v = t + 512;
                *(us8*)&dst[(v >> 3) * CH64 + (v & 7) * 8] = ar[2];
            }
        }
        if (do_b) __syncthreads();
    }

    size_t rowbase = ((size_t)b * 66 + h + 1) * 66;
#pragma unroll
    for (int m = 0; m < 4; ++m)
#pragma unroll
        for (int ii = 0; ii < 3; ++ii)
            if (ii < nt) {
                int oc = (ot0 + ii) * 16 + lrow;
                float bv = bias[oc];
#pragma unroll
                for (int r = 0; r < 4; ++r) {
                    int w = m * 16 + quad * 4 + r;
                    float val = fmaxf(acc[m][ii][r] + bv, 0.f);
                    __hip_bfloat16 hb = __float2bfloat16(val);
                    h1p[(rowbase + (w + 1)) * IC3 + oc] = *(unsigned short*)&hb;
                }
            }
}

// ---------------------------------------------------------------------------
// K6: conv3x3 144->49 + ReLU via bf16 MFMA, software-pipelined (mirror of agg1).
// 27 K-steps of K=64 over (dy, cc, dx); A (66x64) + B (64x64) double-buffered;
// one barrier per step. Writes NCHW fp32 output. XCD-banded.
__global__ void agg2_mfma_kernel(const unsigned short* __restrict__ h1p,
                                 const unsigned short* __restrict__ wb2,
                                 const float* __restrict__ bias, float* __restrict__ out) {
    __shared__ __align__(16) unsigned short aS2[2][66 * CH64];   // 2 x 9.5 KB
    __shared__ __align__(16) unsigned short bS2[2][64 * CH64];   // 2 x 9.2 KB
    int i = blockIdx.x;                    // 256
    int xcd = i & 7;
    int j = i >> 3;
    int h = xcd * 8 + (j & 7);
    int b = j >> 3;
    int t = threadIdx.x;
    int wave = t >> 6, lane = t & 63;
    int lrow = lane & 15, quad = lane >> 4;
    int pt = wave;                         // px-tile

    f32x4 acc[4];
#pragma unroll
    for (int ot = 0; ot < 4; ++ot) acc[ot] = (f32x4){0.f, 0.f, 0.f, 0.f};

    const unsigned short* h1b = h1p + (((size_t)b * 66 + h) * 66) * IC3;

    // initial stage: A(dy=0,cc=0), B(tap0,cc=0)
    {
#pragma unroll
        for (int s = 0; s < 2; ++s) {
            int v = t + s * 256;
            *(us8*)&aS2[0][(v >> 3) * CH64 + (v & 7) * 8] =
                *(const us8*)&h1b[(size_t)(v >> 3) * IC3 + (v & 7) * 8];
        }
        if (t < 16) {
            int v = t + 512;
            *(us8*)&aS2[0][(v >> 3) * CH64 + (v & 7) * 8] =
                *(const us8*)&h1b[(size_t)(v >> 3) * IC3 + (v & 7) * 8];
        }
#pragma unroll
        for (int s = 0; s < 2; ++s) {
            int v = t + s * 256;
            *(us8*)&bS2[0][(v >> 3) * CH64 + (v & 7) * 8] =
                *(const us8*)&wb2[(size_t)(v >> 3) * IC3 + (v & 7) * 8];
        }
    }
    __syncthreads();

    for (int k = 0; k < 27; ++k) {
        int rem = k % 9;
        int dx = rem % 3;
        int abuf = (k / 3) & 1, bbuf = k & 1;

        // prefetch k+1
        us8 br[2], ar[3];
        int kn = k + 1;
        bool do_b = (kn < 27);
        bool do_a = do_b && (kn % 3 == 0);
        int dyn = kn / 9, rn = kn % 9;
        int ccn = rn / 3, dxn = rn % 3;
        if (do_b) {
            const unsigned short* wt = wb2 + ((size_t)(dyn * 3 + dxn) * 64) * IC3 + ccn * 64;
#pragma unroll
            for (int s = 0; s < 2; ++s) {
                int v = t + s * 256;
                br[s] = *(const us8*)&wt[(size_t)(v >> 3) * IC3 + (v & 7) * 8];
            }
        }
        if (do_a) {
            const unsigned short* arow = h1b + (size_t)dyn * 66 * IC3 + ccn * 64;
#pragma unroll
            for (int s = 0; s < 2; ++s) {
                int v = t + s * 256;
                ar[s] = *(const us8*)&arow[(size_t)(v >> 3) * IC3 + (v & 7) * 8];
            }
            if (t < 16) {
                int v = t + 512;
                ar[2] = *(const us8*)&arow[(size_t)(v >> 3) * IC3 + (v & 7) * 8];
            }
        }

        // MFMA burst
        const unsigned short* aP = aS2[abuf];
        const unsigned short* bP = bS2[bbuf];
#pragma unroll
        for (int cc2 = 0; cc2 < 2; ++cc2) {
            bf16x8 af = *(const bf16x8*)&aP[(pt * 16 + lrow + dx) * CH64 + cc2 * 32 + quad * 8];
#pragma unroll
            for (int ot = 0; ot < 4; ++ot) {
                bf16x8 bfr = *(const bf16x8*)&bP[(ot * 16 + lrow) * CH64 + cc2 * 32 + quad * 8];
                acc[ot] = __builtin_amdgcn_mfma_f32_16x16x32_bf16(af, bfr, acc[ot], 0, 0, 0);
            }
        }

        // commit
        if (do_b) {
            unsigned short* dst = bS2[bbuf ^ 1];
#pragma unroll
            for (int s = 0; s < 2; ++s) {
                int v = t + s * 256;
                *(us8*)&dst[(v >> 3) * CH64 + (v & 7) * 8] = br[s];
            }
        }
        if (do_a) {
            unsigned short* dst = aS2[abuf ^ 1];
#pragma unroll
            for (int s = 0; s < 2; ++s) {
                int v = t + s * 256;
                *(us8*)&dst[(v >> 3) * CH64 + (v & 7) * 8] = ar[s];
            }
            if (t < 16) {
                int v = t + 512;
                *(us8*)&dst[(v >> 3) * CH64 + (v & 7) * 8] = ar[2];
            }
        }
        if (do_b) __syncthreads();
    }

    // epilogue: bias + ReLU -> NCHW fp32 out, oc < 49 only
#pragma unroll
    for (int ot = 0; ot < 4; ++ot) {
        int o = ot * 16 + lrow;
        if (o < C2) {
            float bv = bias[o];
#pragma unroll
            for (int r = 0; r < 4; ++r) {
                int w = pt * 16 + quad * 4 + r;
                out[((size_t)b * C2 + o) * HW + h * 64 + w] = fmaxf(acc[ot][r] + bv, 0.f);
            }
        }
    }
}

// ---------------------------------------------------------------------------
extern "C" void kernel_launch(void* const* d_in, const int* in_sizes, int n_in,
                              void* d_out, int out_size, void* d_ws, size_t ws_size,
                              hipStream_t stream) {
    const float* f1    = (const float*)d_in[0];
    const float* f2    = (const float*)d_in[1];
    const float* att_w = (const float*)d_in[2];
    const float* att_b = (const float*)d_in[3];
    const float* w1    = (const float*)d_in[4];
    const float* b1    = (const float*)d_in[5];
    const float* w2    = (const float*)d_in[6];
    const float* b2    = (const float*)d_in[7];
    float* out = (float*)d_out;

    char* wsb = (char*)d_ws;
    size_t off = 0;
    float* wdwp = (float*)(wsb + off); off += (size_t)49 * CVC * 4;
    off = (off + 15) & ~(size_t)15;
    unsigned short* x1bf = (unsigned short*)(wsb + off); off += (size_t)NPIX * C * 2;
    unsigned short* x2bf = (unsigned short*)(wsb + off); off += (size_t)BS * PH * PW * C * 2;
    unsigned short* cvp  = (unsigned short*)(wsb + off); off += (size_t)BS * CVP * CVP * CVC * 2;
    unsigned short* avp  = (unsigned short*)(wsb + off); off += (size_t)BS * 66 * 66 * ICP * 2;
    unsigned short* wb1  = (unsigned short*)(wsb + off); off += (size_t)9 * C1 * ICP * 2;
    unsigned short* h1p  = (unsigned short*)(wsb + off); off += (size_t)BS * 66 * 66 * IC3 * 2;
    unsigned short* wb2  = (unsigned short*)(wsb + off); off += (size_t)9 * 64 * IC3 * 2;
    if (ws_size < off) return;

    prep_kernel<<<4030, 256, 0, stream>>>(x2bf, cvp, avp, h1p, w1, wb1, w2, wb2, att_w, wdwp);
    fused_norm_transpose<<<512, 256, 0, stream>>>(f1, x1bf);
    transpose_pad_kernel<<<4096, 256, 0, stream>>>(f2, x2bf);

    cv_mfma_kernel<<<256, 256, 0, stream>>>(x1bf, x2bf, cvp);
    dw_att_tiled<<<1280, 256, 0, stream>>>(cvp, wdwp, att_b, avp);
    agg1_mfma_kernel<<<256, 256, 0, stream>>>(avp, wb1, b1, h1p);
    agg2_mfma_kernel<<<256, 256, 0, stream>>>(h1p, wb2, b2, out);
}

// Round 12
// 186.968 us; speedup vs baseline: 8.7969x; 1.0456x over previous
//
#include <hip/hip_runtime.h>
#include <hip/hip_bf16.h>

// Problem constants
#define BS   4
#define C    256
#define HW   4096          // 64*64
#define NPIX 16384         // 4*4096
#define NCH  289           // cost-volume channels (17*17)
#define MO   17
#define PH   80            // padded 64+2*8
#define PW   80
#define C1   144
#define C2   49
#define ASTR 264           // cv LDS row stride in bf16 elems
#define ICP  320           // agg1 padded input channels (289 -> 320)
#define IC3  192           // agg2 padded input channels (144 -> 192 = 3*64)
#define CVP  70            // cv padded spatial (64 + 2*3)
#define CVC  320           // cv padded channels
#define CH64 72            // 64-ch chunk LDS stride (64+8): bank-balanced

typedef __bf16  bf16x8 __attribute__((ext_vector_type(8)));
typedef float   f32x4  __attribute__((ext_vector_type(4)));
typedef unsigned short us8 __attribute__((ext_vector_type(8)));

// ---------------------------------------------------------------------------
// Setup kernel: prep (halo zeros + weight rearranges) + f1 norm-transpose +
// f2 pad-transpose, dispatched by blockIdx range. 8638 blocks total.
//   [0,4030)      prep
//   [4030,4542)   f1: fused L2-norm + NCHW->NHWC bf16 (512 blocks)
//   [4542,8638)   f2: NCHW -> padded NHWC bf16 (4096 blocks)
__device__ __forceinline__ void halo_zero_dev(unsigned short* p, int H, int halo,
                                              int Cc, int blk, int t) {
    int W = H;
    int inter = H - 2 * halo;
    int total_pos = H * W - inter * inter;
    int chunks = Cc >> 3;
    size_t tot = (size_t)total_pos * chunks * BS;
    size_t idx = (size_t)blk * 256 + t;
    if (idx >= tot) return;
    int c8 = (int)(idx % chunks);
    size_t r = idx / chunks;
    int pos = (int)(r % total_pos);
    int b = (int)(r / total_pos);
    int h, w;
    int topbot = 2 * halo * W;
    if (pos < halo * W) { h = pos / W; w = pos % W; }
    else if (pos < topbot) { int q = pos - halo * W; h = H - halo + q / W; w = q % W; }
    else {
        int q = pos - topbot;
        int row = q / (2 * halo), off = q % (2 * halo);
        h = halo + row;
        w = (off < halo) ? off : (W - 2 * halo + off);
    }
    us8 z = {0, 0, 0, 0, 0, 0, 0, 0};
    *(us8*)&p[(((size_t)b * H + h) * W + w) * Cc + c8 * 8] = z;
}

__global__ void setup_kernel(unsigned short* __restrict__ x2bf, unsigned short* __restrict__ cvp,
                             unsigned short* __restrict__ avp, unsigned short* __restrict__ h1p,
                             const float* __restrict__ w1, unsigned short* __restrict__ wb1,
                             const float* __restrict__ w2, unsigned short* __restrict__ wb2,
                             const float* __restrict__ att_w, float* __restrict__ wdwp,
                             const float* __restrict__ f1, unsigned short* __restrict__ x1bf,
                             const float* __restrict__ f2) {
    __shared__ float shmem[32 * 257 + 32];
    int blk = blockIdx.x;
    int t = threadIdx.x;
    if (blk < 4030) {
        // ---------------- prep ----------------
        if (blk < 1152) { halo_zero_dev(x2bf, PH, 8, C, blk, t); return; }
        if (blk < 1655) { halo_zero_dev(cvp, CVP, 3, CVC, blk - 1152, t); return; }
        if (blk < 1818) { halo_zero_dev(avp, 66, 1, ICP, blk - 1655, t); return; }
        if (blk < 1916) { halo_zero_dev(h1p, 66, 1, IC3, blk - 1818, t); return; }
        if (blk < 3536) {                 // w1 -> [9][144][320]
            int idx = (blk - 1916) * 256 + t;
            int tap = idx / (C1 * ICP);
            int r = idx - tap * (C1 * ICP);
            int oc = r / ICP;
            int ic = r - oc * ICP;
            float v = (ic < NCH) ? w1[((size_t)(oc * NCH + ic)) * 9 + tap] : 0.f;
            __hip_bfloat16 hb = __float2bfloat16(v);
            wb1[idx] = *(unsigned short*)&hb;
            return;
        }
        if (blk < 3968) {                 // w2 -> [9][64][192]
            int idx = (blk - 3536) * 256 + t;
            int tap = idx / (64 * IC3);
            int r = idx - tap * (64 * IC3);
            int oc = r / IC3;
            int ic = r - oc * IC3;
            float v = (oc < C2 && ic < C1) ? w2[((size_t)(oc * C1 + ic)) * 9 + tap] : 0.f;
            __hip_bfloat16 hb = __float2bfloat16(v);
            wb2[idx] = *(unsigned short*)&hb;
            return;
        }
        {                                 // dw -> [49][320]
            int idx = (blk - 3968) * 256 + t;
            if (idx >= 49 * CVC) return;
            int tap = idx / CVC;
            int ch = idx - tap * CVC;
            wdwp[idx] = (ch < NCH) ? att_w[ch * 49 + tap] : 0.f;
        }
        return;
    }
    if (blk < 4542) {
        // ---------------- f1: fused norm + transpose ----------------
        float* tileT = shmem;
        float* invS = shmem + 32 * 257;
        int bb = blk - 4030;              // 0..511
        int pblk = bb & 127, b = bb >> 7;
        int p0 = pblk * 32;
        int tx = t & 31, ty = t >> 5;
        const float* s = f1 + (size_t)b * C * HW;
#pragma unroll
        for (int i = 0; i < 32; ++i) {
            int c = ty + 8 * i;
            tileT[tx * 257 + c] = s[(size_t)c * HW + p0 + tx];
        }
        __syncthreads();
        int lane = t & 63, wave = t >> 6;
        int px = wave * 8 + (lane >> 3);
        int l = lane & 7;
        float ssum = 0.f;
#pragma unroll
        for (int j = 0; j < 32; ++j) {
            float v = tileT[px * 257 + l + 8 * j];
            ssum += v * v;
        }
        ssum += __shfl_xor(ssum, 1);
        ssum += __shfl_xor(ssum, 2);
        ssum += __shfl_xor(ssum, 4);
        if (l == 0) invS[px] = 1.0f / fmaxf(sqrtf(ssum), 1e-12f);
        __syncthreads();
#pragma unroll 4
        for (int p = 0; p < 32; ++p) {
            float v = tileT[p * 257 + t] * invS[p];
            __hip_bfloat16 hb = __float2bfloat16(v);
            x1bf[((size_t)b * HW + p0 + p) * C + t] = *(unsigned short*)&hb;
        }
        return;
    }
    {
        // ---------------- f2: pad transpose ----------------
        float* tile = shmem;              // [32][33]
        int bb = blk - 4542;              // 0..4095
        int pblk = bb & 127;
        int cblk = (bb >> 7) & 7;
        int b    = bb >> 10;
        int tx = t & 31, ty = t >> 5;
        int c0 = cblk * 32, p0 = pblk * 32;
        const float* s = f2 + (size_t)b * C * HW;
#pragma unroll
        for (int i = 0; i < 4; ++i) {
            int c = c0 + ty + 8 * i;
            tile[(ty + 8 * i) * 33 + tx] = s[(size_t)c * HW + p0 + tx];
        }
        __syncthreads();
#pragma unroll
        for (int i = 0; i < 4; ++i) {
            int p = p0 + ty + 8 * i;
            float v = tile[tx * 33 + ty + 8 * i];
            int c = c0 + tx;
            int h = p >> 6, w = p & 63;
            __hip_bfloat16 hb = __float2bfloat16(v);
            x2bf[(((size_t)b * PH + h + 8) * PW + (w + 8)) * C + c] = *(unsigned short*)&hb;
        }
    }
}

// ---------------------------------------------------------------------------
// K3: cost volume via bf16 MFMA -> padded bf16 cvp [4][70][70][320] at (+3,+3).
// h-pair blocks: block = (b, 2-row pair, 16-col wseg) = 512 blocks, 2/CU.
// Wave = (row, col-tile): row_w = wave>>1, ct = wave&1. 19 stages, dbuf LDS.
__global__ __launch_bounds__(256, 2)
void cv_mfma_kernel(const unsigned short* __restrict__ x1b,
                    const unsigned short* __restrict__ x2b,
                    unsigned short* __restrict__ cvp) {
    __shared__ __align__(16) unsigned short x2s[2][32 * ASTR];
    int i = blockIdx.x;                    // 512
    int xcd = i & 7;
    int j = i >> 3;                        // 0..63
    int hp = xcd * 4 + (j & 3);            // h-pair 0..31, XCD-banded
    int jj = j >> 2;                       // 0..15
    int wseg = jj & 3;
    int b = jj >> 2;
    int h0 = hp * 2;
    int w0 = wseg * 16;
    int t = threadIdx.x;
    int wave = t >> 6, lane = t & 63;
    int lrow = lane & 15, quad = lane >> 4;
    int row_w = wave >> 1, ct = wave & 1;
    int h = h0 + row_w;
    int col_l = ct * 16 + lrow;

    const unsigned short* x1p = x1b + ((size_t)b * HW + h * 64 + w0) * C;
    bf16x8 a[8];
#pragma unroll
    for (int kk = 0; kk < 8; ++kk)
        a[kk] = *(const bf16x8*)&x1p[(size_t)lrow * C + kk * 32 + quad * 8];

    const unsigned short* x2base = x2b + (size_t)b * PH * PW * C;

    {
        const unsigned short* rowp = x2base + ((size_t)h0 * PW + w0) * C;
#pragma unroll
        for (int s = 0; s < 4; ++s) {
            int v = t + s * 256;
            int col = v >> 5, ch8 = v & 31;
            *(us8*)&x2s[0][col * ASTR + ch8 * 8] = *(const us8*)&rowp[(size_t)col * C + ch8 * 8];
        }
    }
    __syncthreads();

    for (int rr = 0; rr < 19; ++rr) {
        us8 pr[4];
        bool dop = (rr + 1 < 19);
        if (dop) {
            const unsigned short* rowp = x2base + ((size_t)(h0 + rr + 1) * PW + w0) * C;
#pragma unroll
            for (int s = 0; s < 4; ++s) {
                int v = t + s * 256;
                int col = v >> 5, ch8 = v & 31;
                pr[s] = *(const us8*)&rowp[(size_t)col * C + ch8 * 8];
            }
        }

        int dj = rr - row_w;
        if ((unsigned)dj <= 16u) {
            const unsigned short* xs = x2s[rr & 1];
            f32x4 acc = {0.f, 0.f, 0.f, 0.f};
#pragma unroll
            for (int kk = 0; kk < 8; ++kk) {
                bf16x8 bb = *(const bf16x8*)&xs[col_l * ASTR + kk * 32 + quad * 8];
                acc = __builtin_amdgcn_mfma_f32_16x16x32_bf16(a[kk], bb, acc, 0, 0, 0);
            }
#pragma unroll
            for (int r = 0; r < 4; ++r) {
                int px_l = quad * 4 + r;
                int di = col_l - px_l;
                if ((unsigned)di <= 16u) {
                    float v = acc[r] * (1.0f / 256.0f);
                    v = (v > 0.f) ? v : 0.1f * v;
                    __hip_bfloat16 hb = __float2bfloat16(v);
                    cvp[(((size_t)b * CVP + h + 3) * CVP + (w0 + px_l + 3)) * CVC + dj * MO + di] =
                        *(unsigned short*)&hb;
                }
            }
        }

        if (dop) {
            unsigned short* dst = x2s[(rr + 1) & 1];
#pragma unroll
            for (int s = 0; s < 4; ++s) {
                int v = t + s * 256;
                int col = v >> 5, ch8 = v & 31;
                *(us8*)&dst[col * ASTR + ch8 * 8] = pr[s];
            }
            __syncthreads();
        }
    }
}

// ---------------------------------------------------------------------------
// K4: depthwise 7x7 attention conv + multiply, LDS-tiled with sliding-window
// register reuse (LDS reads 833 -> 245 per thread). bf16 cvp in.
__global__ void dw_att_tiled(const unsigned short* __restrict__ cvp,
                             const float* __restrict__ wdwp,
                             const float* __restrict__ att_b, unsigned short* __restrict__ av_pad) {
    __shared__ float actS[14 * 14 * 64];
    __shared__ float wdwS[49 * 64];
    int i = blockIdx.x;                    // 1280
    int ty = i & 7;
    int j = i >> 3;
    int cc = j % 5;
    int rest = j / 5;
    int tx = rest & 7, b = rest >> 3;
    int x0 = tx * 8, y0 = ty * 8;
    int c0 = cc * 64;
    int t = threadIdx.x;

    const unsigned short* cvb = cvp + (((size_t)b * CVP + y0) * CVP + x0) * CVC + c0;
    for (int v = t; v < 14 * 14 * 8; v += 256) {
        int rc = v >> 3, c8v = v & 7;
        int yy = rc / 14, xx = rc - yy * 14;
        bf16x8 raw = *(const bf16x8*)&cvb[((size_t)yy * CVP + xx) * CVC + c8v * 8];
        f32x4 lo, hi;
#pragma unroll
        for (int e = 0; e < 4; ++e) { lo[e] = (float)raw[e]; hi[e] = (float)raw[e + 4]; }
        *(f32x4*)&actS[rc * 64 + c8v * 8] = lo;
        *(f32x4*)&actS[rc * 64 + c8v * 8 + 4] = hi;
    }
    for (int v = t; v < 49 * 64; v += 256) {
        int tap = v >> 6, ch = v & 63;
        wdwS[v] = wdwp[tap * CVC + c0 + ch];
    }
    __syncthreads();

    int ch_l = t & 63, pgrp = t >> 6;
    int ch = c0 + ch_l;
    float bv = (ch < NCH) ? att_b[ch] : 0.f;
    float acc[16];
#pragma unroll
    for (int ii = 0; ii < 16; ++ii) acc[ii] = bv;

    for (int dy = 0; dy < 7; ++dy) {
        float wreg[7];
#pragma unroll
        for (int dx = 0; dx < 7; ++dx)
            wreg[dx] = wdwS[(dy * 7 + dx) * 64 + ch_l];
#pragma unroll
        for (int py2 = 0; py2 < 2; ++py2) {
            int row = pgrp * 2 + py2 + dy;
            float rowv[14];
#pragma unroll
            for (int xx = 0; xx < 14; ++xx)
                rowv[xx] = actS[(row * 14 + xx) * 64 + ch_l];
#pragma unroll
            for (int dx = 0; dx < 7; ++dx)
#pragma unroll
                for (int px = 0; px < 8; ++px)
                    acc[py2 * 8 + px] += rowv[px + dx] * wreg[dx];
        }
    }

    if (ch < NCH) {
#pragma unroll
        for (int ii = 0; ii < 16; ++ii) {
            int py = pgrp * 2 + (ii >> 3), px = ii & 7;
            float c0v = actS[((py + 3) * 14 + (px + 3)) * 64 + ch_l];
            __hip_bfloat16 hb = __float2bfloat16(c0v * acc[ii]);
            av_pad[(((size_t)b * 66 + y0 + py + 1) * 66 + (x0 + px + 1)) * ICP + ch] =
                *(unsigned short*)&hb;
        }
    }
}

// ---------------------------------------------------------------------------
// K5: conv3x3 289->144 + ReLU via bf16 MFMA, software-pipelined, XCD-banded.
__global__ void agg1_mfma_kernel(const unsigned short* __restrict__ av_pad,
                                 const unsigned short* __restrict__ wb1,
                                 const float* __restrict__ bias,
                                 unsigned short* __restrict__ h1p) {
    __shared__ __align__(16) unsigned short aS2[2][66 * CH64];
    __shared__ __align__(16) unsigned short bS[2][C1 * CH64];
    int i = blockIdx.x;                    // 256
    int xcd = i & 7;
    int j = i >> 3;
    int h = xcd * 8 + (j & 7);
    int b = j >> 3;
    int t = threadIdx.x;
    int wave = t >> 6, lane = t & 63;
    int lrow = lane & 15, quad = lane >> 4;
    int ot0 = (wave == 0) ? 0 : (wave * 2 + 1);
    int nt  = (wave == 0) ? 3 : 2;

    f32x4 acc[4][3];
#pragma unroll
    for (int m = 0; m < 4; ++m)
#pragma unroll
        for (int ii = 0; ii < 3; ++ii) acc[m][ii] = (f32x4){0.f, 0.f, 0.f, 0.f};

    const unsigned short* avb = av_pad + (((size_t)b * 66 + h) * 66) * ICP;

    {
        const unsigned short* arow = avb;
#pragma unroll
        for (int s = 0; s < 2; ++s) {
            int v = t + s * 256;
            *(us8*)&aS2[0][(v >> 3) * CH64 + (v & 7) * 8] =
                *(const us8*)&arow[(size_t)(v >> 3) * ICP + (v & 7) * 8];
        }
        if (t < 16) {
            int v = t + 512;
            *(us8*)&aS2[0][(v >> 3) * CH64 + (v & 7) * 8] =
                *(const us8*)&arow[(size_t)(v >> 3) * ICP + (v & 7) * 8];
        }
#pragma unroll
        for (int s = 0; s < 4; ++s) {
            int v = t + s * 256;
            *(us8*)&bS[0][(v >> 3) * CH64 + (v & 7) * 8] =
                *(const us8*)&wb1[(size_t)(v >> 3) * ICP + (v & 7) * 8];
        }
        if (t < 128) {
            int v = t + 1024;
            *(us8*)&bS[0][(v >> 3) * CH64 + (v & 7) * 8] =
                *(const us8*)&wb1[(size_t)(v >> 3) * ICP + (v & 7) * 8];
        }
    }
    __syncthreads();

    for (int k = 0; k < 45; ++k) {
        int rr = k % 15;
        int dx = rr % 3;
        int abuf = (k / 3) & 1, bbuf = k & 1;

        us8 br[5], ar[3];
        int kn = k + 1;
        bool do_b = (kn < 45);
        bool do_a = do_b && (kn % 3 == 0);
        int dyn = kn / 15, rn = kn % 15;
        int ccin = rn / 3, dxn = rn % 3;
        if (do_b) {
            const unsigned short* wt = wb1 + ((size_t)(dyn * 3 + dxn) * C1) * ICP + ccin * 64;
#pragma unroll
            for (int s = 0; s < 4; ++s) {
                int v = t + s * 256;
                br[s] = *(const us8*)&wt[(size_t)(v >> 3) * ICP + (v & 7) * 8];
            }
            if (t < 128) {
                int v = t + 1024;
                br[4] = *(const us8*)&wt[(size_t)(v >> 3) * ICP + (v & 7) * 8];
            }
        }
        if (do_a) {
            const unsigned short* arow = avb + (size_t)dyn * 66 * ICP + ccin * 64;
#pragma unroll
            for (int s = 0; s < 2; ++s) {
                int v = t + s * 256;
                ar[s] = *(const us8*)&arow[(size_t)(v >> 3) * ICP + (v & 7) * 8];
            }
            if (t < 16) {
                int v = t + 512;
                ar[2] = *(const us8*)&arow[(size_t)(v >> 3) * ICP + (v & 7) * 8];
            }
        }

        const unsigned short* aP = aS2[abuf];
        const unsigned short* bP = bS[bbuf];
#pragma unroll
        for (int cc2 = 0; cc2 < 2; ++cc2) {
            bf16x8 bfr[3];
#pragma unroll
            for (int ii = 0; ii < 3; ++ii)
                if (ii < nt)
                    bfr[ii] = *(const bf16x8*)&bP[((ot0 + ii) * 16 + lrow) * CH64 + cc2 * 32 + quad * 8];
#pragma unroll
            for (int m = 0; m < 4; ++m) {
                bf16x8 af = *(const bf16x8*)&aP[(m * 16 + lrow + dx) * CH64 + cc2 * 32 + quad * 8];
#pragma unroll
                for (int ii = 0; ii < 3; ++ii)
                    if (ii < nt)
                        acc[m][ii] = __builtin_amdgcn_mfma_f32_16x16x32_bf16(af, bfr[ii], acc[m][ii], 0, 0, 0);
            }
        }

        if (do_b) {
            unsigned short* dst = bS[bbuf ^ 1];
#pragma unroll
            for (int s = 0; s < 4; ++s) {
                int v = t + s * 256;
                *(us8*)&dst[(v >> 3) * CH64 + (v & 7) * 8] = br[s];
            }
            if (t < 128) {
                int v = t + 1024;
                *(us8*)&dst[(v >> 3) * CH64 + (v & 7) * 8] = br[4];
            }
        }
        if (do_a) {
            unsigned short* dst = aS2[abuf ^ 1];
#pragma unroll
            for (int s = 0; s < 2; ++s) {
                int v = t + s * 256;
                *(us8*)&dst[(v >> 3) * CH64 + (v & 7) * 8] = ar[s];
            }
            if (t < 16) {
                int v = t + 512;
                *(us8*)&dst[(v >> 3) * CH64 + (v & 7) * 8] = ar[2];
            }
        }
        if (do_b) __syncthreads();
    }

    size_t rowbase = ((size_t)b * 66 + h + 1) * 66;
#pragma unroll
    for (int m = 0; m < 4; ++m)
#pragma unroll
        for (int ii = 0; ii < 3; ++ii)
            if (ii < nt) {
                int oc = (ot0 + ii) * 16 + lrow;
                float bv = bias[oc];
#pragma unroll
                for (int r = 0; r < 4; ++r) {
                    int w = m * 16 + quad * 4 + r;
                    float val = fmaxf(acc[m][ii][r] + bv, 0.f);
                    __hip_bfloat16 hb = __float2bfloat16(val);
                    h1p[(rowbase + (w + 1)) * IC3 + oc] = *(unsigned short*)&hb;
                }
            }
}

// ---------------------------------------------------------------------------
// K6: conv3x3 144->49 + ReLU via bf16 MFMA, software-pipelined. XCD-banded.
__global__ void agg2_mfma_kernel(const unsigned short* __restrict__ h1p,
                                 const unsigned short* __restrict__ wb2,
                                 const float* __restrict__ bias, float* __restrict__ out) {
    __shared__ __align__(16) unsigned short aS2[2][66 * CH64];
    __shared__ __align__(16) unsigned short bS2[2][64 * CH64];
    int i = blockIdx.x;                    // 256
    int xcd = i & 7;
    int j = i >> 3;
    int h = xcd * 8 + (j & 7);
    int b = j >> 3;
    int t = threadIdx.x;
    int wave = t >> 6, lane = t & 63;
    int lrow = lane & 15, quad = lane >> 4;
    int pt = wave;

    f32x4 acc[4];
#pragma unroll
    for (int ot = 0; ot < 4; ++ot) acc[ot] = (f32x4){0.f, 0.f, 0.f, 0.f};

    const unsigned short* h1b = h1p + (((size_t)b * 66 + h) * 66) * IC3;

    {
#pragma unroll
        for (int s = 0; s < 2; ++s) {
            int v = t + s * 256;
            *(us8*)&aS2[0][(v >> 3) * CH64 + (v & 7) * 8] =
                *(const us8*)&h1b[(size_t)(v >> 3) * IC3 + (v & 7) * 8];
        }
        if (t < 16) {
            int v = t + 512;
            *(us8*)&aS2[0][(v >> 3) * CH64 + (v & 7) * 8] =
                *(const us8*)&h1b[(size_t)(v >> 3) * IC3 + (v & 7) * 8];
        }
#pragma unroll
        for (int s = 0; s < 2; ++s) {
            int v = t + s * 256;
            *(us8*)&bS2[0][(v >> 3) * CH64 + (v & 7) * 8] =
                *(const us8*)&wb2[(size_t)(v >> 3) * IC3 + (v & 7) * 8];
        }
    }
    __syncthreads();

    for (int k = 0; k < 27; ++k) {
        int rem = k % 9;
        int dx = rem % 3;
        int abuf = (k / 3) & 1, bbuf = k & 1;

        us8 br[2], ar[3];
        int kn = k + 1;
        bool do_b = (kn < 27);
        bool do_a = do_b && (kn % 3 == 0);
        int dyn = kn / 9, rn = kn % 9;
        int ccn = rn / 3, dxn = rn % 3;
        if (do_b) {
            const unsigned short* wt = wb2 + ((size_t)(dyn * 3 + dxn) * 64) * IC3 + ccn * 64;
#pragma unroll
            for (int s = 0; s < 2; ++s) {
                int v = t + s * 256;
                br[s] = *(const us8*)&wt[(size_t)(v >> 3) * IC3 + (v & 7) * 8];
            }
        }
        if (do_a) {
            const unsigned short* arow = h1b + (size_t)dyn * 66 * IC3 + ccn * 64;
#pragma unroll
            for (int s = 0; s < 2; ++s) {
                int v = t + s * 256;
                ar[s] = *(const us8*)&arow[(size_t)(v >> 3) * IC3 + (v & 7) * 8];
            }
            if (t < 16) {
                int v = t + 512;
                ar[2] = *(const us8*)&arow[(size_t)(v >> 3) * IC3 + (v & 7) * 8];
            }
        }

        const unsigned short* aP = aS2[abuf];
        const unsigned short* bP = bS2[bbuf];
#pragma unroll
        for (int cc2 = 0; cc2 < 2; ++cc2) {
            bf16x8 af = *(const bf16x8*)&aP[(pt * 16 + lrow + dx) * CH64 + cc2 * 32 + quad * 8];
#pragma unroll
            for (int ot = 0; ot < 4; ++ot) {
                bf16x8 bfr = *(const bf16x8*)&bP[(ot * 16 + lrow) * CH64 + cc2 * 32 + quad * 8];
                acc[ot] = __builtin_amdgcn_mfma_f32_16x16x32_bf16(af, bfr, acc[ot], 0, 0, 0);
            }
        }

        if (do_b) {
            unsigned short* dst = bS2[bbuf ^ 1];
#pragma unroll
            for (int s = 0; s < 2; ++s) {
                int v = t + s * 256;
                *(us8*)&dst[(v >> 3) * CH64 + (v & 7) * 8] = br[s];
            }
        }
        if (do_a) {
            unsigned short* dst = aS2[abuf ^ 1];
#pragma unroll
            for (int s = 0; s < 2; ++s) {
                int v = t + s * 256;
                *(us8*)&dst[(v >> 3) * CH64 + (v & 7) * 8] = ar[s];
            }
            if (t < 16) {
                int v = t + 512;
                *(us8*)&dst[(v >> 3) * CH64 + (v & 7) * 8] = ar[2];
            }
        }
        if (do_b) __syncthreads();
    }

#pragma unroll
    for (int ot = 0; ot < 4; ++ot) {
        int o = ot * 16 + lrow;
        if (o < C2) {
            float bv = bias[o];
#pragma unroll
            for (int r = 0; r < 4; ++r) {
                int w = pt * 16 + quad * 4 + r;
                out[((size_t)b * C2 + o) * HW + h * 64 + w] = fmaxf(acc[ot][r] + bv, 0.f);
            }
        }
    }
}

// ---------------------------------------------------------------------------
extern "C" void kernel_launch(void* const* d_in, const int* in_sizes, int n_in,
                              void* d_out, int out_size, void* d_ws, size_t ws_size,
                              hipStream_t stream) {
    const float* f1    = (const float*)d_in[0];
    const float* f2    = (const float*)d_in[1];
    const float* att_w = (const float*)d_in[2];
    const float* att_b = (const float*)d_in[3];
    const float* w1    = (const float*)d_in[4];
    const float* b1    = (const float*)d_in[5];
    const float* w2    = (const float*)d_in[6];
    const float* b2    = (const float*)d_in[7];
    float* out = (float*)d_out;

    char* wsb = (char*)d_ws;
    size_t off = 0;
    float* wdwp = (float*)(wsb + off); off += (size_t)49 * CVC * 4;
    off = (off + 15) & ~(size_t)15;
    unsigned short* x1bf = (unsigned short*)(wsb + off); off += (size_t)NPIX * C * 2;
    unsigned short* x2bf = (unsigned short*)(wsb + off); off += (size_t)BS * PH * PW * C * 2;
    unsigned short* cvp  = (unsigned short*)(wsb + off); off += (size_t)BS * CVP * CVP * CVC * 2;
    unsigned short* avp  = (unsigned short*)(wsb + off); off += (size_t)BS * 66 * 66 * ICP * 2;
    unsigned short* wb1  = (unsigned short*)(wsb + off); off += (size_t)9 * C1 * ICP * 2;
    unsigned short* h1p  = (unsigned short*)(wsb + off); off += (size_t)BS * 66 * 66 * IC3 * 2;
    unsigned short* wb2  = (unsigned short*)(wsb + off); off += (size_t)9 * 64 * IC3 * 2;
    if (ws_size < off) return;

    setup_kernel<<<8638, 256, 0, stream>>>(x2bf, cvp, avp, h1p, w1, wb1, w2, wb2,
                                           att_w, wdwp, f1, x1bf, f2);
    cv_mfma_kernel<<<512, 256, 0, stream>>>(x1bf, x2bf, cvp);
    dw_att_tiled<<<1280, 256, 0, stream>>>(cvp, wdwp, att_b, avp);
    agg1_mfma_kernel<<<256, 256, 0, stream>>>(avp, wb1, b1, h1p);
    agg2_mfma_kernel<<<256, 256, 0, stream>>>(h1p, wb2, b2, out);
}

// Round 13
// 185.121 us; speedup vs baseline: 8.8847x; 1.0100x over previous
//
#include <hip/hip_runtime.h>
#include <hip/hip_bf16.h>

// Problem constants
#define BS   4
#define C    256
#define HW   4096          // 64*64
#define NPIX 16384         // 4*4096
#define NCH  289           // cost-volume channels (17*17)
#define MO   17
#define PH   80            // padded 64+2*8
#define PW   80
#define C1   144
#define C2   49
#define ASTR 264           // cv LDS row stride in bf16 elems
#define ICP  320           // agg1 padded input channels (289 -> 320)
#define IC3  192           // agg2 padded input channels (144 -> 192 = 3*64)
#define CVP  70            // cv padded spatial (64 + 2*3)
#define CVC  320           // cv padded channels
#define CH64 72            // 64-ch chunk LDS stride (64+8): bank-balanced

typedef __bf16  bf16x8 __attribute__((ext_vector_type(8)));
typedef float   f32x4  __attribute__((ext_vector_type(4)));
typedef unsigned short us8 __attribute__((ext_vector_type(8)));

// ---------------------------------------------------------------------------
// Setup kernel: prep (halo zeros + weight rearranges) + f1 norm-transpose +
// f2 pad-transpose, dispatched by blockIdx range. 8638 blocks total.
__device__ __forceinline__ void halo_zero_dev(unsigned short* p, int H, int halo,
                                              int Cc, int blk, int t) {
    int W = H;
    int inter = H - 2 * halo;
    int total_pos = H * W - inter * inter;
    int chunks = Cc >> 3;
    size_t tot = (size_t)total_pos * chunks * BS;
    size_t idx = (size_t)blk * 256 + t;
    if (idx >= tot) return;
    int c8 = (int)(idx % chunks);
    size_t r = idx / chunks;
    int pos = (int)(r % total_pos);
    int b = (int)(r / total_pos);
    int h, w;
    int topbot = 2 * halo * W;
    if (pos < halo * W) { h = pos / W; w = pos % W; }
    else if (pos < topbot) { int q = pos - halo * W; h = H - halo + q / W; w = q % W; }
    else {
        int q = pos - topbot;
        int row = q / (2 * halo), off = q % (2 * halo);
        h = halo + row;
        w = (off < halo) ? off : (W - 2 * halo + off);
    }
    us8 z = {0, 0, 0, 0, 0, 0, 0, 0};
    *(us8*)&p[(((size_t)b * H + h) * W + w) * Cc + c8 * 8] = z;
}

__global__ void setup_kernel(unsigned short* __restrict__ x2bf, unsigned short* __restrict__ cvp,
                             unsigned short* __restrict__ avp, unsigned short* __restrict__ h1p,
                             const float* __restrict__ w1, unsigned short* __restrict__ wb1,
                             const float* __restrict__ w2, unsigned short* __restrict__ wb2,
                             const float* __restrict__ att_w, float* __restrict__ wdwp,
                             const float* __restrict__ f1, unsigned short* __restrict__ x1bf,
                             const float* __restrict__ f2) {
    __shared__ float shmem[32 * 257 + 32];
    int blk = blockIdx.x;
    int t = threadIdx.x;
    if (blk < 4030) {
        if (blk < 1152) { halo_zero_dev(x2bf, PH, 8, C, blk, t); return; }
        if (blk < 1655) { halo_zero_dev(cvp, CVP, 3, CVC, blk - 1152, t); return; }
        if (blk < 1818) { halo_zero_dev(avp, 66, 1, ICP, blk - 1655, t); return; }
        if (blk < 1916) { halo_zero_dev(h1p, 66, 1, IC3, blk - 1818, t); return; }
        if (blk < 3536) {                 // w1 -> [9][144][320]
            int idx = (blk - 1916) * 256 + t;
            int tap = idx / (C1 * ICP);
            int r = idx - tap * (C1 * ICP);
            int oc = r / ICP;
            int ic = r - oc * ICP;
            float v = (ic < NCH) ? w1[((size_t)(oc * NCH + ic)) * 9 + tap] : 0.f;
            __hip_bfloat16 hb = __float2bfloat16(v);
            wb1[idx] = *(unsigned short*)&hb;
            return;
        }
        if (blk < 3968) {                 // w2 -> [9][64][192]
            int idx = (blk - 3536) * 256 + t;
            int tap = idx / (64 * IC3);
            int r = idx - tap * (64 * IC3);
            int oc = r / IC3;
            int ic = r - oc * IC3;
            float v = (oc < C2 && ic < C1) ? w2[((size_t)(oc * C1 + ic)) * 9 + tap] : 0.f;
            __hip_bfloat16 hb = __float2bfloat16(v);
            wb2[idx] = *(unsigned short*)&hb;
            return;
        }
        {                                 // dw -> [49][320]
            int idx = (blk - 3968) * 256 + t;
            if (idx >= 49 * CVC) return;
            int tap = idx / CVC;
            int ch = idx - tap * CVC;
            wdwp[idx] = (ch < NCH) ? att_w[ch * 49 + tap] : 0.f;
        }
        return;
    }
    if (blk < 4542) {
        // f1: fused norm + transpose
        float* tileT = shmem;
        float* invS = shmem + 32 * 257;
        int bb = blk - 4030;
        int pblk = bb & 127, b = bb >> 7;
        int p0 = pblk * 32;
        int tx = t & 31, ty = t >> 5;
        const float* s = f1 + (size_t)b * C * HW;
#pragma unroll
        for (int i = 0; i < 32; ++i) {
            int c = ty + 8 * i;
            tileT[tx * 257 + c] = s[(size_t)c * HW + p0 + tx];
        }
        __syncthreads();
        int lane = t & 63, wave = t >> 6;
        int px = wave * 8 + (lane >> 3);
        int l = lane & 7;
        float ssum = 0.f;
#pragma unroll
        for (int j = 0; j < 32; ++j) {
            float v = tileT[px * 257 + l + 8 * j];
            ssum += v * v;
        }
        ssum += __shfl_xor(ssum, 1);
        ssum += __shfl_xor(ssum, 2);
        ssum += __shfl_xor(ssum, 4);
        if (l == 0) invS[px] = 1.0f / fmaxf(sqrtf(ssum), 1e-12f);
        __syncthreads();
#pragma unroll 4
        for (int p = 0; p < 32; ++p) {
            float v = tileT[p * 257 + t] * invS[p];
            __hip_bfloat16 hb = __float2bfloat16(v);
            x1bf[((size_t)b * HW + p0 + p) * C + t] = *(unsigned short*)&hb;
        }
        return;
    }
    {
        // f2: pad transpose
        float* tile = shmem;              // [32][33]
        int bb = blk - 4542;
        int pblk = bb & 127;
        int cblk = (bb >> 7) & 7;
        int b    = bb >> 10;
        int tx = t & 31, ty = t >> 5;
        int c0 = cblk * 32, p0 = pblk * 32;
        const float* s = f2 + (size_t)b * C * HW;
#pragma unroll
        for (int i = 0; i < 4; ++i) {
            int c = c0 + ty + 8 * i;
            tile[(ty + 8 * i) * 33 + tx] = s[(size_t)c * HW + p0 + tx];
        }
        __syncthreads();
#pragma unroll
        for (int i = 0; i < 4; ++i) {
            int p = p0 + ty + 8 * i;
            float v = tile[tx * 33 + ty + 8 * i];
            int c = c0 + tx;
            int h = p >> 6, w = p & 63;
            __hip_bfloat16 hb = __float2bfloat16(v);
            x2bf[(((size_t)b * PH + h + 8) * PW + (w + 8)) * C + c] = *(unsigned short*)&hb;
        }
    }
}

// ---------------------------------------------------------------------------
// K3: cost volume via bf16 MFMA -> padded bf16 cvp [4][70][70][320] at (+3,+3).
__global__ __launch_bounds__(256, 2)
void cv_mfma_kernel(const unsigned short* __restrict__ x1b,
                    const unsigned short* __restrict__ x2b,
                    unsigned short* __restrict__ cvp) {
    __shared__ __align__(16) unsigned short x2s[2][32 * ASTR];
    int i = blockIdx.x;                    // 512
    int xcd = i & 7;
    int j = i >> 3;
    int hp = xcd * 4 + (j & 3);
    int jj = j >> 2;
    int wseg = jj & 3;
    int b = jj >> 2;
    int h0 = hp * 2;
    int w0 = wseg * 16;
    int t = threadIdx.x;
    int wave = t >> 6, lane = t & 63;
    int lrow = lane & 15, quad = lane >> 4;
    int row_w = wave >> 1, ct = wave & 1;
    int h = h0 + row_w;
    int col_l = ct * 16 + lrow;

    const unsigned short* x1p = x1b + ((size_t)b * HW + h * 64 + w0) * C;
    bf16x8 a[8];
#pragma unroll
    for (int kk = 0; kk < 8; ++kk)
        a[kk] = *(const bf16x8*)&x1p[(size_t)lrow * C + kk * 32 + quad * 8];

    const unsigned short* x2base = x2b + (size_t)b * PH * PW * C;

    {
        const unsigned short* rowp = x2base + ((size_t)h0 * PW + w0) * C;
#pragma unroll
        for (int s = 0; s < 4; ++s) {
            int v = t + s * 256;
            int col = v >> 5, ch8 = v & 31;
            *(us8*)&x2s[0][col * ASTR + ch8 * 8] = *(const us8*)&rowp[(size_t)col * C + ch8 * 8];
        }
    }
    __syncthreads();

    for (int rr = 0; rr < 19; ++rr) {
        us8 pr[4];
        bool dop = (rr + 1 < 19);
        if (dop) {
            const unsigned short* rowp = x2base + ((size_t)(h0 + rr + 1) * PW + w0) * C;
#pragma unroll
            for (int s = 0; s < 4; ++s) {
                int v = t + s * 256;
                int col = v >> 5, ch8 = v & 31;
                pr[s] = *(const us8*)&rowp[(size_t)col * C + ch8 * 8];
            }
        }

        int dj = rr - row_w;
        if ((unsigned)dj <= 16u) {
            const unsigned short* xs = x2s[rr & 1];
            f32x4 acc = {0.f, 0.f, 0.f, 0.f};
#pragma unroll
            for (int kk = 0; kk < 8; ++kk) {
                bf16x8 bb = *(const bf16x8*)&xs[col_l * ASTR + kk * 32 + quad * 8];
                acc = __builtin_amdgcn_mfma_f32_16x16x32_bf16(a[kk], bb, acc, 0, 0, 0);
            }
#pragma unroll
            for (int r = 0; r < 4; ++r) {
                int px_l = quad * 4 + r;
                int di = col_l - px_l;
                if ((unsigned)di <= 16u) {
                    float v = acc[r] * (1.0f / 256.0f);
                    v = (v > 0.f) ? v : 0.1f * v;
                    __hip_bfloat16 hb = __float2bfloat16(v);
                    cvp[(((size_t)b * CVP + h + 3) * CVP + (w0 + px_l + 3)) * CVC + dj * MO + di] =
                        *(unsigned short*)&hb;
                }
            }
        }

        if (dop) {
            unsigned short* dst = x2s[(rr + 1) & 1];
#pragma unroll
            for (int s = 0; s < 4; ++s) {
                int v = t + s * 256;
                int col = v >> 5, ch8 = v & 31;
                *(us8*)&dst[col * ASTR + ch8 * 8] = pr[s];
            }
            __syncthreads();
        }
    }
}

// ---------------------------------------------------------------------------
// K4: depthwise 7x7 attention conv + multiply. actS kept in bf16 (25 KB) so
// LDS = 37.6 KB -> 4 blocks/CU (was 2). Values identical (bf16->f32 exact).
__global__ __launch_bounds__(256, 4)
void dw_att_tiled(const unsigned short* __restrict__ cvp,
                  const float* __restrict__ wdwp,
                  const float* __restrict__ att_b, unsigned short* __restrict__ av_pad) {
    __shared__ __align__(16) unsigned short actS[14 * 14 * 64];   // 25 KB bf16
    __shared__ float wdwS[49 * 64];                                // 12.5 KB
    int i = blockIdx.x;                    // 1280
    int ty = i & 7;
    int j = i >> 3;
    int cc = j % 5;
    int rest = j / 5;
    int tx = rest & 7, b = rest >> 3;
    int x0 = tx * 8, y0 = ty * 8;
    int c0 = cc * 64;
    int t = threadIdx.x;

    const unsigned short* cvb = cvp + (((size_t)b * CVP + y0) * CVP + x0) * CVC + c0;
    for (int v = t; v < 14 * 14 * 8; v += 256) {
        int rc = v >> 3, c8v = v & 7;
        int yy = rc / 14, xx = rc - yy * 14;
        *(us8*)&actS[rc * 64 + c8v * 8] =
            *(const us8*)&cvb[((size_t)yy * CVP + xx) * CVC + c8v * 8];
    }
    for (int v = t; v < 49 * 64; v += 256) {
        int tap = v >> 6, ch = v & 63;
        wdwS[v] = wdwp[tap * CVC + c0 + ch];
    }
    __syncthreads();

    int ch_l = t & 63, pgrp = t >> 6;
    int ch = c0 + ch_l;
    float bv = (ch < NCH) ? att_b[ch] : 0.f;
    float acc[16];
#pragma unroll
    for (int ii = 0; ii < 16; ++ii) acc[ii] = bv;

    for (int dy = 0; dy < 7; ++dy) {
        float wreg[7];
#pragma unroll
        for (int dx = 0; dx < 7; ++dx)
            wreg[dx] = wdwS[(dy * 7 + dx) * 64 + ch_l];
#pragma unroll
        for (int py2 = 0; py2 < 2; ++py2) {
            int row = pgrp * 2 + py2 + dy;
            float rowv[14];
#pragma unroll
            for (int xx = 0; xx < 14; ++xx) {
                __bf16 bvv = *(const __bf16*)&actS[(row * 14 + xx) * 64 + ch_l];
                rowv[xx] = (float)bvv;
            }
#pragma unroll
            for (int dx = 0; dx < 7; ++dx)
#pragma unroll
                for (int px = 0; px < 8; ++px)
                    acc[py2 * 8 + px] += rowv[px + dx] * wreg[dx];
        }
    }

    if (ch < NCH) {
#pragma unroll
        for (int ii = 0; ii < 16; ++ii) {
            int py = pgrp * 2 + (ii >> 3), px = ii & 7;
            __bf16 cb = *(const __bf16*)&actS[((py + 3) * 14 + (px + 3)) * 64 + ch_l];
            float c0v = (float)cb;
            __hip_bfloat16 hb = __float2bfloat16(c0v * acc[ii]);
            av_pad[(((size_t)b * 66 + y0 + py + 1) * 66 + (x0 + px + 1)) * ICP + ch] =
                *(unsigned short*)&hb;
        }
    }
}

// ---------------------------------------------------------------------------
// K5: conv3x3 289->144 + ReLU via bf16 MFMA, software-pipelined, XCD-banded.
__global__ void agg1_mfma_kernel(const unsigned short* __restrict__ av_pad,
                                 const unsigned short* __restrict__ wb1,
                                 const float* __restrict__ bias,
                                 unsigned short* __restrict__ h1p) {
    __shared__ __align__(16) unsigned short aS2[2][66 * CH64];
    __shared__ __align__(16) unsigned short bS[2][C1 * CH64];
    int i = blockIdx.x;                    // 256
    int xcd = i & 7;
    int j = i >> 3;
    int h = xcd * 8 + (j & 7);
    int b = j >> 3;
    int t = threadIdx.x;
    int wave = t >> 6, lane = t & 63;
    int lrow = lane & 15, quad = lane >> 4;
    int ot0 = (wave == 0) ? 0 : (wave * 2 + 1);
    int nt  = (wave == 0) ? 3 : 2;

    f32x4 acc[4][3];
#pragma unroll
    for (int m = 0; m < 4; ++m)
#pragma unroll
        for (int ii = 0; ii < 3; ++ii) acc[m][ii] = (f32x4){0.f, 0.f, 0.f, 0.f};

    const unsigned short* avb = av_pad + (((size_t)b * 66 + h) * 66) * ICP;

    {
        const unsigned short* arow = avb;
#pragma unroll
        for (int s = 0; s < 2; ++s) {
            int v = t + s * 256;
            *(us8*)&aS2[0][(v >> 3) * CH64 + (v & 7) * 8] =
                *(const us8*)&arow[(size_t)(v >> 3) * ICP + (v & 7) * 8];
        }
        if (t < 16) {
            int v = t + 512;
            *(us8*)&aS2[0][(v >> 3) * CH64 + (v & 7) * 8] =
                *(const us8*)&arow[(size_t)(v >> 3) * ICP + (v & 7) * 8];
        }
#pragma unroll
        for (int s = 0; s < 4; ++s) {
            int v = t + s * 256;
            *(us8*)&bS[0][(v >> 3) * CH64 + (v & 7) * 8] =
                *(const us8*)&wb1[(size_t)(v >> 3) * ICP + (v & 7) * 8];
        }
        if (t < 128) {
            int v = t + 1024;
            *(us8*)&bS[0][(v >> 3) * CH64 + (v & 7) * 8] =
                *(const us8*)&wb1[(size_t)(v >> 3) * ICP + (v & 7) * 8];
        }
    }
    __syncthreads();

    for (int k = 0; k < 45; ++k) {
        int rr = k % 15;
        int dx = rr % 3;
        int abuf = (k / 3) & 1, bbuf = k & 1;

        us8 br[5], ar[3];
        int kn = k + 1;
        bool do_b = (kn < 45);
        bool do_a = do_b && (kn % 3 == 0);
        int dyn = kn / 15, rn = kn % 15;
        int ccin = rn / 3, dxn = rn % 3;
        if (do_b) {
            const unsigned short* wt = wb1 + ((size_t)(dyn * 3 + dxn) * C1) * ICP + ccin * 64;
#pragma unroll
            for (int s = 0; s < 4; ++s) {
                int v = t + s * 256;
                br[s] = *(const us8*)&wt[(size_t)(v >> 3) * ICP + (v & 7) * 8];
            }
            if (t < 128) {
                int v = t + 1024;
                br[4] = *(const us8*)&wt[(size_t)(v >> 3) * ICP + (v & 7) * 8];
            }
        }
        if (do_a) {
            const unsigned short* arow = avb + (size_t)dyn * 66 * ICP + ccin * 64;
#pragma unroll
            for (int s = 0; s < 2; ++s) {
                int v = t + s * 256;
                ar[s] = *(const us8*)&arow[(size_t)(v >> 3) * ICP + (v & 7) * 8];
            }
            if (t < 16) {
                int v = t + 512;
                ar[2] = *(const us8*)&arow[(size_t)(v >> 3) * ICP + (v & 7) * 8];
            }
        }

        const unsigned short* aP = aS2[abuf];
        const unsigned short* bP = bS[bbuf];
#pragma unroll
        for (int cc2 = 0; cc2 < 2; ++cc2) {
            bf16x8 bfr[3];
#pragma unroll
            for (int ii = 0; ii < 3; ++ii)
                if (ii < nt)
                    bfr[ii] = *(const bf16x8*)&bP[((ot0 + ii) * 16 + lrow) * CH64 + cc2 * 32 + quad * 8];
#pragma unroll
            for (int m = 0; m < 4; ++m) {
                bf16x8 af = *(const bf16x8*)&aP[(m * 16 + lrow + dx) * CH64 + cc2 * 32 + quad * 8];
#pragma unroll
                for (int ii = 0; ii < 3; ++ii)
                    if (ii < nt)
                        acc[m][ii] = __builtin_amdgcn_mfma_f32_16x16x32_bf16(af, bfr[ii], acc[m][ii], 0, 0, 0);
            }
        }

        if (do_b) {
            unsigned short* dst = bS[bbuf ^ 1];
#pragma unroll
            for (int s = 0; s < 4; ++s) {
                int v = t + s * 256;
                *(us8*)&dst[(v >> 3) * CH64 + (v & 7) * 8] = br[s];
            }
            if (t < 128) {
                int v = t + 1024;
                *(us8*)&dst[(v >> 3) * CH64 + (v & 7) * 8] = br[4];
            }
        }
        if (do_a) {
            unsigned short* dst = aS2[abuf ^ 1];
#pragma unroll
            for (int s = 0; s < 2; ++s) {
                int v = t + s * 256;
                *(us8*)&dst[(v >> 3) * CH64 + (v & 7) * 8] = ar[s];
            }
            if (t < 16) {
                int v = t + 512;
                *(us8*)&dst[(v >> 3) * CH64 + (v & 7) * 8] = ar[2];
            }
        }
        if (do_b) __syncthreads();
    }

    size_t rowbase = ((size_t)b * 66 + h + 1) * 66;
#pragma unroll
    for (int m = 0; m < 4; ++m)
#pragma unroll
        for (int ii = 0; ii < 3; ++ii)
            if (ii < nt) {
                int oc = (ot0 + ii) * 16 + lrow;
                float bv = bias[oc];
#pragma unroll
                for (int r = 0; r < 4; ++r) {
                    int w = m * 16 + quad * 4 + r;
                    float val = fmaxf(acc[m][ii][r] + bv, 0.f);
                    __hip_bfloat16 hb = __float2bfloat16(val);
                    h1p[(rowbase + (w + 1)) * IC3 + oc] = *(unsigned short*)&hb;
                }
            }
}

// ---------------------------------------------------------------------------
// K6: conv3x3 144->49 + ReLU via bf16 MFMA, software-pipelined. XCD-banded.
__global__ void agg2_mfma_kernel(const unsigned short* __restrict__ h1p,
                                 const unsigned short* __restrict__ wb2,
                                 const float* __restrict__ bias, float* __restrict__ out) {
    __shared__ __align__(16) unsigned short aS2[2][66 * CH64];
    __shared__ __align__(16) unsigned short bS2[2][64 * CH64];
    int i = blockIdx.x;                    // 256
    int xcd = i & 7;
    int j = i >> 3;
    int h = xcd * 8 + (j & 7);
    int b = j >> 3;
    int t = threadIdx.x;
    int wave = t >> 6, lane = t & 63;
    int lrow = lane & 15, quad = lane >> 4;
    int pt = wave;

    f32x4 acc[4];
#pragma unroll
    for (int ot = 0; ot < 4; ++ot) acc[ot] = (f32x4){0.f, 0.f, 0.f, 0.f};

    const unsigned short* h1b = h1p + (((size_t)b * 66 + h) * 66) * IC3;

    {
#pragma unroll
        for (int s = 0; s < 2; ++s) {
            int v = t + s * 256;
            *(us8*)&aS2[0][(v >> 3) * CH64 + (v & 7) * 8] =
                *(const us8*)&h1b[(size_t)(v >> 3) * IC3 + (v & 7) * 8];
        }
        if (t < 16) {
            int v = t + 512;
            *(us8*)&aS2[0][(v >> 3) * CH64 + (v & 7) * 8] =
                *(const us8*)&h1b[(size_t)(v >> 3) * IC3 + (v & 7) * 8];
        }
#pragma unroll
        for (int s = 0; s < 2; ++s) {
            int v = t + s * 256;
            *(us8*)&bS2[0][(v >> 3) * CH64 + (v & 7) * 8] =
                *(const us8*)&wb2[(size_t)(v >> 3) * IC3 + (v & 7) * 8];
        }
    }
    __syncthreads();

    for (int k = 0; k < 27; ++k) {
        int rem = k % 9;
        int dx = rem % 3;
        int abuf = (k / 3) & 1, bbuf = k & 1;

        us8 br[2], ar[3];
        int kn = k + 1;
        bool do_b = (kn < 27);
        bool do_a = do_b && (kn % 3 == 0);
        int dyn = kn / 9, rn = kn % 9;
        int ccn = rn / 3, dxn = rn % 3;
        if (do_b) {
            const unsigned short* wt = wb2 + ((size_t)(dyn * 3 + dxn) * 64) * IC3 + ccn * 64;
#pragma unroll
            for (int s = 0; s < 2; ++s) {
                int v = t + s * 256;
                br[s] = *(const us8*)&wt[(size_t)(v >> 3) * IC3 + (v & 7) * 8];
            }
        }
        if (do_a) {
            const unsigned short* arow = h1b + (size_t)dyn * 66 * IC3 + ccn * 64;
#pragma unroll
            for (int s = 0; s < 2; ++s) {
                int v = t + s * 256;
                ar[s] = *(const us8*)&arow[(size_t)(v >> 3) * IC3 + (v & 7) * 8];
            }
            if (t < 16) {
                int v = t + 512;
                ar[2] = *(const us8*)&arow[(size_t)(v >> 3) * IC3 + (v & 7) * 8];
            }
        }

        const unsigned short* aP = aS2[abuf];
        const unsigned short* bP = bS2[bbuf];
#pragma unroll
        for (int cc2 = 0; cc2 < 2; ++cc2) {
            bf16x8 af = *(const bf16x8*)&aP[(pt * 16 + lrow + dx) * CH64 + cc2 * 32 + quad * 8];
#pragma unroll
            for (int ot = 0; ot < 4; ++ot) {
                bf16x8 bfr = *(const bf16x8*)&bP[(ot * 16 + lrow) * CH64 + cc2 * 32 + quad * 8];
                acc[ot] = __builtin_amdgcn_mfma_f32_16x16x32_bf16(af, bfr, acc[ot], 0, 0, 0);
            }
        }

        if (do_b) {
            unsigned short* dst = bS2[bbuf ^ 1];
#pragma unroll
            for (int s = 0; s < 2; ++s) {
                int v = t + s * 256;
                *(us8*)&dst[(v >> 3) * CH64 + (v & 7) * 8] = br[s];
            }
        }
        if (do_a) {
            unsigned short* dst = aS2[abuf ^ 1];
#pragma unroll
            for (int s = 0; s < 2; ++s) {
                int v = t + s * 256;
                *(us8*)&dst[(v >> 3) * CH64 + (v & 7) * 8] = ar[s];
            }
            if (t < 16) {
                int v = t + 512;
                *(us8*)&dst[(v >> 3) * CH64 + (v & 7) * 8] = ar[2];
            }
        }
        if (do_b) __syncthreads();
    }

#pragma unroll
    for (int ot = 0; ot < 4; ++ot) {
        int o = ot * 16 + lrow;
        if (o < C2) {
            float bv = bias[o];
#pragma unroll
            for (int r = 0; r < 4; ++r) {
                int w = pt * 16 + quad * 4 + r;
                out[((size_t)b * C2 + o) * HW + h * 64 + w] = fmaxf(acc[ot][r] + bv, 0.f);
            }
        }
    }
}

// ---------------------------------------------------------------------------
extern "C" void kernel_launch(void* const* d_in, const int* in_sizes, int n_in,
                              void* d_out, int out_size, void* d_ws, size_t ws_size,
                              hipStream_t stream) {
    const float* f1    = (const float*)d_in[0];
    const float* f2    = (const float*)d_in[1];
    const float* att_w = (const float*)d_in[2];
    const float* att_b = (const float*)d_in[3];
    const float* w1    = (const float*)d_in[4];
    const float* b1    = (const float*)d_in[5];
    const float* w2    = (const float*)d_in[6];
    const float* b2    = (const float*)d_in[7];
    float* out = (float*)d_out;

    char* wsb = (char*)d_ws;
    size_t off = 0;
    float* wdwp = (float*)(wsb + off); off += (size_t)49 * CVC * 4;
    off = (off + 15) & ~(size_t)15;
    unsigned short* x1bf = (unsigned short*)(wsb + off); off += (size_t)NPIX * C * 2;
    unsigned short* x2bf = (unsigned short*)(wsb + off); off += (size_t)BS * PH * PW * C * 2;
    unsigned short* cvp  = (unsigned short*)(wsb + off); off += (size_t)BS * CVP * CVP * CVC * 2;
    unsigned short* avp  = (unsigned short*)(wsb + off); off += (size_t)BS * 66 * 66 * ICP * 2;
    unsigned short* wb1  = (unsigned short*)(wsb + off); off += (size_t)9 * C1 * ICP * 2;
    unsigned short* h1p  = (unsigned short*)(wsb + off); off += (size_t)BS * 66 * 66 * IC3 * 2;
    unsigned short* wb2  = (unsigned short*)(wsb + off); off += (size_t)9 * 64 * IC3 * 2;
    if (ws_size < off) return;

    setup_kernel<<<8638, 256, 0, stream>>>(x2bf, cvp, avp, h1p, w1, wb1, w2, wb2,
                                           att_w, wdwp, f1, x1bf, f2);
    cv_mfma_kernel<<<512, 256, 0, stream>>>(x1bf, x2bf, cvp);
    dw_att_tiled<<<1280, 256, 0, stream>>>(cvp, wdwp, att_b, avp);
    agg1_mfma_kernel<<<256, 256, 0, stream>>>(avp, wb1, b1, h1p);
    agg2_mfma_kernel<<<256, 256, 0, stream>>>(h1p, wb2, b2, out);
}